// Round 1
// baseline (1574.484 us; speedup 1.0000x reference)
//
#include <hip/hip_runtime.h>
#include <hip/hip_bf16.h>
#include <math.h>

constexpr int Nn   = 50000;
constexpr int Ecnt = 800000;
constexpr int Gn   = 128;
constexpr int Din  = 256;
constexpr int Lout = 1024;

__device__ __forceinline__ float lrelu(float x) { return x >= 0.f ? x : 0.2f * x; }

// ---------------- CSR build ----------------
__global__ void count_kernel(const int* __restrict__ dst, int* __restrict__ cnt, int n) {
    int i = blockIdx.x * blockDim.x + threadIdx.x;
    if (i < n) atomicAdd(&cnt[dst[i]], 1);
}

__global__ __launch_bounds__(1024) void scan_kernel(const int* __restrict__ cnt,
                                                    int* __restrict__ row_ptr, int n) {
    __shared__ int buf[1024];
    __shared__ int carry;
    int t = threadIdx.x;
    if (t == 0) carry = 0;
    __syncthreads();
    for (int base = 0; base < n; base += 1024) {
        int v = (base + t < n) ? cnt[base + t] : 0;
        buf[t] = v;
        __syncthreads();
        for (int off = 1; off < 1024; off <<= 1) {
            int x = (t >= off) ? buf[t - off] : 0;
            __syncthreads();
            buf[t] += x;
            __syncthreads();
        }
        int incl = buf[t];
        int c = carry;
        if (base + t < n) row_ptr[base + t] = c + incl - v;   // exclusive
        __syncthreads();
        if (t == 1023) carry = c + buf[1023];
        __syncthreads();
    }
    if (t == 0) row_ptr[n] = carry;
}

__global__ void fill_kernel(const int* __restrict__ src, const int* __restrict__ dst,
                            const int* __restrict__ row_ptr, int* __restrict__ cursor,
                            int* __restrict__ csr_src, int n) {
    int i = blockIdx.x * blockDim.x + threadIdx.x;
    if (i >= n) return;
    int d = dst[i];
    int pos = row_ptr[d] + atomicAdd(&cursor[d], 1);
    csr_src[pos] = src[i];
}

// ---------------- SGEMM: C[M,Nc] = A[M,K] @ B[K,Nc] ----------------
__global__ __launch_bounds__(256) void sgemm64(const float* __restrict__ A,
                                               const float* __restrict__ B,
                                               float* __restrict__ C,
                                               int M, int K, int Nc) {
    __shared__ float As[16][65];  // [k][m]
    __shared__ float Bs[16][65];  // [k][n]
    int tid = threadIdx.x;
    int bm = blockIdx.x * 64;
    int bn = blockIdx.y * 64;
    int tx = tid & 15, ty = tid >> 4;
    float acc[4][4] = {};
    for (int k0 = 0; k0 < K; k0 += 16) {
        #pragma unroll
        for (int i = 0; i < 4; i++) {
            int idx = tid + i * 256;
            int m = idx >> 4, kk = idx & 15;
            As[kk][m] = (bm + m < M) ? A[(size_t)(bm + m) * K + k0 + kk] : 0.f;
            int kb = idx >> 6, nb = idx & 63;
            Bs[kb][nb] = B[(size_t)(k0 + kb) * Nc + bn + nb];
        }
        __syncthreads();
        #pragma unroll
        for (int kk = 0; kk < 16; kk++) {
            float a[4], b[4];
            #pragma unroll
            for (int i = 0; i < 4; i++) a[i] = As[kk][ty * 4 + i];
            #pragma unroll
            for (int j = 0; j < 4; j++) b[j] = Bs[kk][tx * 4 + j];
            #pragma unroll
            for (int i = 0; i < 4; i++)
                #pragma unroll
                for (int j = 0; j < 4; j++) acc[i][j] += a[i] * b[j];
        }
        __syncthreads();
    }
    #pragma unroll
    for (int i = 0; i < 4; i++) {
        int m = bm + ty * 4 + i;
        if (m >= M) continue;
        #pragma unroll
        for (int j = 0; j < 4; j++)
            C[(size_t)m * Nc + bn + tx * 4 + j] = acc[i][j];
    }
}

// ---------------- per-node scores: ssrc = h@a_src, sdst = h@a_dst ----------------
__global__ void scores_kernel(const float* __restrict__ h, const float* __restrict__ a_src,
                              const float* __restrict__ a_dst, float* __restrict__ ssrc,
                              float* __restrict__ sdst, int n, int F) {
    int wid = (blockIdx.x * blockDim.x + threadIdx.x) >> 6;
    int lane = threadIdx.x & 63;
    if (wid >= n) return;
    float vs = 0.f, vd = 0.f;
    for (int f = lane; f < F; f += 64) {
        float hv = h[(size_t)wid * F + f];
        vs += hv * a_src[f];
        vd += hv * a_dst[f];
    }
    #pragma unroll
    for (int o = 32; o; o >>= 1) { vs += __shfl_xor(vs, o); vd += __shfl_xor(vd, o); }
    if (lane == 0) { ssrc[wid] = vs; sdst[wid] = vd; }
}

// ---------------- attention softmax + aggregation (one wave per dst node) ----------------
__global__ void attn_agg_kernel(const float* __restrict__ h, const float* __restrict__ ssrc,
                                const float* __restrict__ sdst,
                                const int* __restrict__ row_ptr, const int* __restrict__ csr_src,
                                const float* __restrict__ bias, float* __restrict__ xout,
                                int n, int F) {
    int wid = (blockIdx.x * blockDim.x + threadIdx.x) >> 6;
    int lane = threadIdx.x & 63;
    if (wid >= n) return;
    int beg = row_ptr[wid], end = row_ptr[wid + 1];
    float sd = sdst[wid];
    float eself = lrelu(ssrc[wid] + sd);
    // pass 1: max
    float m = eself;
    for (int p = beg + lane; p < end; p += 64)
        m = fmaxf(m, lrelu(ssrc[csr_src[p]] + sd));
    #pragma unroll
    for (int o = 32; o; o >>= 1) m = fmaxf(m, __shfl_xor(m, o));
    // pass 2: denom
    float dsum = (lane == 0) ? expf(eself - m) : 0.f;
    for (int p = beg + lane; p < end; p += 64)
        dsum += expf(lrelu(ssrc[csr_src[p]] + sd) - m);
    #pragma unroll
    for (int o = 32; o; o >>= 1) dsum += __shfl_xor(dsum, o);
    float inv = 1.f / dsum;
    // pass 3: weighted accumulate; lane owns feature dim(s)
    float wself = expf(eself - m) * inv;
    float acc0 = wself * h[(size_t)wid * F + lane];
    float acc1 = (F > 64) ? wself * h[(size_t)wid * F + 64 + lane] : 0.f;
    for (int p = beg; p < end; ++p) {
        int s = csr_src[p];
        float w = expf(lrelu(ssrc[s] + sd) - m) * inv;
        acc0 += w * h[(size_t)s * F + lane];
        if (F > 64) acc1 += w * h[(size_t)s * F + 64 + lane];
    }
    float r0 = acc0 + bias[lane];
    xout[(size_t)wid * F + lane] = r0 > 0.f ? r0 : 0.f;
    if (F > 64) {
        float r1 = acc1 + bias[64 + lane];
        xout[(size_t)wid * F + 64 + lane] = r1 > 0.f ? r1 : 0.f;
    }
}

// ---------------- mean pool ----------------
__global__ void pool_accum(const float* __restrict__ x, const int* __restrict__ batch,
                           float* __restrict__ sums, int* __restrict__ cnt, int n) {
    int wid = (blockIdx.x * blockDim.x + threadIdx.x) >> 6;
    int lane = threadIdx.x & 63;
    if (wid >= n) return;
    int b = batch[wid];
    atomicAdd(&sums[b * 64 + lane], x[(size_t)wid * 64 + lane]);
    if (lane == 0) atomicAdd(&cnt[b], 1);
}

__global__ void pool_div(float* __restrict__ sums, const int* __restrict__ cnt, int g) {
    int i = blockIdx.x * blockDim.x + threadIdx.x;
    if (i >= g * 64) return;
    float c = (float)cnt[i >> 6];
    c = c > 1.f ? c : 1.f;
    sums[i] /= c;
}

// ---------------- head: sigmoid((xs+xt)@Wlin + blin) ----------------
__global__ void head_kernel(const float* __restrict__ xs, const float* __restrict__ xt,
                            const float* __restrict__ Wlin, const float* __restrict__ blin,
                            float* __restrict__ out) {
    __shared__ float z[64];
    int g = blockIdx.x;
    int tid = threadIdx.x;
    if (tid < 64) z[tid] = xs[g * 64 + tid] + xt[g * 64 + tid];
    __syncthreads();
    for (int c = tid; c < Lout; c += blockDim.x) {
        float acc = blin[c];
        #pragma unroll
        for (int k = 0; k < 64; k++) acc += z[k] * Wlin[k * Lout + c];
        out[(size_t)g * Lout + c] = 1.f / (1.f + expf(-acc));
    }
}

extern "C" void kernel_launch(void* const* d_in, const int* in_sizes, int n_in,
                              void* d_out, int out_size, void* d_ws, size_t ws_size,
                              hipStream_t stream) {
    // arena in d_ws
    size_t off = 0;
    auto alloc = [&](size_t bytes) -> void* {
        void* p = (char*)d_ws + off;
        off += (bytes + 255) & ~(size_t)255;
        return p;
    };
    float* hbuf    = (float*)alloc((size_t)Nn * 128 * 4);
    float* xbuf    = (float*)alloc((size_t)Nn * 128 * 4);
    float* ssrc    = (float*)alloc((size_t)Nn * 4);
    float* sdst    = (float*)alloc((size_t)Nn * 4);
    int*   row_ptr = (int*)alloc((size_t)(Nn + 1) * 4);
    int*   cur     = (int*)alloc((size_t)Nn * 4);
    int*   csr     = (int*)alloc((size_t)Ecnt * 4);
    float* xs_mean = (float*)alloc((size_t)Gn * 64 * 4);
    float* xt_mean = (float*)alloc((size_t)Gn * 64 * 4);
    int*   cnt     = (int*)alloc((size_t)Gn * 4);

    const int EB = (Ecnt + 255) / 256;           // edge-parallel blocks
    const int NW = (Nn * 64 + 255) / 256;        // wave-per-node blocks

    auto run_side = [&](const float* x, const int* edges, const int* batch,
                        const float* W1, const float* a1s, const float* a1d, const float* b1,
                        const float* W2, const float* a2s, const float* a2d, const float* b2,
                        float* pooled) {
        const int* src = edges;
        const int* dst = edges + Ecnt;
        // CSR by dst
        hipMemsetAsync(cur, 0, (size_t)Nn * 4, stream);
        count_kernel<<<EB, 256, 0, stream>>>(dst, cur, Ecnt);
        scan_kernel<<<1, 1024, 0, stream>>>(cur, row_ptr, Nn);
        hipMemsetAsync(cur, 0, (size_t)Nn * 4, stream);
        fill_kernel<<<EB, 256, 0, stream>>>(src, dst, row_ptr, cur, csr, Ecnt);
        // layer 1: 256 -> 128
        {
            dim3 grid((Nn + 63) / 64, 128 / 64);
            sgemm64<<<grid, 256, 0, stream>>>(x, W1, hbuf, Nn, Din, 128);
        }
        scores_kernel<<<NW, 256, 0, stream>>>(hbuf, a1s, a1d, ssrc, sdst, Nn, 128);
        attn_agg_kernel<<<NW, 256, 0, stream>>>(hbuf, ssrc, sdst, row_ptr, csr, b1, xbuf, Nn, 128);
        // layer 2: 128 -> 64
        {
            dim3 grid((Nn + 63) / 64, 1);
            sgemm64<<<grid, 256, 0, stream>>>(xbuf, W2, hbuf, Nn, 128, 64);
        }
        scores_kernel<<<NW, 256, 0, stream>>>(hbuf, a2s, a2d, ssrc, sdst, Nn, 64);
        attn_agg_kernel<<<NW, 256, 0, stream>>>(hbuf, ssrc, sdst, row_ptr, csr, b2, xbuf, Nn, 64);
        // mean pool
        hipMemsetAsync(pooled, 0, (size_t)Gn * 64 * 4, stream);
        hipMemsetAsync(cnt, 0, (size_t)Gn * 4, stream);
        pool_accum<<<NW, 256, 0, stream>>>(xbuf, batch, pooled, cnt, Nn);
        pool_div<<<(Gn * 64 + 255) / 256, 256, 0, stream>>>(pooled, cnt, Gn);
    };

    const float* x_s  = (const float*)d_in[0];
    const float* x_t  = (const float*)d_in[1];
    const int* ei_s   = (const int*)d_in[2];
    const int* ei_t   = (const int*)d_in[3];
    const int* bat_s  = (const int*)d_in[4];
    const int* bat_t  = (const int*)d_in[5];

    run_side(x_s, ei_s, bat_s,
             (const float*)d_in[6], (const float*)d_in[7], (const float*)d_in[8], (const float*)d_in[9],
             (const float*)d_in[10], (const float*)d_in[11], (const float*)d_in[12], (const float*)d_in[13],
             xs_mean);
    run_side(x_t, ei_t, bat_t,
             (const float*)d_in[14], (const float*)d_in[15], (const float*)d_in[16], (const float*)d_in[17],
             (const float*)d_in[18], (const float*)d_in[19], (const float*)d_in[20], (const float*)d_in[21],
             xt_mean);

    head_kernel<<<Gn, 256, 0, stream>>>(xs_mean, xt_mean,
                                        (const float*)d_in[22], (const float*)d_in[23],
                                        (float*)d_out);
}

// Round 2
// 1043.300 us; speedup vs baseline: 1.5091x; 1.5091x over previous
//
#include <hip/hip_runtime.h>
#include <hip/hip_bf16.h>
#include <math.h>

constexpr int Nn   = 50000;
constexpr int Ecnt = 800000;
constexpr int Gn   = 128;
constexpr int Din  = 256;
constexpr int Lout = 1024;

__device__ __forceinline__ float lrelu(float x) { return x >= 0.f ? x : 0.2f * x; }

// ---------------- CSR build ----------------
__global__ void count_kernel(const int* __restrict__ dst, int* __restrict__ cnt, int n) {
    int i = blockIdx.x * blockDim.x + threadIdx.x;
    if (i < n) atomicAdd(&cnt[dst[i]], 1);
}

// hierarchical scan: (1) per-block 1024-elem scan, (2) scan of 49 block sums, (3) add offsets
__global__ __launch_bounds__(1024) void scan1(const int* __restrict__ cnt,
                                              int* __restrict__ excl, int* __restrict__ bsum, int n) {
    __shared__ int buf[1024];
    int t = threadIdx.x;
    int i = blockIdx.x * 1024 + t;
    int v = (i < n) ? cnt[i] : 0;
    buf[t] = v;
    __syncthreads();
    for (int off = 1; off < 1024; off <<= 1) {
        int x = (t >= off) ? buf[t - off] : 0;
        __syncthreads();
        buf[t] += x;
        __syncthreads();
    }
    if (i < n) excl[i] = buf[t] - v;
    if (t == 1023) bsum[blockIdx.x] = buf[1023];
}

__global__ void scan2(int* __restrict__ bsum, int nb) {   // one wave, nb<=64
    int lane = threadIdx.x;
    int v = (lane < nb) ? bsum[lane] : 0;
    #pragma unroll
    for (int off = 1; off < 64; off <<= 1) {
        int y = __shfl_up(v, off);
        if (lane >= off) v += y;
    }
    if (lane < nb) bsum[lane] = v;   // inclusive
}

__global__ void scan3(int* __restrict__ row_ptr, const int* __restrict__ bsum, int n, int nb) {
    int i = blockIdx.x * blockDim.x + threadIdx.x;
    if (i < n) {
        int b = i >> 10;
        if (b > 0) row_ptr[i] += bsum[b - 1];
    }
    if (i == 0) row_ptr[n] = bsum[nb - 1];
}

__global__ void fill_kernel(const int* __restrict__ src, const int* __restrict__ dst,
                            const int* __restrict__ row_ptr, int* __restrict__ cursor,
                            int* __restrict__ csr_src, int n) {
    int i = blockIdx.x * blockDim.x + threadIdx.x;
    if (i >= n) return;
    int d = dst[i];
    int pos = row_ptr[d] + atomicAdd(&cursor[d], 1);
    csr_src[pos] = src[i];
}

// ---------------- SGEMM: C[M,Nc] = A[M,K] @ B[K,Nc] ----------------
__global__ __launch_bounds__(256) void sgemm64(const float* __restrict__ A,
                                               const float* __restrict__ B,
                                               float* __restrict__ C,
                                               int M, int K, int Nc) {
    __shared__ float As[16][65];  // [k][m]
    __shared__ float Bs[16][65];  // [k][n]
    int tid = threadIdx.x;
    int bm = blockIdx.x * 64;
    int bn = blockIdx.y * 64;
    int tx = tid & 15, ty = tid >> 4;
    float acc[4][4] = {};
    for (int k0 = 0; k0 < K; k0 += 16) {
        #pragma unroll
        for (int i = 0; i < 4; i++) {
            int idx = tid + i * 256;
            int m = idx >> 4, kk = idx & 15;
            As[kk][m] = (bm + m < M) ? A[(size_t)(bm + m) * K + k0 + kk] : 0.f;
            int kb = idx >> 6, nb = idx & 63;
            Bs[kb][nb] = B[(size_t)(k0 + kb) * Nc + bn + nb];
        }
        __syncthreads();
        #pragma unroll
        for (int kk = 0; kk < 16; kk++) {
            float a[4], b[4];
            #pragma unroll
            for (int i = 0; i < 4; i++) a[i] = As[kk][ty * 4 + i];
            #pragma unroll
            for (int j = 0; j < 4; j++) b[j] = Bs[kk][tx * 4 + j];
            #pragma unroll
            for (int i = 0; i < 4; i++)
                #pragma unroll
                for (int j = 0; j < 4; j++) acc[i][j] += a[i] * b[j];
        }
        __syncthreads();
    }
    #pragma unroll
    for (int i = 0; i < 4; i++) {
        int m = bm + ty * 4 + i;
        if (m >= M) continue;
        #pragma unroll
        for (int j = 0; j < 4; j++)
            C[(size_t)m * Nc + bn + tx * 4 + j] = acc[i][j];
    }
}

// ---------------- per-node scores: ssrc = h@a_src, sdst = h@a_dst ----------------
__global__ void scores_kernel(const float* __restrict__ h, const float* __restrict__ a_src,
                              const float* __restrict__ a_dst, float* __restrict__ ssrc,
                              float* __restrict__ sdst, int n, int F) {
    int wid = (blockIdx.x * blockDim.x + threadIdx.x) >> 6;
    int lane = threadIdx.x & 63;
    if (wid >= n) return;
    float vs = 0.f, vd = 0.f;
    for (int f = lane; f < F; f += 64) {
        float hv = h[(size_t)wid * F + f];
        vs += hv * a_src[f];
        vd += hv * a_dst[f];
    }
    #pragma unroll
    for (int o = 32; o; o >>= 1) { vs += __shfl_xor(vs, o); vd += __shfl_xor(vd, o); }
    if (lane == 0) { ssrc[wid] = vs; sdst[wid] = vd; }
}

// ---------------- attention softmax + aggregation (one wave per dst node) ----------------
__global__ void attn_agg_kernel(const float* __restrict__ h, const float* __restrict__ ssrc,
                                const float* __restrict__ sdst,
                                const int* __restrict__ row_ptr, const int* __restrict__ csr_src,
                                const float* __restrict__ bias, float* __restrict__ xout,
                                int n, int F) {
    int wid = (blockIdx.x * blockDim.x + threadIdx.x) >> 6;
    int lane = threadIdx.x & 63;
    if (wid >= n) return;
    int beg = row_ptr[wid], end = row_ptr[wid + 1];
    float sd = sdst[wid];
    float eself = lrelu(ssrc[wid] + sd);
    // pass 1: max
    float m = eself;
    for (int p = beg + lane; p < end; p += 64)
        m = fmaxf(m, lrelu(ssrc[csr_src[p]] + sd));
    #pragma unroll
    for (int o = 32; o; o >>= 1) m = fmaxf(m, __shfl_xor(m, o));
    // pass 2: denom
    float dsum = (lane == 0) ? expf(eself - m) : 0.f;
    for (int p = beg + lane; p < end; p += 64)
        dsum += expf(lrelu(ssrc[csr_src[p]] + sd) - m);
    #pragma unroll
    for (int o = 32; o; o >>= 1) dsum += __shfl_xor(dsum, o);
    float inv = 1.f / dsum;
    // pass 3: weighted accumulate; lane owns feature dim(s)
    float wself = expf(eself - m) * inv;
    float acc0 = wself * h[(size_t)wid * F + lane];
    float acc1 = (F > 64) ? wself * h[(size_t)wid * F + 64 + lane] : 0.f;
    for (int p = beg; p < end; ++p) {
        int s = csr_src[p];
        float w = expf(lrelu(ssrc[s] + sd) - m) * inv;
        acc0 += w * h[(size_t)s * F + lane];
        if (F > 64) acc1 += w * h[(size_t)s * F + 64 + lane];
    }
    float r0 = acc0 + bias[lane];
    xout[(size_t)wid * F + lane] = r0 > 0.f ? r0 : 0.f;
    if (F > 64) {
        float r1 = acc1 + bias[64 + lane];
        xout[(size_t)wid * F + 64 + lane] = r1 > 0.f ? r1 : 0.f;
    }
}

// ---------------- mean pool: batch is SORTED -> segment sum per graph, no atomics ----------------
__global__ __launch_bounds__(256) void pool_kernel(const float* __restrict__ x,
                                                   const int* __restrict__ batch,
                                                   float* __restrict__ pooled, int n) {
    int g = blockIdx.x;
    int tid = threadIdx.x;
    int wave = tid >> 6, lane = tid & 63;
    __shared__ int s_lo, s_hi;
    if (tid == 0) {
        int lo = 0, hi = n;
        while (lo < hi) { int mid = (lo + hi) >> 1; if (batch[mid] < g) lo = mid + 1; else hi = mid; }
        s_lo = lo;
        int lo2 = lo, hi2 = n;
        while (lo2 < hi2) { int mid = (lo2 + hi2) >> 1; if (batch[mid] < g + 1) lo2 = mid + 1; else hi2 = mid; }
        s_hi = lo2;
    }
    __syncthreads();
    int lo = s_lo, hi = s_hi;
    float acc = 0.f;
    for (int i = lo + wave; i < hi; i += 4)
        acc += x[(size_t)i * 64 + lane];
    __shared__ float red[4][64];
    red[wave][lane] = acc;
    __syncthreads();
    if (wave == 0) {
        float s = red[0][lane] + red[1][lane] + red[2][lane] + red[3][lane];
        float c = (float)(hi - lo);
        pooled[g * 64 + lane] = s / fmaxf(c, 1.f);
    }
}

// ---------------- head: sigmoid((xs+xt)@Wlin + blin) ----------------
__global__ void head_kernel(const float* __restrict__ xs, const float* __restrict__ xt,
                            const float* __restrict__ Wlin, const float* __restrict__ blin,
                            float* __restrict__ out) {
    __shared__ float z[64];
    int g = blockIdx.x;
    int tid = threadIdx.x;
    if (tid < 64) z[tid] = xs[g * 64 + tid] + xt[g * 64 + tid];
    __syncthreads();
    for (int c = tid; c < Lout; c += blockDim.x) {
        float acc = blin[c];
        #pragma unroll
        for (int k = 0; k < 64; k++) acc += z[k] * Wlin[k * Lout + c];
        out[(size_t)g * Lout + c] = 1.f / (1.f + expf(-acc));
    }
}

extern "C" void kernel_launch(void* const* d_in, const int* in_sizes, int n_in,
                              void* d_out, int out_size, void* d_ws, size_t ws_size,
                              hipStream_t stream) {
    size_t off = 0;
    auto alloc = [&](size_t bytes) -> void* {
        void* p = (char*)d_ws + off;
        off += (bytes + 255) & ~(size_t)255;
        return p;
    };
    float* hbuf    = (float*)alloc((size_t)Nn * 128 * 4);
    float* xbuf    = (float*)alloc((size_t)Nn * 128 * 4);
    float* ssrc    = (float*)alloc((size_t)Nn * 4);
    float* sdst    = (float*)alloc((size_t)Nn * 4);
    int*   row_ptr = (int*)alloc((size_t)(Nn + 1) * 4);
    int*   cur     = (int*)alloc((size_t)Nn * 4);
    int*   csr     = (int*)alloc((size_t)Ecnt * 4);
    int*   bsum    = (int*)alloc(64 * 4);
    float* xs_mean = (float*)alloc((size_t)Gn * 64 * 4);
    float* xt_mean = (float*)alloc((size_t)Gn * 64 * 4);

    const int EB = (Ecnt + 255) / 256;           // edge-parallel blocks
    const int NW = (Nn * 64 + 255) / 256;        // wave-per-node blocks
    const int NB = (Nn + 1023) / 1024;           // scan blocks (49)

    auto run_side = [&](const float* x, const int* edges, const int* batch,
                        const float* W1, const float* a1s, const float* a1d, const float* b1,
                        const float* W2, const float* a2s, const float* a2d, const float* b2,
                        float* pooled) {
        const int* src = edges;
        const int* dst = edges + Ecnt;
        // CSR by dst
        hipMemsetAsync(cur, 0, (size_t)Nn * 4, stream);
        count_kernel<<<EB, 256, 0, stream>>>(dst, cur, Ecnt);
        scan1<<<NB, 1024, 0, stream>>>(cur, row_ptr, bsum, Nn);
        scan2<<<1, 64, 0, stream>>>(bsum, NB);
        scan3<<<(Nn + 255) / 256, 256, 0, stream>>>(row_ptr, bsum, Nn, NB);
        hipMemsetAsync(cur, 0, (size_t)Nn * 4, stream);
        fill_kernel<<<EB, 256, 0, stream>>>(src, dst, row_ptr, cur, csr, Ecnt);
        // layer 1: 256 -> 128
        {
            dim3 grid((Nn + 63) / 64, 128 / 64);
            sgemm64<<<grid, 256, 0, stream>>>(x, W1, hbuf, Nn, Din, 128);
        }
        scores_kernel<<<NW, 256, 0, stream>>>(hbuf, a1s, a1d, ssrc, sdst, Nn, 128);
        attn_agg_kernel<<<NW, 256, 0, stream>>>(hbuf, ssrc, sdst, row_ptr, csr, b1, xbuf, Nn, 128);
        // layer 2: 128 -> 64
        {
            dim3 grid((Nn + 63) / 64, 1);
            sgemm64<<<grid, 256, 0, stream>>>(xbuf, W2, hbuf, Nn, 128, 64);
        }
        scores_kernel<<<NW, 256, 0, stream>>>(hbuf, a2s, a2d, ssrc, sdst, Nn, 64);
        attn_agg_kernel<<<NW, 256, 0, stream>>>(hbuf, ssrc, sdst, row_ptr, csr, b2, xbuf, Nn, 64);
        // mean pool (sorted batch -> segment sum)
        pool_kernel<<<Gn, 256, 0, stream>>>(xbuf, batch, pooled, Nn);
    };

    const float* x_s  = (const float*)d_in[0];
    const float* x_t  = (const float*)d_in[1];
    const int* ei_s   = (const int*)d_in[2];
    const int* ei_t   = (const int*)d_in[3];
    const int* bat_s  = (const int*)d_in[4];
    const int* bat_t  = (const int*)d_in[5];

    run_side(x_s, ei_s, bat_s,
             (const float*)d_in[6], (const float*)d_in[7], (const float*)d_in[8], (const float*)d_in[9],
             (const float*)d_in[10], (const float*)d_in[11], (const float*)d_in[12], (const float*)d_in[13],
             xs_mean);
    run_side(x_t, ei_t, bat_t,
             (const float*)d_in[14], (const float*)d_in[15], (const float*)d_in[16], (const float*)d_in[17],
             (const float*)d_in[18], (const float*)d_in[19], (const float*)d_in[20], (const float*)d_in[21],
             xt_mean);

    head_kernel<<<Gn, 256, 0, stream>>>(xs_mean, xt_mean,
                                        (const float*)d_in[22], (const float*)d_in[23],
                                        (float*)d_out);
}

// Round 3
// 817.808 us; speedup vs baseline: 1.9252x; 1.2757x over previous
//
#include <hip/hip_runtime.h>
#include <hip/hip_bf16.h>
#include <math.h>

constexpr int Nn   = 50000;
constexpr int Ecnt = 800000;
constexpr int Gn   = 128;
constexpr int Din  = 256;
constexpr int Lout = 1024;

__device__ __forceinline__ float lrelu(float x) { return x >= 0.f ? x : 0.2f * x; }

// bf16x2 packed in uint32 helpers (fp32 math everywhere, bf16 storage)
__device__ __forceinline__ float bflo(uint32_t v) { return __uint_as_float(v << 16); }
__device__ __forceinline__ float bfhi(uint32_t v) { return __uint_as_float(v & 0xffff0000u); }
__device__ __forceinline__ uint32_t f2bf(float f) {
    uint32_t x = __float_as_uint(f);
    return (x + 0x7fffu + ((x >> 16) & 1u)) >> 16;
}
__device__ __forceinline__ uint32_t packbf(float lo, float hi) {
    return f2bf(lo) | (f2bf(hi) << 16);
}

// ---------------- CSR build ----------------
__global__ void count_kernel(const int* __restrict__ dst, int* __restrict__ cnt, int n) {
    int i = blockIdx.x * blockDim.x + threadIdx.x;
    if (i < n) atomicAdd(&cnt[dst[i]], 1);
}

__global__ __launch_bounds__(1024) void scan1(const int* __restrict__ cnt,
                                              int* __restrict__ excl, int* __restrict__ bsum, int n) {
    __shared__ int buf[1024];
    int t = threadIdx.x;
    int i = blockIdx.x * 1024 + t;
    int v = (i < n) ? cnt[i] : 0;
    buf[t] = v;
    __syncthreads();
    for (int off = 1; off < 1024; off <<= 1) {
        int x = (t >= off) ? buf[t - off] : 0;
        __syncthreads();
        buf[t] += x;
        __syncthreads();
    }
    if (i < n) excl[i] = buf[t] - v;
    if (t == 1023) bsum[blockIdx.x] = buf[1023];
}

__global__ void scan2(int* __restrict__ bsum, int nb) {
    int lane = threadIdx.x;
    int v = (lane < nb) ? bsum[lane] : 0;
    #pragma unroll
    for (int off = 1; off < 64; off <<= 1) {
        int y = __shfl_up(v, off);
        if (lane >= off) v += y;
    }
    if (lane < nb) bsum[lane] = v;
}

__global__ void scan3(int* __restrict__ row_ptr, const int* __restrict__ bsum, int n, int nb) {
    int i = blockIdx.x * blockDim.x + threadIdx.x;
    if (i < n) {
        int b = i >> 10;
        if (b > 0) row_ptr[i] += bsum[b - 1];
    }
    if (i == 0) row_ptr[n] = bsum[nb - 1];
}

__global__ void fill_kernel(const int* __restrict__ src, const int* __restrict__ dst,
                            const int* __restrict__ row_ptr, int* __restrict__ cursor,
                            int* __restrict__ csr_src, int n) {
    int i = blockIdx.x * blockDim.x + threadIdx.x;
    if (i >= n) return;
    int d = dst[i];
    int pos = row_ptr[d] + atomicAdd(&cursor[d], 1);
    csr_src[pos] = src[i];
}

// ---------------- SGEMM: C[M,Nc](bf16) = A[M,K] @ B[K,Nc], A fp32 or bf16 ----------------
template<bool BF16A>
__global__ __launch_bounds__(256) void sgemm64(const void* __restrict__ Av,
                                               const float* __restrict__ B,
                                               uint32_t* __restrict__ C,
                                               int M, int K, int Nc) {
    __shared__ float As[16][65];  // [k][m]
    __shared__ float Bs[16][65];  // [k][n]
    int tid = threadIdx.x;
    int bm = blockIdx.x * 64;
    int bn = blockIdx.y * 64;
    int tx = tid & 15, ty = tid >> 4;
    float acc[4][4] = {};
    for (int k0 = 0; k0 < K; k0 += 16) {
        if constexpr (BF16A) {
            const uint32_t* A = (const uint32_t*)Av;   // [M, K/2] packed
            #pragma unroll
            for (int i = 0; i < 2; i++) {
                int idx = tid + i * 256;               // 512 uints
                int mm = idx >> 3, ku = idx & 7;
                uint32_t v = (bm + mm < M) ? A[(size_t)(bm + mm) * (K >> 1) + (k0 >> 1) + ku] : 0u;
                As[2 * ku][mm]     = bflo(v);
                As[2 * ku + 1][mm] = bfhi(v);
            }
            #pragma unroll
            for (int i = 0; i < 4; i++) {
                int idx = tid + i * 256;
                int kb = idx >> 6, nb = idx & 63;
                Bs[kb][nb] = B[(size_t)(k0 + kb) * Nc + bn + nb];
            }
        } else {
            const float* A = (const float*)Av;
            #pragma unroll
            for (int i = 0; i < 4; i++) {
                int idx = tid + i * 256;
                int m = idx >> 4, kk = idx & 15;
                As[kk][m] = (bm + m < M) ? A[(size_t)(bm + m) * K + k0 + kk] : 0.f;
                int kb = idx >> 6, nb = idx & 63;
                Bs[kb][nb] = B[(size_t)(k0 + kb) * Nc + bn + nb];
            }
        }
        __syncthreads();
        #pragma unroll
        for (int kk = 0; kk < 16; kk++) {
            float a[4], b[4];
            #pragma unroll
            for (int i = 0; i < 4; i++) a[i] = As[kk][ty * 4 + i];
            #pragma unroll
            for (int j = 0; j < 4; j++) b[j] = Bs[kk][tx * 4 + j];
            #pragma unroll
            for (int i = 0; i < 4; i++)
                #pragma unroll
                for (int j = 0; j < 4; j++) acc[i][j] += a[i] * b[j];
        }
        __syncthreads();
    }
    #pragma unroll
    for (int i = 0; i < 4; i++) {
        int m = bm + ty * 4 + i;
        if (m >= M) continue;
        uint2 u;
        u.x = packbf(acc[i][0], acc[i][1]);
        u.y = packbf(acc[i][2], acc[i][3]);
        *reinterpret_cast<uint2*>(C + (size_t)m * (Nc >> 1) + ((bn + tx * 4) >> 1)) = u;
    }
}

// ---------------- per-node scores from bf16 h ----------------
template<int F>
__global__ void scores_kernel(const uint32_t* __restrict__ h, const float* __restrict__ a_src,
                              const float* __restrict__ a_dst, float* __restrict__ ssrc,
                              float* __restrict__ sdst, int n) {
    int wid = (blockIdx.x * blockDim.x + threadIdx.x) >> 6;
    int lane = threadIdx.x & 63;
    if (wid >= n) return;
    constexpr int RU = F / 2;
    float vs = 0.f, vd = 0.f;
    if (lane < RU) {
        uint32_t v = h[(size_t)wid * RU + lane];
        float lo = bflo(v), hi = bfhi(v);
        vs = lo * a_src[2 * lane] + hi * a_src[2 * lane + 1];
        vd = lo * a_dst[2 * lane] + hi * a_dst[2 * lane + 1];
    }
    #pragma unroll
    for (int o = 32; o; o >>= 1) { vs += __shfl_xor(vs, o); vd += __shfl_xor(vd, o); }
    if (lane == 0) { ssrc[wid] = vs; sdst[wid] = vd; }
}

// ---------------- attention softmax + aggregation (one wave per dst node) ----------------
template<int F>
__global__ __launch_bounds__(256) void attn_agg(const uint32_t* __restrict__ h,
        const float* __restrict__ ssrc, const float* __restrict__ sdst,
        const int* __restrict__ row_ptr, const int* __restrict__ csr_src,
        const float* __restrict__ bias, uint32_t* __restrict__ xout, int n) {
    int wid = (blockIdx.x * blockDim.x + threadIdx.x) >> 6;
    int lane = threadIdx.x & 63;
    if (wid >= n) return;
    int beg = row_ptr[wid], end = row_ptr[wid + 1];
    float sd = sdst[wid];
    float eself = lrelu(ssrc[wid] + sd);
    // pass 1: max (lane-parallel over edges)
    float m = eself;
    for (int p = beg + lane; p < end; p += 64)
        m = fmaxf(m, lrelu(ssrc[csr_src[p]] + sd));
    #pragma unroll
    for (int o = 32; o; o >>= 1) m = fmaxf(m, __shfl_xor(m, o));
    // pass 2: denom
    float dsum = (lane == 0) ? expf(eself - m) : 0.f;
    for (int p = beg + lane; p < end; p += 64)
        dsum += expf(lrelu(ssrc[csr_src[p]] + sd) - m);
    #pragma unroll
    for (int o = 32; o; o >>= 1) dsum += __shfl_xor(dsum, o);
    float inv = 1.f / dsum;
    float wself = expf(eself - m) * inv;

    constexpr int RU = F / 2;
    if constexpr (F == 128) {
        // lane owns features (2*lane, 2*lane+1); 2 edges in flight per iter
        uint32_t v = h[(size_t)wid * RU + lane];
        float acc0 = wself * bflo(v), acc1 = wself * bfhi(v);
        int p = beg;
        for (; p + 1 < end; p += 2) {
            int s0 = csr_src[p], s1 = csr_src[p + 1];
            uint32_t v0 = h[(size_t)s0 * RU + lane];
            uint32_t v1 = h[(size_t)s1 * RU + lane];
            float w0 = expf(lrelu(ssrc[s0] + sd) - m) * inv;
            float w1 = expf(lrelu(ssrc[s1] + sd) - m) * inv;
            acc0 += w0 * bflo(v0) + w1 * bflo(v1);
            acc1 += w0 * bfhi(v0) + w1 * bfhi(v1);
        }
        if (p < end) {
            int s0 = csr_src[p];
            uint32_t v0 = h[(size_t)s0 * RU + lane];
            float w0 = expf(lrelu(ssrc[s0] + sd) - m) * inv;
            acc0 += w0 * bflo(v0);
            acc1 += w0 * bfhi(v0);
        }
        float r0 = fmaxf(acc0 + bias[2 * lane], 0.f);
        float r1 = fmaxf(acc1 + bias[2 * lane + 1], 0.f);
        xout[(size_t)wid * RU + lane] = packbf(r0, r1);
    } else {
        // F=64: half-waves process alternating edges; lane&31 owns a dword (2 feats)
        int half = lane >> 5, i = lane & 31;
        float acc0 = 0.f, acc1 = 0.f;
        if (half == 0) {
            uint32_t v = h[(size_t)wid * RU + i];
            acc0 = wself * bflo(v);
            acc1 = wself * bfhi(v);
        }
        for (int p = beg + half; p < end; p += 2) {
            int s0 = csr_src[p];
            uint32_t v = h[(size_t)s0 * RU + i];
            float w = expf(lrelu(ssrc[s0] + sd) - m) * inv;
            acc0 += w * bflo(v);
            acc1 += w * bfhi(v);
        }
        acc0 += __shfl_xor(acc0, 32);
        acc1 += __shfl_xor(acc1, 32);
        if (half == 0) {
            float r0 = fmaxf(acc0 + bias[2 * i], 0.f);
            float r1 = fmaxf(acc1 + bias[2 * i + 1], 0.f);
            xout[(size_t)wid * RU + i] = packbf(r0, r1);
        }
    }
}

// ---------------- mean pool (sorted batch), bf16 input ----------------
__global__ __launch_bounds__(256) void pool_kernel(const uint32_t* __restrict__ x,
                                                   const int* __restrict__ batch,
                                                   float* __restrict__ pooled, int n) {
    int g = blockIdx.x;
    int tid = threadIdx.x;
    __shared__ int s_lo, s_hi;
    if (tid == 0) {
        int lo = 0, hi = n;
        while (lo < hi) { int mid = (lo + hi) >> 1; if (batch[mid] < g) lo = mid + 1; else hi = mid; }
        s_lo = lo;
        int lo2 = lo, hi2 = n;
        while (lo2 < hi2) { int mid = (lo2 + hi2) >> 1; if (batch[mid] < g + 1) lo2 = mid + 1; else hi2 = mid; }
        s_hi = lo2;
    }
    __syncthreads();
    int lo = s_lo, hi = s_hi;
    int grp = tid >> 5, col = tid & 31;      // 8 row-groups x 32 dword-cols
    float a0 = 0.f, a1 = 0.f;
    for (int i = lo + grp; i < hi; i += 8) {
        uint32_t v = x[(size_t)i * 32 + col];
        a0 += bflo(v);
        a1 += bfhi(v);
    }
    __shared__ float red0[8][32], red1[8][32];
    red0[grp][col] = a0;
    red1[grp][col] = a1;
    __syncthreads();
    if (tid < 32) {
        float s0 = 0.f, s1 = 0.f;
        #pragma unroll
        for (int r = 0; r < 8; r++) { s0 += red0[r][tid]; s1 += red1[r][tid]; }
        float c = fmaxf((float)(hi - lo), 1.f);
        pooled[g * 64 + 2 * tid]     = s0 / c;
        pooled[g * 64 + 2 * tid + 1] = s1 / c;
    }
}

// ---------------- head: sigmoid((xs+xt)@Wlin + blin) ----------------
__global__ void head_kernel(const float* __restrict__ xs, const float* __restrict__ xt,
                            const float* __restrict__ Wlin, const float* __restrict__ blin,
                            float* __restrict__ out) {
    __shared__ float z[64];
    int g = blockIdx.x;
    int tid = threadIdx.x;
    if (tid < 64) z[tid] = xs[g * 64 + tid] + xt[g * 64 + tid];
    __syncthreads();
    for (int c = tid; c < Lout; c += blockDim.x) {
        float acc = blin[c];
        #pragma unroll
        for (int k = 0; k < 64; k++) acc += z[k] * Wlin[k * Lout + c];
        out[(size_t)g * Lout + c] = 1.f / (1.f + expf(-acc));
    }
}

extern "C" void kernel_launch(void* const* d_in, const int* in_sizes, int n_in,
                              void* d_out, int out_size, void* d_ws, size_t ws_size,
                              hipStream_t stream) {
    size_t off = 0;
    auto alloc = [&](size_t bytes) -> void* {
        void* p = (char*)d_ws + off;
        off += (bytes + 255) & ~(size_t)255;
        return p;
    };
    uint32_t* hbuf  = (uint32_t*)alloc((size_t)Nn * 64 * 4);   // bf16x2, up to F=128
    uint32_t* xbuf  = (uint32_t*)alloc((size_t)Nn * 64 * 4);
    float* ssrc     = (float*)alloc((size_t)Nn * 4);
    float* sdst     = (float*)alloc((size_t)Nn * 4);
    int*   row_ptr  = (int*)alloc((size_t)(Nn + 1) * 4);
    int*   cur      = (int*)alloc((size_t)Nn * 4);
    int*   csr      = (int*)alloc((size_t)Ecnt * 4);
    int*   bsum     = (int*)alloc(64 * 4);
    float* xs_mean  = (float*)alloc((size_t)Gn * 64 * 4);
    float* xt_mean  = (float*)alloc((size_t)Gn * 64 * 4);

    const int EB = (Ecnt + 255) / 256;
    const int NW = (Nn * 64 + 255) / 256;
    const int NB = (Nn + 1023) / 1024;

    auto run_side = [&](const float* x, const int* edges, const int* batch,
                        const float* W1, const float* a1s, const float* a1d, const float* b1,
                        const float* W2, const float* a2s, const float* a2d, const float* b2,
                        float* pooled) {
        const int* src = edges;
        const int* dst = edges + Ecnt;
        hipMemsetAsync(cur, 0, (size_t)Nn * 4, stream);
        count_kernel<<<EB, 256, 0, stream>>>(dst, cur, Ecnt);
        scan1<<<NB, 1024, 0, stream>>>(cur, row_ptr, bsum, Nn);
        scan2<<<1, 64, 0, stream>>>(bsum, NB);
        scan3<<<(Nn + 255) / 256, 256, 0, stream>>>(row_ptr, bsum, Nn, NB);
        hipMemsetAsync(cur, 0, (size_t)Nn * 4, stream);
        fill_kernel<<<EB, 256, 0, stream>>>(src, dst, row_ptr, cur, csr, Ecnt);
        // layer 1: 256 -> 128 (fp32 A)
        {
            dim3 grid((Nn + 63) / 64, 2);
            sgemm64<false><<<grid, 256, 0, stream>>>(x, W1, hbuf, Nn, Din, 128);
        }
        scores_kernel<128><<<NW, 256, 0, stream>>>(hbuf, a1s, a1d, ssrc, sdst, Nn);
        attn_agg<128><<<NW, 256, 0, stream>>>(hbuf, ssrc, sdst, row_ptr, csr, b1, xbuf, Nn);
        // layer 2: 128 -> 64 (bf16 A)
        {
            dim3 grid((Nn + 63) / 64, 1);
            sgemm64<true><<<grid, 256, 0, stream>>>(xbuf, W2, hbuf, Nn, 128, 64);
        }
        scores_kernel<64><<<NW, 256, 0, stream>>>(hbuf, a2s, a2d, ssrc, sdst, Nn);
        attn_agg<64><<<NW, 256, 0, stream>>>(hbuf, ssrc, sdst, row_ptr, csr, b2, xbuf, Nn);
        pool_kernel<<<Gn, 256, 0, stream>>>(xbuf, batch, pooled, Nn);
    };

    const float* x_s = (const float*)d_in[0];
    const float* x_t = (const float*)d_in[1];
    const int* ei_s  = (const int*)d_in[2];
    const int* ei_t  = (const int*)d_in[3];
    const int* bat_s = (const int*)d_in[4];
    const int* bat_t = (const int*)d_in[5];

    run_side(x_s, ei_s, bat_s,
             (const float*)d_in[6], (const float*)d_in[7], (const float*)d_in[8], (const float*)d_in[9],
             (const float*)d_in[10], (const float*)d_in[11], (const float*)d_in[12], (const float*)d_in[13],
             xs_mean);
    run_side(x_t, ei_t, bat_t,
             (const float*)d_in[14], (const float*)d_in[15], (const float*)d_in[16], (const float*)d_in[17],
             (const float*)d_in[18], (const float*)d_in[19], (const float*)d_in[20], (const float*)d_in[21],
             xt_mean);

    head_kernel<<<Gn, 256, 0, stream>>>(xs_mean, xt_mean,
                                        (const float*)d_in[22], (const float*)d_in[23],
                                        (float*)d_out);
}

// Round 4
// 650.911 us; speedup vs baseline: 2.4189x; 1.2564x over previous
//
#include <hip/hip_runtime.h>
#include <hip/hip_bf16.h>
#include <math.h>

constexpr int Nn   = 50000;
constexpr int Ecnt = 800000;
constexpr int Gn   = 128;
constexpr int Din  = 256;
constexpr int Lout = 1024;

typedef __attribute__((ext_vector_type(8))) short short8;   // 8 bf16 (4 VGPRs)
typedef __attribute__((ext_vector_type(4))) float f32x4;    // MFMA accumulator

__device__ __forceinline__ float lrelu(float x) { return x >= 0.f ? x : 0.2f * x; }

__device__ __forceinline__ float bflo(uint32_t v) { return __uint_as_float(v << 16); }
__device__ __forceinline__ float bfhi(uint32_t v) { return __uint_as_float(v & 0xffff0000u); }
__device__ __forceinline__ uint32_t f2bf(float f) {
    uint32_t x = __float_as_uint(f);
    return (x + 0x7fffu + ((x >> 16) & 1u)) >> 16;
}
__device__ __forceinline__ uint32_t packbf(float lo, float hi) {
    return f2bf(lo) | (f2bf(hi) << 16);
}

// ---------------- CSR build ----------------
__global__ void count_kernel(const int* __restrict__ dst, int* __restrict__ cnt, int n) {
    int i = blockIdx.x * blockDim.x + threadIdx.x;
    if (i < n) atomicAdd(&cnt[dst[i]], 1);
}

__global__ __launch_bounds__(1024) void scan1(const int* __restrict__ cnt,
                                              int* __restrict__ excl, int* __restrict__ bsum, int n) {
    __shared__ int buf[1024];
    int t = threadIdx.x;
    int i = blockIdx.x * 1024 + t;
    int v = (i < n) ? cnt[i] : 0;
    buf[t] = v;
    __syncthreads();
    for (int off = 1; off < 1024; off <<= 1) {
        int x = (t >= off) ? buf[t - off] : 0;
        __syncthreads();
        buf[t] += x;
        __syncthreads();
    }
    if (i < n) excl[i] = buf[t] - v;
    if (t == 1023) bsum[blockIdx.x] = buf[1023];
}

__global__ void scan2(int* __restrict__ bsum, int nb) {
    int lane = threadIdx.x;
    int v = (lane < nb) ? bsum[lane] : 0;
    #pragma unroll
    for (int off = 1; off < 64; off <<= 1) {
        int y = __shfl_up(v, off);
        if (lane >= off) v += y;
    }
    if (lane < nb) bsum[lane] = v;
}

__global__ void scan3(int* __restrict__ row_ptr, const int* __restrict__ bsum, int n, int nb) {
    int i = blockIdx.x * blockDim.x + threadIdx.x;
    if (i < n) {
        int b = i >> 10;
        if (b > 0) row_ptr[i] += bsum[b - 1];
    }
    if (i == 0) row_ptr[n] = bsum[nb - 1];
}

__global__ void fill_kernel(const int* __restrict__ src, const int* __restrict__ dst,
                            const int* __restrict__ row_ptr, int* __restrict__ cursor,
                            int* __restrict__ csr_src, int n) {
    int i = blockIdx.x * blockDim.x + threadIdx.x;
    if (i >= n) return;
    int d = dst[i];
    int pos = row_ptr[d] + atomicAdd(&cursor[d], 1);
    csr_src[pos] = src[i];
}

// ---------------- MFMA bf16 GEMM: C[M,BN](bf16 packed) = A[M,K] @ B[K,BN] ----------------
// BM=64, BK=64, 4 waves in 2x2; per-wave MFx NF 16x16x32 fragments.
// A: fp32 [M,K] (BF16A=false) or packed bf16 [M,K/2] (BF16A=true). B: fp32 [K,BN].
template<int MF, int NF, int BN, bool BF16A>
__global__ __launch_bounds__(256) void mfma_gemm(const void* __restrict__ Av,
                                                 const float* __restrict__ B,
                                                 uint32_t* __restrict__ C,
                                                 int M, int K) {
    __shared__ uint32_t Al[64][36];   // [row][k-dword], 32 dwords + 4 pad
    __shared__ uint32_t Bl[BN][36];   // [col][k-dword] (B transposed)
    int tid  = threadIdx.x;
    int lane = tid & 63;
    int wid  = tid >> 6;
    int wr = wid >> 1, wc = wid & 1;
    int bm = blockIdx.x * 64;

    f32x4 acc[MF][NF];
    #pragma unroll
    for (int i = 0; i < MF; i++)
        #pragma unroll
        for (int j = 0; j < NF; j++) acc[i][j] = (f32x4){0.f, 0.f, 0.f, 0.f};

    for (int k0 = 0; k0 < K; k0 += 64) {
        // ---- stage A tile: rows bm..bm+63, k k0..k0+63, as bf16 ----
        {
            int row = tid >> 2, q = tid & 3;       // 4 threads per row, 16 k each
            bool valid = (bm + row) < M;
            uint32_t d[8];
            if constexpr (BF16A) {
                const uint32_t* A = (const uint32_t*)Av;  // [M][K/2]
                if (valid) {
                    const uint32_t* p = A + (size_t)(bm + row) * (K >> 1) + (k0 >> 1) + q * 8;
                    uint4 u0 = *(const uint4*)p;
                    uint4 u1 = *(const uint4*)(p + 4);
                    d[0] = u0.x; d[1] = u0.y; d[2] = u0.z; d[3] = u0.w;
                    d[4] = u1.x; d[5] = u1.y; d[6] = u1.z; d[7] = u1.w;
                } else {
                    #pragma unroll
                    for (int i = 0; i < 8; i++) d[i] = 0u;
                }
            } else {
                const float* A = (const float*)Av;
                if (valid) {
                    const float* p = A + (size_t)(bm + row) * K + k0 + q * 16;
                    #pragma unroll
                    for (int i = 0; i < 4; i++) {
                        float4 f = *(const float4*)(p + i * 4);
                        d[2 * i]     = packbf(f.x, f.y);
                        d[2 * i + 1] = packbf(f.z, f.w);
                    }
                } else {
                    #pragma unroll
                    for (int i = 0; i < 8; i++) d[i] = 0u;
                }
            }
            uint4* dst = (uint4*)&Al[row][q * 8];
            dst[0] = make_uint4(d[0], d[1], d[2], d[3]);
            dst[1] = make_uint4(d[4], d[5], d[6], d[7]);
        }
        // ---- stage B tile transposed: Bl[n][kd] = pack(B[k0+2kd][n], B[k0+2kd+1][n]) ----
        {
            constexpr int NITER = BN * 32 / 256;
            constexpr int SH = (BN == 128) ? 7 : 6;
            #pragma unroll
            for (int i = 0; i < NITER; i++) {
                int idx = tid + i * 256;
                int n = idx & (BN - 1);
                int kd = idx >> SH;
                float b0 = B[(size_t)(k0 + 2 * kd) * BN + n];
                float b1 = B[(size_t)(k0 + 2 * kd + 1) * BN + n];
                Bl[n][kd] = packbf(b0, b1);
            }
        }
        __syncthreads();
        // ---- MFMA: 2 K-substeps of 32 ----
        int lr = lane & 15, lk = lane >> 4;
        #pragma unroll
        for (int ks = 0; ks < 2; ks++) {
            short8 af[MF], bf[NF];
            #pragma unroll
            for (int mf = 0; mf < MF; mf++)
                af[mf] = *(const short8*)&Al[wr * (MF * 16) + mf * 16 + lr][ks * 16 + lk * 4];
            #pragma unroll
            for (int nf = 0; nf < NF; nf++)
                bf[nf] = *(const short8*)&Bl[wc * (NF * 16) + nf * 16 + lr][ks * 16 + lk * 4];
            #pragma unroll
            for (int mf = 0; mf < MF; mf++)
                #pragma unroll
                for (int nf = 0; nf < NF; nf++)
                    acc[mf][nf] = __builtin_amdgcn_mfma_f32_16x16x32_bf16(af[mf], bf[nf], acc[mf][nf], 0, 0, 0);
        }
        __syncthreads();
    }
    // ---- epilogue: pack adjacent cols via lane-pair shuffle, store bf16x2 ----
    int lr = lane & 15, lg = lane >> 4;
    #pragma unroll
    for (int mf = 0; mf < MF; mf++) {
        #pragma unroll
        for (int nf = 0; nf < NF; nf++) {
            int col = wc * (NF * 16) + nf * 16 + lr;
            #pragma unroll
            for (int j = 0; j < 4; j++) {
                int row = bm + wr * (MF * 16) + mf * 16 + lg * 4 + j;
                float v = acc[mf][nf][j];
                float w = __shfl_xor(v, 1);
                if (!(lane & 1) && row < M)
                    C[(size_t)row * (BN >> 1) + (col >> 1)] = packbf(v, w);
            }
        }
    }
}

// ---------------- per-node scores from bf16 h ----------------
template<int F>
__global__ void scores_kernel(const uint32_t* __restrict__ h, const float* __restrict__ a_src,
                              const float* __restrict__ a_dst, float* __restrict__ ssrc,
                              float* __restrict__ sdst, int n) {
    int wid = (blockIdx.x * blockDim.x + threadIdx.x) >> 6;
    int lane = threadIdx.x & 63;
    if (wid >= n) return;
    constexpr int RU = F / 2;
    float vs = 0.f, vd = 0.f;
    if (lane < RU) {
        uint32_t v = h[(size_t)wid * RU + lane];
        float lo = bflo(v), hi = bfhi(v);
        vs = lo * a_src[2 * lane] + hi * a_src[2 * lane + 1];
        vd = lo * a_dst[2 * lane] + hi * a_dst[2 * lane + 1];
    }
    #pragma unroll
    for (int o = 32; o; o >>= 1) { vs += __shfl_xor(vs, o); vd += __shfl_xor(vd, o); }
    if (lane == 0) { ssrc[wid] = vs; sdst[wid] = vd; }
}

// ---------------- attention softmax + aggregation (one wave per dst node) ----------------
template<int F>
__global__ __launch_bounds__(256) void attn_agg(const uint32_t* __restrict__ h,
        const float* __restrict__ ssrc, const float* __restrict__ sdst,
        const int* __restrict__ row_ptr, const int* __restrict__ csr_src,
        const float* __restrict__ bias, uint32_t* __restrict__ xout, int n) {
    int wid = (blockIdx.x * blockDim.x + threadIdx.x) >> 6;
    int lane = threadIdx.x & 63;
    if (wid >= n) return;
    int beg = row_ptr[wid], end = row_ptr[wid + 1];
    float sd = sdst[wid];
    float eself = lrelu(ssrc[wid] + sd);
    float m = eself;
    for (int p = beg + lane; p < end; p += 64)
        m = fmaxf(m, lrelu(ssrc[csr_src[p]] + sd));
    #pragma unroll
    for (int o = 32; o; o >>= 1) m = fmaxf(m, __shfl_xor(m, o));
    float dsum = (lane == 0) ? expf(eself - m) : 0.f;
    for (int p = beg + lane; p < end; p += 64)
        dsum += expf(lrelu(ssrc[csr_src[p]] + sd) - m);
    #pragma unroll
    for (int o = 32; o; o >>= 1) dsum += __shfl_xor(dsum, o);
    float inv = 1.f / dsum;
    float wself = expf(eself - m) * inv;

    constexpr int RU = F / 2;
    if constexpr (F == 128) {
        uint32_t v = h[(size_t)wid * RU + lane];
        float acc0 = wself * bflo(v), acc1 = wself * bfhi(v);
        int p = beg;
        for (; p + 1 < end; p += 2) {
            int s0 = csr_src[p], s1 = csr_src[p + 1];
            uint32_t v0 = h[(size_t)s0 * RU + lane];
            uint32_t v1 = h[(size_t)s1 * RU + lane];
            float w0 = expf(lrelu(ssrc[s0] + sd) - m) * inv;
            float w1 = expf(lrelu(ssrc[s1] + sd) - m) * inv;
            acc0 += w0 * bflo(v0) + w1 * bflo(v1);
            acc1 += w0 * bfhi(v0) + w1 * bfhi(v1);
        }
        if (p < end) {
            int s0 = csr_src[p];
            uint32_t v0 = h[(size_t)s0 * RU + lane];
            float w0 = expf(lrelu(ssrc[s0] + sd) - m) * inv;
            acc0 += w0 * bflo(v0);
            acc1 += w0 * bfhi(v0);
        }
        float r0 = fmaxf(acc0 + bias[2 * lane], 0.f);
        float r1 = fmaxf(acc1 + bias[2 * lane + 1], 0.f);
        xout[(size_t)wid * RU + lane] = packbf(r0, r1);
    } else {
        int half = lane >> 5, i = lane & 31;
        float acc0 = 0.f, acc1 = 0.f;
        if (half == 0) {
            uint32_t v = h[(size_t)wid * RU + i];
            acc0 = wself * bflo(v);
            acc1 = wself * bfhi(v);
        }
        for (int p = beg + half; p < end; p += 2) {
            int s0 = csr_src[p];
            uint32_t v = h[(size_t)s0 * RU + i];
            float w = expf(lrelu(ssrc[s0] + sd) - m) * inv;
            acc0 += w * bflo(v);
            acc1 += w * bfhi(v);
        }
        acc0 += __shfl_xor(acc0, 32);
        acc1 += __shfl_xor(acc1, 32);
        if (half == 0) {
            float r0 = fmaxf(acc0 + bias[2 * i], 0.f);
            float r1 = fmaxf(acc1 + bias[2 * i + 1], 0.f);
            xout[(size_t)wid * RU + i] = packbf(r0, r1);
        }
    }
}

// ---------------- mean pool (sorted batch), bf16 input ----------------
__global__ __launch_bounds__(256) void pool_kernel(const uint32_t* __restrict__ x,
                                                   const int* __restrict__ batch,
                                                   float* __restrict__ pooled, int n) {
    int g = blockIdx.x;
    int tid = threadIdx.x;
    __shared__ int s_lo, s_hi;
    if (tid == 0) {
        int lo = 0, hi = n;
        while (lo < hi) { int mid = (lo + hi) >> 1; if (batch[mid] < g) lo = mid + 1; else hi = mid; }
        s_lo = lo;
        int lo2 = lo, hi2 = n;
        while (lo2 < hi2) { int mid = (lo2 + hi2) >> 1; if (batch[mid] < g + 1) lo2 = mid + 1; else hi2 = mid; }
        s_hi = lo2;
    }
    __syncthreads();
    int lo = s_lo, hi = s_hi;
    int grp = tid >> 5, col = tid & 31;
    float a0 = 0.f, a1 = 0.f;
    for (int i = lo + grp; i < hi; i += 8) {
        uint32_t v = x[(size_t)i * 32 + col];
        a0 += bflo(v);
        a1 += bfhi(v);
    }
    __shared__ float red0[8][32], red1[8][32];
    red0[grp][col] = a0;
    red1[grp][col] = a1;
    __syncthreads();
    if (tid < 32) {
        float s0 = 0.f, s1 = 0.f;
        #pragma unroll
        for (int r = 0; r < 8; r++) { s0 += red0[r][tid]; s1 += red1[r][tid]; }
        float c = fmaxf((float)(hi - lo), 1.f);
        pooled[g * 64 + 2 * tid]     = s0 / c;
        pooled[g * 64 + 2 * tid + 1] = s1 / c;
    }
}

// ---------------- head ----------------
__global__ void head_kernel(const float* __restrict__ xs, const float* __restrict__ xt,
                            const float* __restrict__ Wlin, const float* __restrict__ blin,
                            float* __restrict__ out) {
    __shared__ float z[64];
    int g = blockIdx.x;
    int tid = threadIdx.x;
    if (tid < 64) z[tid] = xs[g * 64 + tid] + xt[g * 64 + tid];
    __syncthreads();
    for (int c = tid; c < Lout; c += blockDim.x) {
        float acc = blin[c];
        #pragma unroll
        for (int k = 0; k < 64; k++) acc += z[k] * Wlin[k * Lout + c];
        out[(size_t)g * Lout + c] = 1.f / (1.f + expf(-acc));
    }
}

extern "C" void kernel_launch(void* const* d_in, const int* in_sizes, int n_in,
                              void* d_out, int out_size, void* d_ws, size_t ws_size,
                              hipStream_t stream) {
    size_t off = 0;
    auto alloc = [&](size_t bytes) -> void* {
        void* p = (char*)d_ws + off;
        off += (bytes + 255) & ~(size_t)255;
        return p;
    };
    uint32_t* hbuf  = (uint32_t*)alloc((size_t)Nn * 64 * 4);
    uint32_t* xbuf  = (uint32_t*)alloc((size_t)Nn * 64 * 4);
    float* ssrc     = (float*)alloc((size_t)Nn * 4);
    float* sdst     = (float*)alloc((size_t)Nn * 4);
    int*   row_ptr  = (int*)alloc((size_t)(Nn + 1) * 4);
    int*   cur      = (int*)alloc((size_t)Nn * 4);
    int*   csr      = (int*)alloc((size_t)Ecnt * 4);
    int*   bsum     = (int*)alloc(64 * 4);
    float* xs_mean  = (float*)alloc((size_t)Gn * 64 * 4);
    float* xt_mean  = (float*)alloc((size_t)Gn * 64 * 4);

    const int EB = (Ecnt + 255) / 256;
    const int NW = (Nn * 64 + 255) / 256;
    const int NB = (Nn + 1023) / 1024;
    const int GB = (Nn + 63) / 64;            // mfma_gemm blocks (BM=64)

    auto run_side = [&](const float* x, const int* edges, const int* batch,
                        const float* W1, const float* a1s, const float* a1d, const float* b1,
                        const float* W2, const float* a2s, const float* a2d, const float* b2,
                        float* pooled) {
        const int* src = edges;
        const int* dst = edges + Ecnt;
        hipMemsetAsync(cur, 0, (size_t)Nn * 4, stream);
        count_kernel<<<EB, 256, 0, stream>>>(dst, cur, Ecnt);
        scan1<<<NB, 1024, 0, stream>>>(cur, row_ptr, bsum, Nn);
        scan2<<<1, 64, 0, stream>>>(bsum, NB);
        scan3<<<(Nn + 255) / 256, 256, 0, stream>>>(row_ptr, bsum, Nn, NB);
        hipMemsetAsync(cur, 0, (size_t)Nn * 4, stream);
        fill_kernel<<<EB, 256, 0, stream>>>(src, dst, row_ptr, cur, csr, Ecnt);
        // layer 1: 256 -> 128 (fp32 A -> bf16 MFMA)
        mfma_gemm<2, 4, 128, false><<<GB, 256, 0, stream>>>(x, W1, hbuf, Nn, Din);
        scores_kernel<128><<<NW, 256, 0, stream>>>(hbuf, a1s, a1d, ssrc, sdst, Nn);
        attn_agg<128><<<NW, 256, 0, stream>>>(hbuf, ssrc, sdst, row_ptr, csr, b1, xbuf, Nn);
        // layer 2: 128 -> 64 (bf16 A)
        mfma_gemm<2, 2, 64, true><<<GB, 256, 0, stream>>>(xbuf, W2, hbuf, Nn, 128);
        scores_kernel<64><<<NW, 256, 0, stream>>>(hbuf, a2s, a2d, ssrc, sdst, Nn);
        attn_agg<64><<<NW, 256, 0, stream>>>(hbuf, ssrc, sdst, row_ptr, csr, b2, xbuf, Nn);
        pool_kernel<<<Gn, 256, 0, stream>>>(xbuf, batch, pooled, Nn);
    };

    const float* x_s = (const float*)d_in[0];
    const float* x_t = (const float*)d_in[1];
    const int* ei_s  = (const int*)d_in[2];
    const int* ei_t  = (const int*)d_in[3];
    const int* bat_s = (const int*)d_in[4];
    const int* bat_t = (const int*)d_in[5];

    run_side(x_s, ei_s, bat_s,
             (const float*)d_in[6], (const float*)d_in[7], (const float*)d_in[8], (const float*)d_in[9],
             (const float*)d_in[10], (const float*)d_in[11], (const float*)d_in[12], (const float*)d_in[13],
             xs_mean);
    run_side(x_t, ei_t, bat_t,
             (const float*)d_in[14], (const float*)d_in[15], (const float*)d_in[16], (const float*)d_in[17],
             (const float*)d_in[18], (const float*)d_in[19], (const float*)d_in[20], (const float*)d_in[21],
             xt_mean);

    head_kernel<<<Gn, 256, 0, stream>>>(xs_mean, xt_mean,
                                        (const float*)d_in[22], (const float*)d_in[23],
                                        (float*)d_out);
}

// Round 5
// 594.312 us; speedup vs baseline: 2.6493x; 1.0952x over previous
//
#include <hip/hip_runtime.h>
#include <hip/hip_bf16.h>
#include <math.h>

constexpr int Nn   = 50000;
constexpr int Ecnt = 800000;
constexpr int Gn   = 128;
constexpr int Din  = 256;
constexpr int Lout = 1024;

typedef __attribute__((ext_vector_type(8))) short short8;   // 8 bf16 (4 VGPRs)
typedef __attribute__((ext_vector_type(4))) float f32x4;    // MFMA accumulator

__device__ __forceinline__ float lrelu(float x) { return x >= 0.f ? x : 0.2f * x; }

__device__ __forceinline__ float bflo(uint32_t v) { return __uint_as_float(v << 16); }
__device__ __forceinline__ float bfhi(uint32_t v) { return __uint_as_float(v & 0xffff0000u); }
__device__ __forceinline__ uint32_t f2bf(float f) {
    uint32_t x = __float_as_uint(f);
    return (x + 0x7fffu + ((x >> 16) & 1u)) >> 16;
}
__device__ __forceinline__ uint32_t packbf(float lo, float hi) {
    return f2bf(lo) | (f2bf(hi) << 16);
}

// ---------------- CSR build ----------------
__global__ void count_kernel(const int* __restrict__ dst, int* __restrict__ cnt, int n) {
    int i = blockIdx.x * blockDim.x + threadIdx.x;
    if (i < n) atomicAdd(&cnt[dst[i]], 1);
}

__global__ __launch_bounds__(1024) void scan1(const int* __restrict__ cnt,
                                              int* __restrict__ excl, int* __restrict__ bsum, int n) {
    __shared__ int buf[1024];
    int t = threadIdx.x;
    int i = blockIdx.x * 1024 + t;
    int v = (i < n) ? cnt[i] : 0;
    buf[t] = v;
    __syncthreads();
    for (int off = 1; off < 1024; off <<= 1) {
        int x = (t >= off) ? buf[t - off] : 0;
        __syncthreads();
        buf[t] += x;
        __syncthreads();
    }
    if (i < n) excl[i] = buf[t] - v;
    if (t == 1023) bsum[blockIdx.x] = buf[1023];
}

__global__ void scan2(int* __restrict__ bsum, int nb) {
    int lane = threadIdx.x;
    int v = (lane < nb) ? bsum[lane] : 0;
    #pragma unroll
    for (int off = 1; off < 64; off <<= 1) {
        int y = __shfl_up(v, off);
        if (lane >= off) v += y;
    }
    if (lane < nb) bsum[lane] = v;
}

__global__ void scan3(int* __restrict__ row_ptr, const int* __restrict__ bsum, int n, int nb) {
    int i = blockIdx.x * blockDim.x + threadIdx.x;
    if (i < n) {
        int b = i >> 10;
        if (b > 0) row_ptr[i] += bsum[b - 1];
    }
    if (i == 0) row_ptr[n] = bsum[nb - 1];
}

// fill: consumes counts in `cnt` by atomicSub (no extra memset needed)
__global__ void fill_kernel(const int* __restrict__ src, const int* __restrict__ dst,
                            const int* __restrict__ row_ptr, int* __restrict__ cnt,
                            int* __restrict__ csr_src, int n) {
    int i = blockIdx.x * blockDim.x + threadIdx.x;
    if (i >= n) return;
    int d = dst[i];
    int r = atomicSub(&cnt[d], 1);
    csr_src[row_ptr[d] + r - 1] = src[i];
}

// ---------------- MFMA bf16 GEMM: C[M,BN](bf16 packed) = A[M,K] @ B[K,BN] ----------------
template<int MF, int NF, int BN, bool BF16A>
__global__ __launch_bounds__(256) void mfma_gemm(const void* __restrict__ Av,
                                                 const float* __restrict__ B,
                                                 uint32_t* __restrict__ C,
                                                 int M, int K) {
    __shared__ uint32_t Al[64][36];   // [row][k-dword], 32 dwords + 4 pad
    __shared__ uint32_t Bl[BN][36];   // [col][k-dword] (B transposed)
    int tid  = threadIdx.x;
    int lane = tid & 63;
    int wid  = tid >> 6;
    int wr = wid >> 1, wc = wid & 1;
    int bm = blockIdx.x * 64;

    f32x4 acc[MF][NF];
    #pragma unroll
    for (int i = 0; i < MF; i++)
        #pragma unroll
        for (int j = 0; j < NF; j++) acc[i][j] = (f32x4){0.f, 0.f, 0.f, 0.f};

    for (int k0 = 0; k0 < K; k0 += 64) {
        {
            int row = tid >> 2, q = tid & 3;
            bool valid = (bm + row) < M;
            uint32_t d[8];
            if constexpr (BF16A) {
                const uint32_t* A = (const uint32_t*)Av;
                if (valid) {
                    const uint32_t* p = A + (size_t)(bm + row) * (K >> 1) + (k0 >> 1) + q * 8;
                    uint4 u0 = *(const uint4*)p;
                    uint4 u1 = *(const uint4*)(p + 4);
                    d[0] = u0.x; d[1] = u0.y; d[2] = u0.z; d[3] = u0.w;
                    d[4] = u1.x; d[5] = u1.y; d[6] = u1.z; d[7] = u1.w;
                } else {
                    #pragma unroll
                    for (int i = 0; i < 8; i++) d[i] = 0u;
                }
            } else {
                const float* A = (const float*)Av;
                if (valid) {
                    const float* p = A + (size_t)(bm + row) * K + k0 + q * 16;
                    #pragma unroll
                    for (int i = 0; i < 4; i++) {
                        float4 f = *(const float4*)(p + i * 4);
                        d[2 * i]     = packbf(f.x, f.y);
                        d[2 * i + 1] = packbf(f.z, f.w);
                    }
                } else {
                    #pragma unroll
                    for (int i = 0; i < 8; i++) d[i] = 0u;
                }
            }
            uint4* dst = (uint4*)&Al[row][q * 8];
            dst[0] = make_uint4(d[0], d[1], d[2], d[3]);
            dst[1] = make_uint4(d[4], d[5], d[6], d[7]);
        }
        {
            constexpr int NITER = BN * 32 / 256;
            constexpr int SH = (BN == 128) ? 7 : 6;
            #pragma unroll
            for (int i = 0; i < NITER; i++) {
                int idx = tid + i * 256;
                int n = idx & (BN - 1);
                int kd = idx >> SH;
                float b0 = B[(size_t)(k0 + 2 * kd) * BN + n];
                float b1 = B[(size_t)(k0 + 2 * kd + 1) * BN + n];
                Bl[n][kd] = packbf(b0, b1);
            }
        }
        __syncthreads();
        int lr = lane & 15, lk = lane >> 4;
        #pragma unroll
        for (int ks = 0; ks < 2; ks++) {
            short8 af[MF], bf[NF];
            #pragma unroll
            for (int mf = 0; mf < MF; mf++)
                af[mf] = *(const short8*)&Al[wr * (MF * 16) + mf * 16 + lr][ks * 16 + lk * 4];
            #pragma unroll
            for (int nf = 0; nf < NF; nf++)
                bf[nf] = *(const short8*)&Bl[wc * (NF * 16) + nf * 16 + lr][ks * 16 + lk * 4];
            #pragma unroll
            for (int mf = 0; mf < MF; mf++)
                #pragma unroll
                for (int nf = 0; nf < NF; nf++)
                    acc[mf][nf] = __builtin_amdgcn_mfma_f32_16x16x32_bf16(af[mf], bf[nf], acc[mf][nf], 0, 0, 0);
        }
        __syncthreads();
    }
    int lr = lane & 15, lg = lane >> 4;
    #pragma unroll
    for (int mf = 0; mf < MF; mf++) {
        #pragma unroll
        for (int nf = 0; nf < NF; nf++) {
            int col = wc * (NF * 16) + nf * 16 + lr;
            #pragma unroll
            for (int j = 0; j < 4; j++) {
                int row = bm + wr * (MF * 16) + mf * 16 + lg * 4 + j;
                float v = acc[mf][nf][j];
                float w = __shfl_xor(v, 1);
                if (!(lane & 1) && row < M)
                    C[(size_t)row * (BN >> 1) + (col >> 1)] = packbf(v, w);
            }
        }
    }
}

// ---------------- per-node scores from bf16 h ----------------
template<int F>
__global__ void scores_kernel(const uint32_t* __restrict__ h, const float* __restrict__ a_src,
                              const float* __restrict__ a_dst, float* __restrict__ ssrc,
                              float* __restrict__ sdst, int n) {
    int wid = (blockIdx.x * blockDim.x + threadIdx.x) >> 6;
    int lane = threadIdx.x & 63;
    if (wid >= n) return;
    constexpr int RU = F / 2;
    float vs = 0.f, vd = 0.f;
    if (lane < RU) {
        uint32_t v = h[(size_t)wid * RU + lane];
        float lo = bflo(v), hi = bfhi(v);
        vs = lo * a_src[2 * lane] + hi * a_src[2 * lane + 1];
        vd = lo * a_dst[2 * lane] + hi * a_dst[2 * lane + 1];
    }
    #pragma unroll
    for (int o = 32; o; o >>= 1) { vs += __shfl_xor(vs, o); vd += __shfl_xor(vd, o); }
    if (lane == 0) { ssrc[wid] = vs; sdst[wid] = vd; }
}

// ---------------- attention softmax + aggregation (one wave per dst node) ----------------
template<int F>
__global__ __launch_bounds__(256) void attn_agg(const uint32_t* __restrict__ h,
        const float* __restrict__ ssrc, const float* __restrict__ sdst,
        const int* __restrict__ row_ptr, const int* __restrict__ csr_src,
        const float* __restrict__ bias, uint32_t* __restrict__ xout, int n) {
    int wid = (blockIdx.x * blockDim.x + threadIdx.x) >> 6;
    int lane = threadIdx.x & 63;
    if (wid >= n) return;
    int beg = row_ptr[wid], end = row_ptr[wid + 1];
    float sd = sdst[wid];
    float eself = lrelu(ssrc[wid] + sd);
    float m = eself;
    for (int p = beg + lane; p < end; p += 64)
        m = fmaxf(m, lrelu(ssrc[csr_src[p]] + sd));
    #pragma unroll
    for (int o = 32; o; o >>= 1) m = fmaxf(m, __shfl_xor(m, o));
    float dsum = (lane == 0) ? expf(eself - m) : 0.f;
    for (int p = beg + lane; p < end; p += 64)
        dsum += expf(lrelu(ssrc[csr_src[p]] + sd) - m);
    #pragma unroll
    for (int o = 32; o; o >>= 1) dsum += __shfl_xor(dsum, o);
    float inv = 1.f / dsum;
    float wself = expf(eself - m) * inv;

    constexpr int RU = F / 2;
    if constexpr (F == 128) {
        uint32_t v = h[(size_t)wid * RU + lane];
        float acc0 = wself * bflo(v), acc1 = wself * bfhi(v);
        int p = beg;
        for (; p + 1 < end; p += 2) {
            int s0 = csr_src[p], s1 = csr_src[p + 1];
            uint32_t v0 = h[(size_t)s0 * RU + lane];
            uint32_t v1 = h[(size_t)s1 * RU + lane];
            float w0 = expf(lrelu(ssrc[s0] + sd) - m) * inv;
            float w1 = expf(lrelu(ssrc[s1] + sd) - m) * inv;
            acc0 += w0 * bflo(v0) + w1 * bflo(v1);
            acc1 += w0 * bfhi(v0) + w1 * bfhi(v1);
        }
        if (p < end) {
            int s0 = csr_src[p];
            uint32_t v0 = h[(size_t)s0 * RU + lane];
            float w0 = expf(lrelu(ssrc[s0] + sd) - m) * inv;
            acc0 += w0 * bflo(v0);
            acc1 += w0 * bfhi(v0);
        }
        float r0 = fmaxf(acc0 + bias[2 * lane], 0.f);
        float r1 = fmaxf(acc1 + bias[2 * lane + 1], 0.f);
        xout[(size_t)wid * RU + lane] = packbf(r0, r1);
    } else {
        int half = lane >> 5, i = lane & 31;
        float acc0 = 0.f, acc1 = 0.f;
        if (half == 0) {
            uint32_t v = h[(size_t)wid * RU + i];
            acc0 = wself * bflo(v);
            acc1 = wself * bfhi(v);
        }
        for (int p = beg + half; p < end; p += 2) {
            int s0 = csr_src[p];
            uint32_t v = h[(size_t)s0 * RU + i];
            float w = expf(lrelu(ssrc[s0] + sd) - m) * inv;
            acc0 += w * bflo(v);
            acc1 += w * bfhi(v);
        }
        acc0 += __shfl_xor(acc0, 32);
        acc1 += __shfl_xor(acc1, 32);
        if (half == 0) {
            float r0 = fmaxf(acc0 + bias[2 * i], 0.f);
            float r1 = fmaxf(acc1 + bias[2 * i + 1], 0.f);
            xout[(size_t)wid * RU + i] = packbf(r0, r1);
        }
    }
}

// ---------------- mean pool (sorted batch), bf16 input ----------------
__global__ __launch_bounds__(256) void pool_kernel(const uint32_t* __restrict__ x,
                                                   const int* __restrict__ batch,
                                                   float* __restrict__ pooled, int n) {
    int g = blockIdx.x;
    int tid = threadIdx.x;
    __shared__ int s_lo, s_hi;
    if (tid == 0) {
        int lo = 0, hi = n;
        while (lo < hi) { int mid = (lo + hi) >> 1; if (batch[mid] < g) lo = mid + 1; else hi = mid; }
        s_lo = lo;
        int lo2 = lo, hi2 = n;
        while (lo2 < hi2) { int mid = (lo2 + hi2) >> 1; if (batch[mid] < g + 1) lo2 = mid + 1; else hi2 = mid; }
        s_hi = lo2;
    }
    __syncthreads();
    int lo = s_lo, hi = s_hi;
    int grp = tid >> 5, col = tid & 31;
    float a0 = 0.f, a1 = 0.f;
    for (int i = lo + grp; i < hi; i += 8) {
        uint32_t v = x[(size_t)i * 32 + col];
        a0 += bflo(v);
        a1 += bfhi(v);
    }
    __shared__ float red0[8][32], red1[8][32];
    red0[grp][col] = a0;
    red1[grp][col] = a1;
    __syncthreads();
    if (tid < 32) {
        float s0 = 0.f, s1 = 0.f;
        #pragma unroll
        for (int r = 0; r < 8; r++) { s0 += red0[r][tid]; s1 += red1[r][tid]; }
        float c = fmaxf((float)(hi - lo), 1.f);
        pooled[g * 64 + 2 * tid]     = s0 / c;
        pooled[g * 64 + 2 * tid + 1] = s1 / c;
    }
}

// ---------------- head: one thread per output element, 4 independent acc chains ----------------
__global__ __launch_bounds__(256) void head_kernel(const float* __restrict__ xs,
                                                   const float* __restrict__ xt,
                                                   const float* __restrict__ Wlin,
                                                   const float* __restrict__ blin,
                                                   float* __restrict__ out) {
    int g = blockIdx.y;
    int c = blockIdx.x * 256 + threadIdx.x;
    __shared__ float z[64];
    if (threadIdx.x < 64) z[threadIdx.x] = xs[g * 64 + threadIdx.x] + xt[g * 64 + threadIdx.x];
    __syncthreads();
    float a0 = 0.f, a1 = 0.f, a2 = 0.f, a3 = 0.f;
    #pragma unroll
    for (int k = 0; k < 64; k += 4) {
        a0 += z[k]     * Wlin[(size_t)(k)     * Lout + c];
        a1 += z[k + 1] * Wlin[(size_t)(k + 1) * Lout + c];
        a2 += z[k + 2] * Wlin[(size_t)(k + 2) * Lout + c];
        a3 += z[k + 3] * Wlin[(size_t)(k + 3) * Lout + c];
    }
    float acc = (a0 + a1) + (a2 + a3) + blin[c];
    out[(size_t)g * Lout + c] = 1.f / (1.f + expf(-acc));
}

extern "C" void kernel_launch(void* const* d_in, const int* in_sizes, int n_in,
                              void* d_out, int out_size, void* d_ws, size_t ws_size,
                              hipStream_t stream) {
    size_t off = 0;
    auto alloc = [&](size_t bytes) -> void* {
        void* p = (char*)d_ws + off;
        off += (bytes + 255) & ~(size_t)255;
        return p;
    };
    uint32_t* hbuf  = (uint32_t*)alloc((size_t)Nn * 64 * 4);
    uint32_t* xbuf  = (uint32_t*)alloc((size_t)Nn * 64 * 4);
    float* ssrc     = (float*)alloc((size_t)Nn * 4);
    float* sdst     = (float*)alloc((size_t)Nn * 4);
    int*   row_ptr  = (int*)alloc((size_t)(Nn + 1) * 4);
    int*   cur      = (int*)alloc((size_t)Nn * 4);
    int*   csr      = (int*)alloc((size_t)Ecnt * 4);
    int*   bsum     = (int*)alloc(64 * 4);
    float* xs_mean  = (float*)alloc((size_t)Gn * 64 * 4);
    float* xt_mean  = (float*)alloc((size_t)Gn * 64 * 4);

    const int EB = (Ecnt + 255) / 256;
    const int NW = (Nn * 64 + 255) / 256;
    const int NB = (Nn + 1023) / 1024;
    const int GB = (Nn + 63) / 64;

    auto run_side = [&](const float* x, const int* edges, const int* batch,
                        const float* W1, const float* a1s, const float* a1d, const float* b1,
                        const float* W2, const float* a2s, const float* a2d, const float* b2,
                        float* pooled) {
        const int* src = edges;
        const int* dst = edges + Ecnt;
        hipMemsetAsync(cur, 0, (size_t)Nn * 4, stream);
        count_kernel<<<EB, 256, 0, stream>>>(dst, cur, Ecnt);
        scan1<<<NB, 1024, 0, stream>>>(cur, row_ptr, bsum, Nn);
        scan2<<<1, 64, 0, stream>>>(bsum, NB);
        scan3<<<(Nn + 255) / 256, 256, 0, stream>>>(row_ptr, bsum, Nn, NB);
        fill_kernel<<<EB, 256, 0, stream>>>(src, dst, row_ptr, cur, csr, Ecnt);
        mfma_gemm<2, 4, 128, false><<<GB, 256, 0, stream>>>(x, W1, hbuf, Nn, Din);
        scores_kernel<128><<<NW, 256, 0, stream>>>(hbuf, a1s, a1d, ssrc, sdst, Nn);
        attn_agg<128><<<NW, 256, 0, stream>>>(hbuf, ssrc, sdst, row_ptr, csr, b1, xbuf, Nn);
        mfma_gemm<2, 2, 64, true><<<GB, 256, 0, stream>>>(xbuf, W2, hbuf, Nn, 128);
        scores_kernel<64><<<NW, 256, 0, stream>>>(hbuf, a2s, a2d, ssrc, sdst, Nn);
        attn_agg<64><<<NW, 256, 0, stream>>>(hbuf, ssrc, sdst, row_ptr, csr, b2, xbuf, Nn);
        pool_kernel<<<Gn, 256, 0, stream>>>(xbuf, batch, pooled, Nn);
    };

    const float* x_s = (const float*)d_in[0];
    const float* x_t = (const float*)d_in[1];
    const int* ei_s  = (const int*)d_in[2];
    const int* ei_t  = (const int*)d_in[3];
    const int* bat_s = (const int*)d_in[4];
    const int* bat_t = (const int*)d_in[5];

    run_side(x_s, ei_s, bat_s,
             (const float*)d_in[6], (const float*)d_in[7], (const float*)d_in[8], (const float*)d_in[9],
             (const float*)d_in[10], (const float*)d_in[11], (const float*)d_in[12], (const float*)d_in[13],
             xs_mean);
    run_side(x_t, ei_t, bat_t,
             (const float*)d_in[14], (const float*)d_in[15], (const float*)d_in[16], (const float*)d_in[17],
             (const float*)d_in[18], (const float*)d_in[19], (const float*)d_in[20], (const float*)d_in[21],
             xt_mean);

    head_kernel<<<dim3(Lout / 256, Gn), 256, 0, stream>>>(xs_mean, xt_mean,
                                        (const float*)d_in[22], (const float*)d_in[23],
                                        (float*)d_out);
}

// Round 6
// 533.605 us; speedup vs baseline: 2.9507x; 1.1138x over previous
//
#include <hip/hip_runtime.h>
#include <hip/hip_bf16.h>
#include <math.h>

constexpr int Nn   = 50000;
constexpr int Ecnt = 800000;
constexpr int Gn   = 128;
constexpr int Din  = 256;
constexpr int Lout = 1024;

typedef __attribute__((ext_vector_type(8))) short short8;   // 8 bf16 (4 VGPRs)
typedef __attribute__((ext_vector_type(4))) float f32x4;    // MFMA accumulator

__device__ __forceinline__ float lrelu(float x) { return x >= 0.f ? x : 0.2f * x; }

__device__ __forceinline__ float bflo(uint32_t v) { return __uint_as_float(v << 16); }
__device__ __forceinline__ float bfhi(uint32_t v) { return __uint_as_float(v & 0xffff0000u); }
__device__ __forceinline__ uint32_t f2bf(float f) {
    uint32_t x = __float_as_uint(f);
    return (x + 0x7fffu + ((x >> 16) & 1u)) >> 16;
}
__device__ __forceinline__ uint32_t packbf(float lo, float hi) {
    return f2bf(lo) | (f2bf(hi) << 16);
}

// ---------------- CSR build ----------------
__global__ void count_kernel(const int* __restrict__ dst, int* __restrict__ cnt, int n) {
    int i = blockIdx.x * blockDim.x + threadIdx.x;
    if (i < n) atomicAdd(&cnt[dst[i]], 1);
}

__global__ __launch_bounds__(1024) void scan1(const int* __restrict__ cnt,
                                              int* __restrict__ excl, int* __restrict__ bsum, int n) {
    __shared__ int buf[1024];
    int t = threadIdx.x;
    int i = blockIdx.x * 1024 + t;
    int v = (i < n) ? cnt[i] : 0;
    buf[t] = v;
    __syncthreads();
    for (int off = 1; off < 1024; off <<= 1) {
        int x = (t >= off) ? buf[t - off] : 0;
        __syncthreads();
        buf[t] += x;
        __syncthreads();
    }
    if (i < n) excl[i] = buf[t] - v;
    if (t == 1023) bsum[blockIdx.x] = buf[1023];
}

__global__ void scan2(int* __restrict__ bsum, int nb) {
    int lane = threadIdx.x;
    int v = (lane < nb) ? bsum[lane] : 0;
    #pragma unroll
    for (int off = 1; off < 64; off <<= 1) {
        int y = __shfl_up(v, off);
        if (lane >= off) v += y;
    }
    if (lane < nb) bsum[lane] = v;
}

__global__ void scan3(int* __restrict__ row_ptr, const int* __restrict__ bsum, int n, int nb) {
    int i = blockIdx.x * blockDim.x + threadIdx.x;
    if (i < n) {
        int b = i >> 10;
        if (b > 0) row_ptr[i] += bsum[b - 1];
    }
    if (i == 0) row_ptr[n] = bsum[nb - 1];
}

// fill: consumes counts in `cnt` by atomicSub (no extra memset needed)
__global__ void fill_kernel(const int* __restrict__ src, const int* __restrict__ dst,
                            const int* __restrict__ row_ptr, int* __restrict__ cnt,
                            int* __restrict__ csr_src, int n) {
    int i = blockIdx.x * blockDim.x + threadIdx.x;
    if (i >= n) return;
    int d = dst[i];
    int r = atomicSub(&cnt[d], 1);
    csr_src[row_ptr[d] + r - 1] = src[i];
}

// ---------------- MFMA bf16 GEMM: C[M,BN](bf16 packed) = A[M,K] @ B[K,BN] ----------------
template<int MF, int NF, int BN, bool BF16A>
__global__ __launch_bounds__(256) void mfma_gemm(const void* __restrict__ Av,
                                                 const float* __restrict__ B,
                                                 uint32_t* __restrict__ C,
                                                 int M, int K) {
    __shared__ uint32_t Al[64][36];   // [row][k-dword], 32 dwords + 4 pad
    __shared__ uint32_t Bl[BN][36];   // [col][k-dword] (B transposed)
    int tid  = threadIdx.x;
    int lane = tid & 63;
    int wid  = tid >> 6;
    int wr = wid >> 1, wc = wid & 1;
    int bm = blockIdx.x * 64;

    f32x4 acc[MF][NF];
    #pragma unroll
    for (int i = 0; i < MF; i++)
        #pragma unroll
        for (int j = 0; j < NF; j++) acc[i][j] = (f32x4){0.f, 0.f, 0.f, 0.f};

    for (int k0 = 0; k0 < K; k0 += 64) {
        {
            int row = tid >> 2, q = tid & 3;
            bool valid = (bm + row) < M;
            uint32_t d[8];
            if constexpr (BF16A) {
                const uint32_t* A = (const uint32_t*)Av;
                if (valid) {
                    const uint32_t* p = A + (size_t)(bm + row) * (K >> 1) + (k0 >> 1) + q * 8;
                    uint4 u0 = *(const uint4*)p;
                    uint4 u1 = *(const uint4*)(p + 4);
                    d[0] = u0.x; d[1] = u0.y; d[2] = u0.z; d[3] = u0.w;
                    d[4] = u1.x; d[5] = u1.y; d[6] = u1.z; d[7] = u1.w;
                } else {
                    #pragma unroll
                    for (int i = 0; i < 8; i++) d[i] = 0u;
                }
            } else {
                const float* A = (const float*)Av;
                if (valid) {
                    const float* p = A + (size_t)(bm + row) * K + k0 + q * 16;
                    #pragma unroll
                    for (int i = 0; i < 4; i++) {
                        float4 f = *(const float4*)(p + i * 4);
                        d[2 * i]     = packbf(f.x, f.y);
                        d[2 * i + 1] = packbf(f.z, f.w);
                    }
                } else {
                    #pragma unroll
                    for (int i = 0; i < 8; i++) d[i] = 0u;
                }
            }
            uint4* dst = (uint4*)&Al[row][q * 8];
            dst[0] = make_uint4(d[0], d[1], d[2], d[3]);
            dst[1] = make_uint4(d[4], d[5], d[6], d[7]);
        }
        {
            constexpr int NITER = BN * 32 / 256;
            constexpr int SH = (BN == 128) ? 7 : 6;
            #pragma unroll
            for (int i = 0; i < NITER; i++) {
                int idx = tid + i * 256;
                int n = idx & (BN - 1);
                int kd = idx >> SH;
                float b0 = B[(size_t)(k0 + 2 * kd) * BN + n];
                float b1 = B[(size_t)(k0 + 2 * kd + 1) * BN + n];
                Bl[n][kd] = packbf(b0, b1);
            }
        }
        __syncthreads();
        int lr = lane & 15, lk = lane >> 4;
        #pragma unroll
        for (int ks = 0; ks < 2; ks++) {
            short8 af[MF], bf[NF];
            #pragma unroll
            for (int mf = 0; mf < MF; mf++)
                af[mf] = *(const short8*)&Al[wr * (MF * 16) + mf * 16 + lr][ks * 16 + lk * 4];
            #pragma unroll
            for (int nf = 0; nf < NF; nf++)
                bf[nf] = *(const short8*)&Bl[wc * (NF * 16) + nf * 16 + lr][ks * 16 + lk * 4];
            #pragma unroll
            for (int mf = 0; mf < MF; mf++)
                #pragma unroll
                for (int nf = 0; nf < NF; nf++)
                    acc[mf][nf] = __builtin_amdgcn_mfma_f32_16x16x32_bf16(af[mf], bf[nf], acc[mf][nf], 0, 0, 0);
        }
        __syncthreads();
    }
    int lr = lane & 15, lg = lane >> 4;
    #pragma unroll
    for (int mf = 0; mf < MF; mf++) {
        #pragma unroll
        for (int nf = 0; nf < NF; nf++) {
            int col = wc * (NF * 16) + nf * 16 + lr;
            #pragma unroll
            for (int j = 0; j < 4; j++) {
                int row = bm + wr * (MF * 16) + mf * 16 + lg * 4 + j;
                float v = acc[mf][nf][j];
                float w = __shfl_xor(v, 1);
                if (!(lane & 1) && row < M)
                    C[(size_t)row * (BN >> 1) + (col >> 1)] = packbf(v, w);
            }
        }
    }
}

// ---------------- per-node scores from bf16 h ----------------
template<int F>
__global__ void scores_kernel(const uint32_t* __restrict__ h, const float* __restrict__ a_src,
                              const float* __restrict__ a_dst, float* __restrict__ ssrc,
                              float* __restrict__ sdst, int n) {
    int wid = (blockIdx.x * blockDim.x + threadIdx.x) >> 6;
    int lane = threadIdx.x & 63;
    if (wid >= n) return;
    constexpr int RU = F / 2;
    float vs = 0.f, vd = 0.f;
    if (lane < RU) {
        uint32_t v = h[(size_t)wid * RU + lane];
        float lo = bflo(v), hi = bfhi(v);
        vs = lo * a_src[2 * lane] + hi * a_src[2 * lane + 1];
        vd = lo * a_dst[2 * lane] + hi * a_dst[2 * lane + 1];
    }
    #pragma unroll
    for (int o = 32; o; o >>= 1) { vs += __shfl_xor(vs, o); vd += __shfl_xor(vd, o); }
    if (lane == 0) { ssrc[wid] = vs; sdst[wid] = vd; }
}

// ---------------- attention softmax + aggregation (one wave per dst node) ----------------
// Fast path (deg <= 64): per-edge score/exp computed ONCE lane-parallel, kept in regs,
// broadcast into the accumulate loop via __shfl. No transcendentals in the inner loop.
template<int F>
__global__ __launch_bounds__(256) void attn_agg(const uint32_t* __restrict__ h,
        const float* __restrict__ ssrc, const float* __restrict__ sdst,
        const int* __restrict__ row_ptr, const int* __restrict__ csr_src,
        const float* __restrict__ bias, uint32_t* __restrict__ xout, int n) {
    int wid = (blockIdx.x * blockDim.x + threadIdx.x) >> 6;
    int lane = threadIdx.x & 63;
    if (wid >= n) return;
    int beg = row_ptr[wid], end = row_ptr[wid + 1];
    int deg = end - beg;
    float sd = sdst[wid];
    float eself = lrelu(ssrc[wid] + sd);
    constexpr int RU = F / 2;

    if (deg <= 64) {
        int p = beg + lane;
        bool act = p < end;
        int s = act ? csr_src[p] : 0;
        float e = act ? lrelu(ssrc[s] + sd) : -1e30f;
        float m = fmaxf(eself, e);
        #pragma unroll
        for (int o = 32; o; o >>= 1) m = fmaxf(m, __shfl_xor(m, o));
        float ex = act ? __expf(e - m) : 0.f;
        float dsum = ex;
        #pragma unroll
        for (int o = 32; o; o >>= 1) dsum += __shfl_xor(dsum, o);
        float exself = __expf(eself - m);
        dsum += exself;
        float inv = 1.f / dsum;
        float w = ex * inv;          // this lane's edge weight
        float wself = exself * inv;

        if constexpr (F == 128) {
            uint32_t v = h[((size_t)wid << 6) + lane];
            float acc0 = wself * bflo(v), acc1 = wself * bfhi(v);
            for (int j = 0; j < deg; ++j) {
                float wj = __shfl(w, j);
                int sj   = __shfl(s, j);
                uint32_t u = h[((size_t)sj << 6) + lane];
                acc0 += wj * bflo(u);
                acc1 += wj * bfhi(u);
            }
            float r0 = fmaxf(acc0 + bias[2 * lane], 0.f);
            float r1 = fmaxf(acc1 + bias[2 * lane + 1], 0.f);
            xout[((size_t)wid << 6) + lane] = packbf(r0, r1);
        } else {
            // two half-waves process alternating edges; lane&31 owns a dword (2 feats)
            int half = lane >> 5, i = lane & 31;
            float acc0 = 0.f, acc1 = 0.f;
            if (half == 0) {
                uint32_t v = h[((size_t)wid << 5) + i];
                acc0 = wself * bflo(v);
                acc1 = wself * bfhi(v);
            }
            for (int j = half; j < deg; j += 2) {
                float wj = __shfl(w, j);
                int sj   = __shfl(s, j);
                uint32_t u = h[((size_t)sj << 5) + i];
                acc0 += wj * bflo(u);
                acc1 += wj * bfhi(u);
            }
            acc0 += __shfl_xor(acc0, 32);
            acc1 += __shfl_xor(acc1, 32);
            if (half == 0) {
                float r0 = fmaxf(acc0 + bias[2 * i], 0.f);
                float r1 = fmaxf(acc1 + bias[2 * i + 1], 0.f);
                xout[((size_t)wid << 5) + i] = packbf(r0, r1);
            }
        }
        return;
    }

    // ---- generic path (deg > 64): 3-pass ----
    float m = eself;
    for (int p = beg + lane; p < end; p += 64)
        m = fmaxf(m, lrelu(ssrc[csr_src[p]] + sd));
    #pragma unroll
    for (int o = 32; o; o >>= 1) m = fmaxf(m, __shfl_xor(m, o));
    float dsum = (lane == 0) ? __expf(eself - m) : 0.f;
    for (int p = beg + lane; p < end; p += 64)
        dsum += __expf(lrelu(ssrc[csr_src[p]] + sd) - m);
    #pragma unroll
    for (int o = 32; o; o >>= 1) dsum += __shfl_xor(dsum, o);
    float inv = 1.f / dsum;
    float wself = __expf(eself - m) * inv;

    if constexpr (F == 128) {
        uint32_t v = h[(size_t)wid * RU + lane];
        float acc0 = wself * bflo(v), acc1 = wself * bfhi(v);
        for (int p = beg; p < end; ++p) {
            int s0 = csr_src[p];
            uint32_t v0 = h[(size_t)s0 * RU + lane];
            float w0 = __expf(lrelu(ssrc[s0] + sd) - m) * inv;
            acc0 += w0 * bflo(v0);
            acc1 += w0 * bfhi(v0);
        }
        float r0 = fmaxf(acc0 + bias[2 * lane], 0.f);
        float r1 = fmaxf(acc1 + bias[2 * lane + 1], 0.f);
        xout[(size_t)wid * RU + lane] = packbf(r0, r1);
    } else {
        int half = lane >> 5, i = lane & 31;
        float acc0 = 0.f, acc1 = 0.f;
        if (half == 0) {
            uint32_t v = h[(size_t)wid * RU + i];
            acc0 = wself * bflo(v);
            acc1 = wself * bfhi(v);
        }
        for (int p = beg + half; p < end; p += 2) {
            int s0 = csr_src[p];
            uint32_t v = h[(size_t)s0 * RU + i];
            float w0 = __expf(lrelu(ssrc[s0] + sd) - m) * inv;
            acc0 += w0 * bflo(v);
            acc1 += w0 * bfhi(v);
        }
        acc0 += __shfl_xor(acc0, 32);
        acc1 += __shfl_xor(acc1, 32);
        if (half == 0) {
            float r0 = fmaxf(acc0 + bias[2 * i], 0.f);
            float r1 = fmaxf(acc1 + bias[2 * i + 1], 0.f);
            xout[(size_t)wid * RU + i] = packbf(r0, r1);
        }
    }
}

// ---------------- mean pool (sorted batch), bf16 input ----------------
__global__ __launch_bounds__(256) void pool_kernel(const uint32_t* __restrict__ x,
                                                   const int* __restrict__ batch,
                                                   float* __restrict__ pooled, int n) {
    int g = blockIdx.x;
    int tid = threadIdx.x;
    __shared__ int s_lo, s_hi;
    if (tid == 0) {
        int lo = 0, hi = n;
        while (lo < hi) { int mid = (lo + hi) >> 1; if (batch[mid] < g) lo = mid + 1; else hi = mid; }
        s_lo = lo;
        int lo2 = lo, hi2 = n;
        while (lo2 < hi2) { int mid = (lo2 + hi2) >> 1; if (batch[mid] < g + 1) lo2 = mid + 1; else hi2 = mid; }
        s_hi = lo2;
    }
    __syncthreads();
    int lo = s_lo, hi = s_hi;
    int grp = tid >> 5, col = tid & 31;
    float a0 = 0.f, a1 = 0.f;
    for (int i = lo + grp; i < hi; i += 8) {
        uint32_t v = x[(size_t)i * 32 + col];
        a0 += bflo(v);
        a1 += bfhi(v);
    }
    __shared__ float red0[8][32], red1[8][32];
    red0[grp][col] = a0;
    red1[grp][col] = a1;
    __syncthreads();
    if (tid < 32) {
        float s0 = 0.f, s1 = 0.f;
        #pragma unroll
        for (int r = 0; r < 8; r++) { s0 += red0[r][tid]; s1 += red1[r][tid]; }
        float c = fmaxf((float)(hi - lo), 1.f);
        pooled[g * 64 + 2 * tid]     = s0 / c;
        pooled[g * 64 + 2 * tid + 1] = s1 / c;
    }
}

// ---------------- head: one thread per output element, 4 independent acc chains ----------------
__global__ __launch_bounds__(256) void head_kernel(const float* __restrict__ xs,
                                                   const float* __restrict__ xt,
                                                   const float* __restrict__ Wlin,
                                                   const float* __restrict__ blin,
                                                   float* __restrict__ out) {
    int g = blockIdx.y;
    int c = blockIdx.x * 256 + threadIdx.x;
    __shared__ float z[64];
    if (threadIdx.x < 64) z[threadIdx.x] = xs[g * 64 + threadIdx.x] + xt[g * 64 + threadIdx.x];
    __syncthreads();
    float a0 = 0.f, a1 = 0.f, a2 = 0.f, a3 = 0.f;
    #pragma unroll
    for (int k = 0; k < 64; k += 4) {
        a0 += z[k]     * Wlin[(size_t)(k)     * Lout + c];
        a1 += z[k + 1] * Wlin[(size_t)(k + 1) * Lout + c];
        a2 += z[k + 2] * Wlin[(size_t)(k + 2) * Lout + c];
        a3 += z[k + 3] * Wlin[(size_t)(k + 3) * Lout + c];
    }
    float acc = (a0 + a1) + (a2 + a3) + blin[c];
    out[(size_t)g * Lout + c] = 1.f / (1.f + expf(-acc));
}

extern "C" void kernel_launch(void* const* d_in, const int* in_sizes, int n_in,
                              void* d_out, int out_size, void* d_ws, size_t ws_size,
                              hipStream_t stream) {
    size_t off = 0;
    auto alloc = [&](size_t bytes) -> void* {
        void* p = (char*)d_ws + off;
        off += (bytes + 255) & ~(size_t)255;
        return p;
    };
    uint32_t* hbuf  = (uint32_t*)alloc((size_t)Nn * 64 * 4);
    uint32_t* xbuf  = (uint32_t*)alloc((size_t)Nn * 64 * 4);
    float* ssrc     = (float*)alloc((size_t)Nn * 4);
    float* sdst     = (float*)alloc((size_t)Nn * 4);
    int*   row_ptr  = (int*)alloc((size_t)(Nn + 1) * 4);
    int*   cur      = (int*)alloc((size_t)Nn * 4);
    int*   csr      = (int*)alloc((size_t)Ecnt * 4);
    int*   bsum     = (int*)alloc(64 * 4);
    float* xs_mean  = (float*)alloc((size_t)Gn * 64 * 4);
    float* xt_mean  = (float*)alloc((size_t)Gn * 64 * 4);

    const int EB = (Ecnt + 255) / 256;
    const int NW = (Nn * 64 + 255) / 256;
    const int NB = (Nn + 1023) / 1024;
    const int GB = (Nn + 63) / 64;

    auto run_side = [&](const float* x, const int* edges, const int* batch,
                        const float* W1, const float* a1s, const float* a1d, const float* b1,
                        const float* W2, const float* a2s, const float* a2d, const float* b2,
                        float* pooled) {
        const int* src = edges;
        const int* dst = edges + Ecnt;
        hipMemsetAsync(cur, 0, (size_t)Nn * 4, stream);
        count_kernel<<<EB, 256, 0, stream>>>(dst, cur, Ecnt);
        scan1<<<NB, 1024, 0, stream>>>(cur, row_ptr, bsum, Nn);
        scan2<<<1, 64, 0, stream>>>(bsum, NB);
        scan3<<<(Nn + 255) / 256, 256, 0, stream>>>(row_ptr, bsum, Nn, NB);
        fill_kernel<<<EB, 256, 0, stream>>>(src, dst, row_ptr, cur, csr, Ecnt);
        mfma_gemm<2, 4, 128, false><<<GB, 256, 0, stream>>>(x, W1, hbuf, Nn, Din);
        scores_kernel<128><<<NW, 256, 0, stream>>>(hbuf, a1s, a1d, ssrc, sdst, Nn);
        attn_agg<128><<<NW, 256, 0, stream>>>(hbuf, ssrc, sdst, row_ptr, csr, b1, xbuf, Nn);
        mfma_gemm<2, 2, 64, true><<<GB, 256, 0, stream>>>(xbuf, W2, hbuf, Nn, 128);
        scores_kernel<64><<<NW, 256, 0, stream>>>(hbuf, a2s, a2d, ssrc, sdst, Nn);
        attn_agg<64><<<NW, 256, 0, stream>>>(hbuf, ssrc, sdst, row_ptr, csr, b2, xbuf, Nn);
        pool_kernel<<<Gn, 256, 0, stream>>>(xbuf, batch, pooled, Nn);
    };

    const float* x_s = (const float*)d_in[0];
    const float* x_t = (const float*)d_in[1];
    const int* ei_s  = (const int*)d_in[2];
    const int* ei_t  = (const int*)d_in[3];
    const int* bat_s = (const int*)d_in[4];
    const int* bat_t = (const int*)d_in[5];

    run_side(x_s, ei_s, bat_s,
             (const float*)d_in[6], (const float*)d_in[7], (const float*)d_in[8], (const float*)d_in[9],
             (const float*)d_in[10], (const float*)d_in[11], (const float*)d_in[12], (const float*)d_in[13],
             xs_mean);
    run_side(x_t, ei_t, bat_t,
             (const float*)d_in[14], (const float*)d_in[15], (const float*)d_in[16], (const float*)d_in[17],
             (const float*)d_in[18], (const float*)d_in[19], (const float*)d_in[20], (const float*)d_in[21],
             xt_mean);

    head_kernel<<<dim3(Lout / 256, Gn), 256, 0, stream>>>(xs_mean, xt_mean,
                                        (const float*)d_in[22], (const float*)d_in[23],
                                        (float*)d_out);
}

// Round 7
// 467.457 us; speedup vs baseline: 3.3682x; 1.1415x over previous
//
#include <hip/hip_runtime.h>
#include <hip/hip_bf16.h>
#include <math.h>

constexpr int Nn   = 50000;
constexpr int Ecnt = 800000;
constexpr int Gn   = 128;
constexpr int Din  = 256;
constexpr int Lout = 1024;

typedef __attribute__((ext_vector_type(8))) short short8;   // 8 bf16 (4 VGPRs)
typedef __attribute__((ext_vector_type(4))) float f32x4;    // MFMA accumulator

__device__ __forceinline__ float lrelu(float x) { return x >= 0.f ? x : 0.2f * x; }

__device__ __forceinline__ float bflo(uint32_t v) { return __uint_as_float(v << 16); }
__device__ __forceinline__ float bfhi(uint32_t v) { return __uint_as_float(v & 0xffff0000u); }
__device__ __forceinline__ uint32_t f2bf(float f) {
    uint32_t x = __float_as_uint(f);
    return (x + 0x7fffu + ((x >> 16) & 1u)) >> 16;
}
__device__ __forceinline__ uint32_t packbf(float lo, float hi) {
    return f2bf(lo) | (f2bf(hi) << 16);
}

// ---------------- CSR build ----------------
__global__ void count_kernel(const int* __restrict__ dst, int* __restrict__ cnt, int n) {
    int i = blockIdx.x * blockDim.x + threadIdx.x;
    if (i < n) atomicAdd(&cnt[dst[i]], 1);
}

__global__ __launch_bounds__(1024) void scan1(const int* __restrict__ cnt,
                                              int* __restrict__ excl, int* __restrict__ bsum, int n) {
    __shared__ int buf[1024];
    int t = threadIdx.x;
    int i = blockIdx.x * 1024 + t;
    int v = (i < n) ? cnt[i] : 0;
    buf[t] = v;
    __syncthreads();
    for (int off = 1; off < 1024; off <<= 1) {
        int x = (t >= off) ? buf[t - off] : 0;
        __syncthreads();
        buf[t] += x;
        __syncthreads();
    }
    if (i < n) excl[i] = buf[t] - v;
    if (t == 1023) bsum[blockIdx.x] = buf[1023];
}

__global__ void scan2(int* __restrict__ bsum, int nb) {
    int lane = threadIdx.x;
    int v = (lane < nb) ? bsum[lane] : 0;
    #pragma unroll
    for (int off = 1; off < 64; off <<= 1) {
        int y = __shfl_up(v, off);
        if (lane >= off) v += y;
    }
    if (lane < nb) bsum[lane] = v;
}

__global__ void scan3(int* __restrict__ row_ptr, const int* __restrict__ bsum, int n, int nb) {
    int i = blockIdx.x * blockDim.x + threadIdx.x;
    if (i < n) {
        int b = i >> 10;
        if (b > 0) row_ptr[i] += bsum[b - 1];
    }
    if (i == 0) row_ptr[n] = bsum[nb - 1];
}

// fill: consumes counts in `cnt` by atomicSub (no extra memset needed)
__global__ void fill_kernel(const int* __restrict__ src, const int* __restrict__ dst,
                            const int* __restrict__ row_ptr, int* __restrict__ cnt,
                            int* __restrict__ csr_src, int n) {
    int i = blockIdx.x * blockDim.x + threadIdx.x;
    if (i >= n) return;
    int d = dst[i];
    int r = atomicSub(&cnt[d], 1);
    csr_src[row_ptr[d] + r - 1] = src[i];
}

// ---------------- MFMA bf16 GEMM: C[M,BN](bf16 packed) = A[M,K] @ B[K,BN] ----------------
template<int MF, int NF, int BN, bool BF16A>
__global__ __launch_bounds__(256) void mfma_gemm(const void* __restrict__ Av,
                                                 const float* __restrict__ B,
                                                 uint32_t* __restrict__ C,
                                                 int M, int K) {
    __shared__ uint32_t Al[64][36];   // [row][k-dword], 32 dwords + 4 pad
    __shared__ uint32_t Bl[BN][36];   // [col][k-dword] (B transposed)
    int tid  = threadIdx.x;
    int lane = tid & 63;
    int wid  = tid >> 6;
    int wr = wid >> 1, wc = wid & 1;
    int bm = blockIdx.x * 64;

    f32x4 acc[MF][NF];
    #pragma unroll
    for (int i = 0; i < MF; i++)
        #pragma unroll
        for (int j = 0; j < NF; j++) acc[i][j] = (f32x4){0.f, 0.f, 0.f, 0.f};

    for (int k0 = 0; k0 < K; k0 += 64) {
        {
            int row = tid >> 2, q = tid & 3;
            bool valid = (bm + row) < M;
            uint32_t d[8];
            if constexpr (BF16A) {
                const uint32_t* A = (const uint32_t*)Av;
                if (valid) {
                    const uint32_t* p = A + (size_t)(bm + row) * (K >> 1) + (k0 >> 1) + q * 8;
                    uint4 u0 = *(const uint4*)p;
                    uint4 u1 = *(const uint4*)(p + 4);
                    d[0] = u0.x; d[1] = u0.y; d[2] = u0.z; d[3] = u0.w;
                    d[4] = u1.x; d[5] = u1.y; d[6] = u1.z; d[7] = u1.w;
                } else {
                    #pragma unroll
                    for (int i = 0; i < 8; i++) d[i] = 0u;
                }
            } else {
                const float* A = (const float*)Av;
                if (valid) {
                    const float* p = A + (size_t)(bm + row) * K + k0 + q * 16;
                    #pragma unroll
                    for (int i = 0; i < 4; i++) {
                        float4 f = *(const float4*)(p + i * 4);
                        d[2 * i]     = packbf(f.x, f.y);
                        d[2 * i + 1] = packbf(f.z, f.w);
                    }
                } else {
                    #pragma unroll
                    for (int i = 0; i < 8; i++) d[i] = 0u;
                }
            }
            uint4* dst = (uint4*)&Al[row][q * 8];
            dst[0] = make_uint4(d[0], d[1], d[2], d[3]);
            dst[1] = make_uint4(d[4], d[5], d[6], d[7]);
        }
        {
            constexpr int NITER = BN * 32 / 256;
            constexpr int SH = (BN == 128) ? 7 : 6;
            #pragma unroll
            for (int i = 0; i < NITER; i++) {
                int idx = tid + i * 256;
                int n = idx & (BN - 1);
                int kd = idx >> SH;
                float b0 = B[(size_t)(k0 + 2 * kd) * BN + n];
                float b1 = B[(size_t)(k0 + 2 * kd + 1) * BN + n];
                Bl[n][kd] = packbf(b0, b1);
            }
        }
        __syncthreads();
        int lr = lane & 15, lk = lane >> 4;
        #pragma unroll
        for (int ks = 0; ks < 2; ks++) {
            short8 af[MF], bf[NF];
            #pragma unroll
            for (int mf = 0; mf < MF; mf++)
                af[mf] = *(const short8*)&Al[wr * (MF * 16) + mf * 16 + lr][ks * 16 + lk * 4];
            #pragma unroll
            for (int nf = 0; nf < NF; nf++)
                bf[nf] = *(const short8*)&Bl[wc * (NF * 16) + nf * 16 + lr][ks * 16 + lk * 4];
            #pragma unroll
            for (int mf = 0; mf < MF; mf++)
                #pragma unroll
                for (int nf = 0; nf < NF; nf++)
                    acc[mf][nf] = __builtin_amdgcn_mfma_f32_16x16x32_bf16(af[mf], bf[nf], acc[mf][nf], 0, 0, 0);
        }
        __syncthreads();
    }
    int lr = lane & 15, lg = lane >> 4;
    #pragma unroll
    for (int mf = 0; mf < MF; mf++) {
        #pragma unroll
        for (int nf = 0; nf < NF; nf++) {
            int col = wc * (NF * 16) + nf * 16 + lr;
            #pragma unroll
            for (int j = 0; j < 4; j++) {
                int row = bm + wr * (MF * 16) + mf * 16 + lg * 4 + j;
                float v = acc[mf][nf][j];
                float w = __shfl_xor(v, 1);
                if (!(lane & 1) && row < M)
                    C[(size_t)row * (BN >> 1) + (col >> 1)] = packbf(v, w);
            }
        }
    }
}

// ---------------- per-node scores from bf16 h ----------------
template<int F>
__global__ void scores_kernel(const uint32_t* __restrict__ h, const float* __restrict__ a_src,
                              const float* __restrict__ a_dst, float* __restrict__ ssrc,
                              float* __restrict__ sdst, int n) {
    int wid = (blockIdx.x * blockDim.x + threadIdx.x) >> 6;
    int lane = threadIdx.x & 63;
    if (wid >= n) return;
    constexpr int RU = F / 2;
    float vs = 0.f, vd = 0.f;
    if (lane < RU) {
        uint32_t v = h[(size_t)wid * RU + lane];
        float lo = bflo(v), hi = bfhi(v);
        vs = lo * a_src[2 * lane] + hi * a_src[2 * lane + 1];
        vd = lo * a_dst[2 * lane] + hi * a_dst[2 * lane + 1];
    }
    #pragma unroll
    for (int o = 32; o; o >>= 1) { vs += __shfl_xor(vs, o); vd += __shfl_xor(vd, o); }
    if (lane == 0) { ssrc[wid] = vs; sdst[wid] = vd; }
}

// ---------------- attention softmax + aggregation (one wave per dst node) ----------------
// Fast path (deg <= 64): per-edge score/exp computed ONCE lane-parallel; accumulate loop
// 4-way unrolled so 4 independent gather loads are in flight (latency hiding).
template<int F>
__global__ __launch_bounds__(256) void attn_agg(const uint32_t* __restrict__ h,
        const float* __restrict__ ssrc, const float* __restrict__ sdst,
        const int* __restrict__ row_ptr, const int* __restrict__ csr_src,
        const float* __restrict__ bias, uint32_t* __restrict__ xout, int n) {
    int wid = (blockIdx.x * blockDim.x + threadIdx.x) >> 6;
    int lane = threadIdx.x & 63;
    if (wid >= n) return;
    int beg = row_ptr[wid], end = row_ptr[wid + 1];
    int deg = end - beg;
    float sd = sdst[wid];
    float eself = lrelu(ssrc[wid] + sd);
    constexpr int RU = F / 2;

    if (deg <= 64) {
        int p = beg + lane;
        bool act = p < end;
        int s = act ? csr_src[p] : 0;
        float e = act ? lrelu(ssrc[s] + sd) : -1e30f;
        float m = fmaxf(eself, e);
        #pragma unroll
        for (int o = 32; o; o >>= 1) m = fmaxf(m, __shfl_xor(m, o));
        float ex = act ? __expf(e - m) : 0.f;
        float dsum = ex;
        #pragma unroll
        for (int o = 32; o; o >>= 1) dsum += __shfl_xor(dsum, o);
        float exself = __expf(eself - m);
        dsum += exself;
        float inv = 1.f / dsum;
        float w = ex * inv;          // this lane's edge weight
        float wself = exself * inv;

        if constexpr (F == 128) {
            uint32_t v = h[((size_t)wid << 6) + lane];
            float acc0 = wself * bflo(v), acc1 = wself * bfhi(v);
            int j = 0;
            for (; j + 3 < deg; j += 4) {
                float w0 = __shfl(w, j),     w1 = __shfl(w, j + 1);
                float w2 = __shfl(w, j + 2), w3 = __shfl(w, j + 3);
                int   s0 = __shfl(s, j),     s1 = __shfl(s, j + 1);
                int   s2 = __shfl(s, j + 2), s3 = __shfl(s, j + 3);
                uint32_t u0 = h[((size_t)s0 << 6) + lane];
                uint32_t u1 = h[((size_t)s1 << 6) + lane];
                uint32_t u2 = h[((size_t)s2 << 6) + lane];
                uint32_t u3 = h[((size_t)s3 << 6) + lane];
                acc0 += w0 * bflo(u0) + w1 * bflo(u1) + w2 * bflo(u2) + w3 * bflo(u3);
                acc1 += w0 * bfhi(u0) + w1 * bfhi(u1) + w2 * bfhi(u2) + w3 * bfhi(u3);
            }
            for (; j < deg; ++j) {
                float wj = __shfl(w, j);
                int sj   = __shfl(s, j);
                uint32_t u = h[((size_t)sj << 6) + lane];
                acc0 += wj * bflo(u);
                acc1 += wj * bfhi(u);
            }
            float r0 = fmaxf(acc0 + bias[2 * lane], 0.f);
            float r1 = fmaxf(acc1 + bias[2 * lane + 1], 0.f);
            xout[((size_t)wid << 6) + lane] = packbf(r0, r1);
        } else {
            // two half-waves process alternating edges; lane&31 owns a dword (2 feats)
            int half = lane >> 5, i = lane & 31;
            float acc0 = 0.f, acc1 = 0.f;
            if (half == 0) {
                uint32_t v = h[((size_t)wid << 5) + i];
                acc0 = wself * bflo(v);
                acc1 = wself * bfhi(v);
            }
            int j = half;
            for (; j + 6 < deg; j += 8) {
                float w0 = __shfl(w, j),     w1 = __shfl(w, j + 2);
                float w2 = __shfl(w, j + 4), w3 = __shfl(w, j + 6);
                int   s0 = __shfl(s, j),     s1 = __shfl(s, j + 2);
                int   s2 = __shfl(s, j + 4), s3 = __shfl(s, j + 6);
                uint32_t u0 = h[((size_t)s0 << 5) + i];
                uint32_t u1 = h[((size_t)s1 << 5) + i];
                uint32_t u2 = h[((size_t)s2 << 5) + i];
                uint32_t u3 = h[((size_t)s3 << 5) + i];
                acc0 += w0 * bflo(u0) + w1 * bflo(u1) + w2 * bflo(u2) + w3 * bflo(u3);
                acc1 += w0 * bfhi(u0) + w1 * bfhi(u1) + w2 * bfhi(u2) + w3 * bfhi(u3);
            }
            for (; j < deg; j += 2) {
                float wj = __shfl(w, j);
                int sj   = __shfl(s, j);
                uint32_t u = h[((size_t)sj << 5) + i];
                acc0 += wj * bflo(u);
                acc1 += wj * bfhi(u);
            }
            acc0 += __shfl_xor(acc0, 32);
            acc1 += __shfl_xor(acc1, 32);
            if (half == 0) {
                float r0 = fmaxf(acc0 + bias[2 * i], 0.f);
                float r1 = fmaxf(acc1 + bias[2 * i + 1], 0.f);
                xout[((size_t)wid << 5) + i] = packbf(r0, r1);
            }
        }
        return;
    }

    // ---- generic path (deg > 64): 3-pass ----
    float m = eself;
    for (int p = beg + lane; p < end; p += 64)
        m = fmaxf(m, lrelu(ssrc[csr_src[p]] + sd));
    #pragma unroll
    for (int o = 32; o; o >>= 1) m = fmaxf(m, __shfl_xor(m, o));
    float dsum = (lane == 0) ? __expf(eself - m) : 0.f;
    for (int p = beg + lane; p < end; p += 64)
        dsum += __expf(lrelu(ssrc[csr_src[p]] + sd) - m);
    #pragma unroll
    for (int o = 32; o; o >>= 1) dsum += __shfl_xor(dsum, o);
    float inv = 1.f / dsum;
    float wself = __expf(eself - m) * inv;

    if constexpr (F == 128) {
        uint32_t v = h[(size_t)wid * RU + lane];
        float acc0 = wself * bflo(v), acc1 = wself * bfhi(v);
        for (int p = beg; p < end; ++p) {
            int s0 = csr_src[p];
            uint32_t v0 = h[(size_t)s0 * RU + lane];
            float w0 = __expf(lrelu(ssrc[s0] + sd) - m) * inv;
            acc0 += w0 * bflo(v0);
            acc1 += w0 * bfhi(v0);
        }
        float r0 = fmaxf(acc0 + bias[2 * lane], 0.f);
        float r1 = fmaxf(acc1 + bias[2 * lane + 1], 0.f);
        xout[(size_t)wid * RU + lane] = packbf(r0, r1);
    } else {
        int half = lane >> 5, i = lane & 31;
        float acc0 = 0.f, acc1 = 0.f;
        if (half == 0) {
            uint32_t v = h[(size_t)wid * RU + i];
            acc0 = wself * bflo(v);
            acc1 = wself * bfhi(v);
        }
        for (int p = beg + half; p < end; p += 2) {
            int s0 = csr_src[p];
            uint32_t v = h[(size_t)s0 * RU + i];
            float w0 = __expf(lrelu(ssrc[s0] + sd) - m) * inv;
            acc0 += w0 * bflo(v);
            acc1 += w0 * bfhi(v);
        }
        acc0 += __shfl_xor(acc0, 32);
        acc1 += __shfl_xor(acc1, 32);
        if (half == 0) {
            float r0 = fmaxf(acc0 + bias[2 * i], 0.f);
            float r1 = fmaxf(acc1 + bias[2 * i + 1], 0.f);
            xout[(size_t)wid * RU + i] = packbf(r0, r1);
        }
    }
}

// ---------------- mean pool (sorted batch), bf16 input ----------------
__global__ __launch_bounds__(256) void pool_kernel(const uint32_t* __restrict__ x,
                                                   const int* __restrict__ batch,
                                                   float* __restrict__ pooled, int n) {
    int g = blockIdx.x;
    int tid = threadIdx.x;
    __shared__ int s_lo, s_hi;
    if (tid == 0) {
        int lo = 0, hi = n;
        while (lo < hi) { int mid = (lo + hi) >> 1; if (batch[mid] < g) lo = mid + 1; else hi = mid; }
        s_lo = lo;
        int lo2 = lo, hi2 = n;
        while (lo2 < hi2) { int mid = (lo2 + hi2) >> 1; if (batch[mid] < g + 1) lo2 = mid + 1; else hi2 = mid; }
        s_hi = lo2;
    }
    __syncthreads();
    int lo = s_lo, hi = s_hi;
    int grp = tid >> 5, col = tid & 31;
    float a0 = 0.f, a1 = 0.f;
    for (int i = lo + grp; i < hi; i += 8) {
        uint32_t v = x[(size_t)i * 32 + col];
        a0 += bflo(v);
        a1 += bfhi(v);
    }
    __shared__ float red0[8][32], red1[8][32];
    red0[grp][col] = a0;
    red1[grp][col] = a1;
    __syncthreads();
    if (tid < 32) {
        float s0 = 0.f, s1 = 0.f;
        #pragma unroll
        for (int r = 0; r < 8; r++) { s0 += red0[r][tid]; s1 += red1[r][tid]; }
        float c = fmaxf((float)(hi - lo), 1.f);
        pooled[g * 64 + 2 * tid]     = s0 / c;
        pooled[g * 64 + 2 * tid + 1] = s1 / c;
    }
}

// ---------------- head: one thread per output element, 4 independent acc chains ----------------
__global__ __launch_bounds__(256) void head_kernel(const float* __restrict__ xs,
                                                   const float* __restrict__ xt,
                                                   const float* __restrict__ Wlin,
                                                   const float* __restrict__ blin,
                                                   float* __restrict__ out) {
    int g = blockIdx.y;
    int c = blockIdx.x * 256 + threadIdx.x;
    __shared__ float z[64];
    if (threadIdx.x < 64) z[threadIdx.x] = xs[g * 64 + threadIdx.x] + xt[g * 64 + threadIdx.x];
    __syncthreads();
    float a0 = 0.f, a1 = 0.f, a2 = 0.f, a3 = 0.f;
    #pragma unroll
    for (int k = 0; k < 64; k += 4) {
        a0 += z[k]     * Wlin[(size_t)(k)     * Lout + c];
        a1 += z[k + 1] * Wlin[(size_t)(k + 1) * Lout + c];
        a2 += z[k + 2] * Wlin[(size_t)(k + 2) * Lout + c];
        a3 += z[k + 3] * Wlin[(size_t)(k + 3) * Lout + c];
    }
    float acc = (a0 + a1) + (a2 + a3) + blin[c];
    out[(size_t)g * Lout + c] = 1.f / (1.f + expf(-acc));
}

extern "C" void kernel_launch(void* const* d_in, const int* in_sizes, int n_in,
                              void* d_out, int out_size, void* d_ws, size_t ws_size,
                              hipStream_t stream) {
    size_t off = 0;
    auto alloc = [&](size_t bytes) -> void* {
        void* p = (char*)d_ws + off;
        off += (bytes + 255) & ~(size_t)255;
        return p;
    };
    uint32_t* hbuf  = (uint32_t*)alloc((size_t)Nn * 64 * 4);
    uint32_t* xbuf  = (uint32_t*)alloc((size_t)Nn * 64 * 4);
    float* ssrc     = (float*)alloc((size_t)Nn * 4);
    float* sdst     = (float*)alloc((size_t)Nn * 4);
    int*   row_ptr  = (int*)alloc((size_t)(Nn + 1) * 4);
    int*   cur      = (int*)alloc((size_t)Nn * 4);
    int*   csr      = (int*)alloc((size_t)Ecnt * 4);
    int*   bsum     = (int*)alloc(64 * 4);
    float* xs_mean  = (float*)alloc((size_t)Gn * 64 * 4);
    float* xt_mean  = (float*)alloc((size_t)Gn * 64 * 4);

    const int EB = (Ecnt + 255) / 256;
    const int NW = (Nn * 64 + 255) / 256;
    const int NB = (Nn + 1023) / 1024;
    const int GB = (Nn + 63) / 64;

    auto run_side = [&](const float* x, const int* edges, const int* batch,
                        const float* W1, const float* a1s, const float* a1d, const float* b1,
                        const float* W2, const float* a2s, const float* a2d, const float* b2,
                        float* pooled) {
        const int* src = edges;
        const int* dst = edges + Ecnt;
        hipMemsetAsync(cur, 0, (size_t)Nn * 4, stream);
        count_kernel<<<EB, 256, 0, stream>>>(dst, cur, Ecnt);
        scan1<<<NB, 1024, 0, stream>>>(cur, row_ptr, bsum, Nn);
        scan2<<<1, 64, 0, stream>>>(bsum, NB);
        scan3<<<(Nn + 255) / 256, 256, 0, stream>>>(row_ptr, bsum, Nn, NB);
        fill_kernel<<<EB, 256, 0, stream>>>(src, dst, row_ptr, cur, csr, Ecnt);
        mfma_gemm<2, 4, 128, false><<<GB, 256, 0, stream>>>(x, W1, hbuf, Nn, Din);
        scores_kernel<128><<<NW, 256, 0, stream>>>(hbuf, a1s, a1d, ssrc, sdst, Nn);
        attn_agg<128><<<NW, 256, 0, stream>>>(hbuf, ssrc, sdst, row_ptr, csr, b1, xbuf, Nn);
        mfma_gemm<2, 2, 64, true><<<GB, 256, 0, stream>>>(xbuf, W2, hbuf, Nn, 128);
        scores_kernel<64><<<NW, 256, 0, stream>>>(hbuf, a2s, a2d, ssrc, sdst, Nn);
        attn_agg<64><<<NW, 256, 0, stream>>>(hbuf, ssrc, sdst, row_ptr, csr, b2, xbuf, Nn);
        pool_kernel<<<Gn, 256, 0, stream>>>(xbuf, batch, pooled, Nn);
    };

    const float* x_s = (const float*)d_in[0];
    const float* x_t = (const float*)d_in[1];
    const int* ei_s  = (const int*)d_in[2];
    const int* ei_t  = (const int*)d_in[3];
    const int* bat_s = (const int*)d_in[4];
    const int* bat_t = (const int*)d_in[5];

    run_side(x_s, ei_s, bat_s,
             (const float*)d_in[6], (const float*)d_in[7], (const float*)d_in[8], (const float*)d_in[9],
             (const float*)d_in[10], (const float*)d_in[11], (const float*)d_in[12], (const float*)d_in[13],
             xs_mean);
    run_side(x_t, ei_t, bat_t,
             (const float*)d_in[14], (const float*)d_in[15], (const float*)d_in[16], (const float*)d_in[17],
             (const float*)d_in[18], (const float*)d_in[19], (const float*)d_in[20], (const float*)d_in[21],
             xt_mean);

    head_kernel<<<dim3(Lout / 256, Gn), 256, 0, stream>>>(xs_mean, xt_mean,
                                        (const float*)d_in[22], (const float*)d_in[23],
                                        (float*)d_out);
}

// Round 8
// 350.235 us; speedup vs baseline: 4.4955x; 1.3347x over previous
//
#include <hip/hip_runtime.h>
#include <hip/hip_bf16.h>
#include <math.h>

constexpr int Nn   = 50000;
constexpr int Ecnt = 800000;
constexpr int Gn   = 128;
constexpr int Din  = 256;
constexpr int Lout = 1024;

constexpr int BKT_SH = 7;                       // 128 nodes per bucket
constexpr int NBKT   = (Nn + 127) >> BKT_SH;    // 391
constexpr int CHUNK  = 2048;                    // edges per partition block

typedef __attribute__((ext_vector_type(8))) short short8;   // 8 bf16 (4 VGPRs)
typedef __attribute__((ext_vector_type(4))) float f32x4;    // MFMA accumulator

__device__ __forceinline__ float lrelu(float x) { return x >= 0.f ? x : 0.2f * x; }

__device__ __forceinline__ float bflo(uint32_t v) { return __uint_as_float(v << 16); }
__device__ __forceinline__ float bfhi(uint32_t v) { return __uint_as_float(v & 0xffff0000u); }
__device__ __forceinline__ uint32_t f2bf(float f) {
    uint32_t x = __float_as_uint(f);
    return (x + 0x7fffu + ((x >> 16) & 1u)) >> 16;
}
__device__ __forceinline__ uint32_t packbf(float lo, float hi) {
    return f2bf(lo) | (f2bf(hi) << 16);
}

// ================= CSR build: bucket partition =================
// Pass A: bucket histogram (LDS-aggregated)
__global__ __launch_bounds__(256) void bkt_count(const int* __restrict__ dst,
                                                 int* __restrict__ bkt_cnt, int E) {
    __shared__ int h[NBKT];
    for (int i = threadIdx.x; i < NBKT; i += 256) h[i] = 0;
    __syncthreads();
    int base = blockIdx.x * CHUNK;
    int end = min(base + CHUNK, E);
    for (int i = base + threadIdx.x; i < end; i += 256)
        atomicAdd(&h[dst[i] >> BKT_SH], 1);
    __syncthreads();
    for (int i = threadIdx.x; i < NBKT; i += 256) {
        int c = h[i];
        if (c) atomicAdd(&bkt_cnt[i], c);
    }
}

// Pass B: exclusive scan of bucket counts (single block)
__global__ __launch_bounds__(512) void bkt_scan(const int* __restrict__ bkt_cnt,
                                                int* __restrict__ bkt_ptr,
                                                int* __restrict__ bkt_cur,
                                                int* __restrict__ row_ptr) {
    __shared__ int buf[512];
    int t = threadIdx.x;
    int v = (t < NBKT) ? bkt_cnt[t] : 0;
    buf[t] = v;
    __syncthreads();
    for (int off = 1; off < 512; off <<= 1) {
        int x = (t >= off) ? buf[t - off] : 0;
        __syncthreads();
        buf[t] += x;
        __syncthreads();
    }
    if (t < NBKT) {
        int excl = buf[t] - v;
        bkt_ptr[t] = excl;
        bkt_cur[t] = excl;
    }
    if (t == 511) {
        bkt_ptr[NBKT] = buf[511];
        row_ptr[Nn]   = buf[511];
    }
}

// Pass C: scatter edges into bucket-grouped array (block reserves per-bucket ranges)
__global__ __launch_bounds__(256) void bkt_scatter(const int* __restrict__ src,
                                                   const int* __restrict__ dst,
                                                   int* __restrict__ bkt_cur,
                                                   uint2* __restrict__ bkt_edges, int E) {
    __shared__ int h[NBKT];
    __shared__ int cur[NBKT];
    for (int i = threadIdx.x; i < NBKT; i += 256) h[i] = 0;
    __syncthreads();
    int base = blockIdx.x * CHUNK;
    int end = min(base + CHUNK, E);
    for (int i = base + threadIdx.x; i < end; i += 256)
        atomicAdd(&h[dst[i] >> BKT_SH], 1);
    __syncthreads();
    for (int i = threadIdx.x; i < NBKT; i += 256) {
        int c = h[i];
        h[i] = c ? atomicAdd(&bkt_cur[i], c) : 0;   // global base for this block's edges in bucket i
        cur[i] = 0;
    }
    __syncthreads();
    for (int i = base + threadIdx.x; i < end; i += 256) {
        int d = dst[i], b = d >> BKT_SH;
        int pos = h[b] + atomicAdd(&cur[b], 1);
        bkt_edges[pos] = make_uint2((unsigned)src[i], (unsigned)d);
    }
}

// Pass D: per-bucket finalize — node sub-histogram + scan in LDS, write row_ptr + csr
__global__ __launch_bounds__(256) void csr_finalize(const uint2* __restrict__ bkt_edges,
                                                    const int* __restrict__ bkt_ptr,
                                                    int* __restrict__ row_ptr,
                                                    int* __restrict__ csr, int n) {
    int b = blockIdx.x;
    int base = bkt_ptr[b];
    int cnt  = bkt_ptr[b + 1] - base;
    __shared__ int hist[128], curs[128], sc[128];
    int t = threadIdx.x;
    if (t < 128) hist[t] = 0;
    __syncthreads();
    for (int i = t; i < cnt; i += 256)
        atomicAdd(&hist[bkt_edges[base + i].y & 127], 1);
    __syncthreads();
    if (t < 128) sc[t] = hist[t];
    __syncthreads();
    for (int off = 1; off < 128; off <<= 1) {
        int x = (t >= off && t < 128) ? sc[t - off] : 0;
        __syncthreads();
        if (t < 128) sc[t] += x;
        __syncthreads();
    }
    if (t < 128) {
        int excl = sc[t] - hist[t];
        int node = (b << BKT_SH) + t;
        if (node < n) row_ptr[node] = base + excl;
        curs[t] = excl;
    }
    __syncthreads();
    for (int i = t; i < cnt; i += 256) {
        uint2 e = bkt_edges[base + i];
        int pos = atomicAdd(&curs[e.y & 127], 1);
        csr[base + pos] = (int)e.x;
    }
}

// ---------------- MFMA bf16 GEMM + fused per-row scores ----------------
// C[M,BN](bf16 packed) = A[M,K] @ B[K,BN];  ssrc/sdst[row] = C_row · a_src / a_dst
template<int MF, int NF, int BN, bool BF16A>
__global__ __launch_bounds__(256) void mfma_gemm(const void* __restrict__ Av,
                                                 const float* __restrict__ B,
                                                 uint32_t* __restrict__ C,
                                                 const float* __restrict__ Asrc,
                                                 const float* __restrict__ Adst,
                                                 float* __restrict__ ssrc,
                                                 float* __restrict__ sdst,
                                                 int M, int K) {
    __shared__ uint32_t Al[64][36];   // [row][k-dword], 32 dwords + 4 pad
    __shared__ uint32_t Bl[BN][36];   // [col][k-dword] (B transposed)
    __shared__ float sS[64][2], sD[64][2];
    int tid  = threadIdx.x;
    int lane = tid & 63;
    int wid  = tid >> 6;
    int wr = wid >> 1, wc = wid & 1;
    int bm = blockIdx.x * 64;

    f32x4 acc[MF][NF];
    #pragma unroll
    for (int i = 0; i < MF; i++)
        #pragma unroll
        for (int j = 0; j < NF; j++) acc[i][j] = (f32x4){0.f, 0.f, 0.f, 0.f};

    for (int k0 = 0; k0 < K; k0 += 64) {
        {
            int row = tid >> 2, q = tid & 3;
            bool valid = (bm + row) < M;
            uint32_t d[8];
            if constexpr (BF16A) {
                const uint32_t* A = (const uint32_t*)Av;
                if (valid) {
                    const uint32_t* p = A + (size_t)(bm + row) * (K >> 1) + (k0 >> 1) + q * 8;
                    uint4 u0 = *(const uint4*)p;
                    uint4 u1 = *(const uint4*)(p + 4);
                    d[0] = u0.x; d[1] = u0.y; d[2] = u0.z; d[3] = u0.w;
                    d[4] = u1.x; d[5] = u1.y; d[6] = u1.z; d[7] = u1.w;
                } else {
                    #pragma unroll
                    for (int i = 0; i < 8; i++) d[i] = 0u;
                }
            } else {
                const float* A = (const float*)Av;
                if (valid) {
                    const float* p = A + (size_t)(bm + row) * K + k0 + q * 16;
                    #pragma unroll
                    for (int i = 0; i < 4; i++) {
                        float4 f = *(const float4*)(p + i * 4);
                        d[2 * i]     = packbf(f.x, f.y);
                        d[2 * i + 1] = packbf(f.z, f.w);
                    }
                } else {
                    #pragma unroll
                    for (int i = 0; i < 8; i++) d[i] = 0u;
                }
            }
            uint4* dstp = (uint4*)&Al[row][q * 8];
            dstp[0] = make_uint4(d[0], d[1], d[2], d[3]);
            dstp[1] = make_uint4(d[4], d[5], d[6], d[7]);
        }
        {
            constexpr int NITER = BN * 32 / 256;
            constexpr int SH = (BN == 128) ? 7 : 6;
            #pragma unroll
            for (int i = 0; i < NITER; i++) {
                int idx = tid + i * 256;
                int n = idx & (BN - 1);
                int kd = idx >> SH;
                float b0 = B[(size_t)(k0 + 2 * kd) * BN + n];
                float b1 = B[(size_t)(k0 + 2 * kd + 1) * BN + n];
                Bl[n][kd] = packbf(b0, b1);
            }
        }
        __syncthreads();
        int lr = lane & 15, lk = lane >> 4;
        #pragma unroll
        for (int ks = 0; ks < 2; ks++) {
            short8 af[MF], bf[NF];
            #pragma unroll
            for (int mf = 0; mf < MF; mf++)
                af[mf] = *(const short8*)&Al[wr * (MF * 16) + mf * 16 + lr][ks * 16 + lk * 4];
            #pragma unroll
            for (int nf = 0; nf < NF; nf++)
                bf[nf] = *(const short8*)&Bl[wc * (NF * 16) + nf * 16 + lr][ks * 16 + lk * 4];
            #pragma unroll
            for (int mf = 0; mf < MF; mf++)
                #pragma unroll
                for (int nf = 0; nf < NF; nf++)
                    acc[mf][nf] = __builtin_amdgcn_mfma_f32_16x16x32_bf16(af[mf], bf[nf], acc[mf][nf], 0, 0, 0);
        }
        __syncthreads();
    }
    int lr = lane & 15, lg = lane >> 4;
    // fused scores: per-lane partial dot over its NF columns, reduce across 16 lr lanes + 2 wc waves
    {
        float a_s[NF], a_d[NF];
        #pragma unroll
        for (int nf = 0; nf < NF; nf++) {
            int col = wc * (NF * 16) + nf * 16 + lr;
            a_s[nf] = Asrc[col];
            a_d[nf] = Adst[col];
        }
        #pragma unroll
        for (int mf = 0; mf < MF; mf++) {
            #pragma unroll
            for (int j = 0; j < 4; j++) {
                float ps = 0.f, pd = 0.f;
                #pragma unroll
                for (int nf = 0; nf < NF; nf++) {
                    float v = acc[mf][nf][j];
                    ps += v * a_s[nf];
                    pd += v * a_d[nf];
                }
                #pragma unroll
                for (int o = 1; o < 16; o <<= 1) {
                    ps += __shfl_xor(ps, o);
                    pd += __shfl_xor(pd, o);
                }
                if (lr == 0) {
                    int rl = wr * (MF * 16) + mf * 16 + lg * 4 + j;
                    sS[rl][wc] = ps;
                    sD[rl][wc] = pd;
                }
            }
        }
    }
    // C write (bf16 packed via lane-pair shuffle)
    #pragma unroll
    for (int mf = 0; mf < MF; mf++) {
        #pragma unroll
        for (int nf = 0; nf < NF; nf++) {
            int col = wc * (NF * 16) + nf * 16 + lr;
            #pragma unroll
            for (int j = 0; j < 4; j++) {
                int row = bm + wr * (MF * 16) + mf * 16 + lg * 4 + j;
                float v = acc[mf][nf][j];
                float w = __shfl_xor(v, 1);
                if (!(lane & 1) && row < M)
                    C[(size_t)row * (BN >> 1) + (col >> 1)] = packbf(v, w);
            }
        }
    }
    __syncthreads();
    if (tid < 64) {
        int row = bm + tid;
        if (row < M) {
            ssrc[row] = sS[tid][0] + sS[tid][1];
            sdst[row] = sD[tid][0] + sD[tid][1];
        }
    }
}

// ---------------- attention softmax + aggregation (one wave per dst node) ----------------
template<int F>
__global__ __launch_bounds__(256) void attn_agg(const uint32_t* __restrict__ h,
        const float* __restrict__ ssrc, const float* __restrict__ sdst,
        const int* __restrict__ row_ptr, const int* __restrict__ csr_src,
        const float* __restrict__ bias, uint32_t* __restrict__ xout, int n) {
    int wid = (blockIdx.x * blockDim.x + threadIdx.x) >> 6;
    int lane = threadIdx.x & 63;
    if (wid >= n) return;
    int beg = row_ptr[wid], end = row_ptr[wid + 1];
    int deg = end - beg;
    float sd = sdst[wid];
    float eself = lrelu(ssrc[wid] + sd);
    constexpr int RU = F / 2;

    if (deg <= 64) {
        int p = beg + lane;
        bool act = p < end;
        int s = act ? csr_src[p] : 0;
        float e = act ? lrelu(ssrc[s] + sd) : -1e30f;
        float m = fmaxf(eself, e);
        #pragma unroll
        for (int o = 32; o; o >>= 1) m = fmaxf(m, __shfl_xor(m, o));
        float ex = act ? __expf(e - m) : 0.f;
        float dsum = ex;
        #pragma unroll
        for (int o = 32; o; o >>= 1) dsum += __shfl_xor(dsum, o);
        float exself = __expf(eself - m);
        dsum += exself;
        float inv = 1.f / dsum;
        float w = ex * inv;
        float wself = exself * inv;

        if constexpr (F == 128) {
            uint32_t v = h[((size_t)wid << 6) + lane];
            float acc0 = wself * bflo(v), acc1 = wself * bfhi(v);
            int j = 0;
            for (; j + 3 < deg; j += 4) {
                float w0 = __shfl(w, j),     w1 = __shfl(w, j + 1);
                float w2 = __shfl(w, j + 2), w3 = __shfl(w, j + 3);
                int   s0 = __shfl(s, j),     s1 = __shfl(s, j + 1);
                int   s2 = __shfl(s, j + 2), s3 = __shfl(s, j + 3);
                uint32_t u0 = h[((size_t)s0 << 6) + lane];
                uint32_t u1 = h[((size_t)s1 << 6) + lane];
                uint32_t u2 = h[((size_t)s2 << 6) + lane];
                uint32_t u3 = h[((size_t)s3 << 6) + lane];
                acc0 += w0 * bflo(u0) + w1 * bflo(u1) + w2 * bflo(u2) + w3 * bflo(u3);
                acc1 += w0 * bfhi(u0) + w1 * bfhi(u1) + w2 * bfhi(u2) + w3 * bfhi(u3);
            }
            for (; j < deg; ++j) {
                float wj = __shfl(w, j);
                int sj   = __shfl(s, j);
                uint32_t u = h[((size_t)sj << 6) + lane];
                acc0 += wj * bflo(u);
                acc1 += wj * bfhi(u);
            }
            float r0 = fmaxf(acc0 + bias[2 * lane], 0.f);
            float r1 = fmaxf(acc1 + bias[2 * lane + 1], 0.f);
            xout[((size_t)wid << 6) + lane] = packbf(r0, r1);
        } else {
            int half = lane >> 5, i = lane & 31;
            float acc0 = 0.f, acc1 = 0.f;
            if (half == 0) {
                uint32_t v = h[((size_t)wid << 5) + i];
                acc0 = wself * bflo(v);
                acc1 = wself * bfhi(v);
            }
            int j = half;
            for (; j + 6 < deg; j += 8) {
                float w0 = __shfl(w, j),     w1 = __shfl(w, j + 2);
                float w2 = __shfl(w, j + 4), w3 = __shfl(w, j + 6);
                int   s0 = __shfl(s, j),     s1 = __shfl(s, j + 2);
                int   s2 = __shfl(s, j + 4), s3 = __shfl(s, j + 6);
                uint32_t u0 = h[((size_t)s0 << 5) + i];
                uint32_t u1 = h[((size_t)s1 << 5) + i];
                uint32_t u2 = h[((size_t)s2 << 5) + i];
                uint32_t u3 = h[((size_t)s3 << 5) + i];
                acc0 += w0 * bflo(u0) + w1 * bflo(u1) + w2 * bflo(u2) + w3 * bflo(u3);
                acc1 += w0 * bfhi(u0) + w1 * bfhi(u1) + w2 * bfhi(u2) + w3 * bfhi(u3);
            }
            for (; j < deg; j += 2) {
                float wj = __shfl(w, j);
                int sj   = __shfl(s, j);
                uint32_t u = h[((size_t)sj << 5) + i];
                acc0 += wj * bflo(u);
                acc1 += wj * bfhi(u);
            }
            acc0 += __shfl_xor(acc0, 32);
            acc1 += __shfl_xor(acc1, 32);
            if (half == 0) {
                float r0 = fmaxf(acc0 + bias[2 * i], 0.f);
                float r1 = fmaxf(acc1 + bias[2 * i + 1], 0.f);
                xout[((size_t)wid << 5) + i] = packbf(r0, r1);
            }
        }
        return;
    }

    // generic path (deg > 64)
    float m = eself;
    for (int p = beg + lane; p < end; p += 64)
        m = fmaxf(m, lrelu(ssrc[csr_src[p]] + sd));
    #pragma unroll
    for (int o = 32; o; o >>= 1) m = fmaxf(m, __shfl_xor(m, o));
    float dsum = (lane == 0) ? __expf(eself - m) : 0.f;
    for (int p = beg + lane; p < end; p += 64)
        dsum += __expf(lrelu(ssrc[csr_src[p]] + sd) - m);
    #pragma unroll
    for (int o = 32; o; o >>= 1) dsum += __shfl_xor(dsum, o);
    float inv = 1.f / dsum;
    float wself = __expf(eself - m) * inv;

    if constexpr (F == 128) {
        uint32_t v = h[(size_t)wid * RU + lane];
        float acc0 = wself * bflo(v), acc1 = wself * bfhi(v);
        for (int p = beg; p < end; ++p) {
            int s0 = csr_src[p];
            uint32_t v0 = h[(size_t)s0 * RU + lane];
            float w0 = __expf(lrelu(ssrc[s0] + sd) - m) * inv;
            acc0 += w0 * bflo(v0);
            acc1 += w0 * bfhi(v0);
        }
        float r0 = fmaxf(acc0 + bias[2 * lane], 0.f);
        float r1 = fmaxf(acc1 + bias[2 * lane + 1], 0.f);
        xout[(size_t)wid * RU + lane] = packbf(r0, r1);
    } else {
        int half = lane >> 5, i = lane & 31;
        float acc0 = 0.f, acc1 = 0.f;
        if (half == 0) {
            uint32_t v = h[(size_t)wid * RU + i];
            acc0 = wself * bflo(v);
            acc1 = wself * bfhi(v);
        }
        for (int p = beg + half; p < end; p += 2) {
            int s0 = csr_src[p];
            uint32_t v = h[(size_t)s0 * RU + i];
            float w0 = __expf(lrelu(ssrc[s0] + sd) - m) * inv;
            acc0 += w0 * bflo(v);
            acc1 += w0 * bfhi(v);
        }
        acc0 += __shfl_xor(acc0, 32);
        acc1 += __shfl_xor(acc1, 32);
        if (half == 0) {
            float r0 = fmaxf(acc0 + bias[2 * i], 0.f);
            float r1 = fmaxf(acc1 + bias[2 * i + 1], 0.f);
            xout[(size_t)wid * RU + i] = packbf(r0, r1);
        }
    }
}

// ---------------- mean pool (sorted batch), bf16 input ----------------
__global__ __launch_bounds__(256) void pool_kernel(const uint32_t* __restrict__ x,
                                                   const int* __restrict__ batch,
                                                   float* __restrict__ pooled, int n) {
    int g = blockIdx.x;
    int tid = threadIdx.x;
    __shared__ int s_lo, s_hi;
    if (tid == 0) {
        int lo = 0, hi = n;
        while (lo < hi) { int mid = (lo + hi) >> 1; if (batch[mid] < g) lo = mid + 1; else hi = mid; }
        s_lo = lo;
        int lo2 = lo, hi2 = n;
        while (lo2 < hi2) { int mid = (lo2 + hi2) >> 1; if (batch[mid] < g + 1) lo2 = mid + 1; else hi2 = mid; }
        s_hi = lo2;
    }
    __syncthreads();
    int lo = s_lo, hi = s_hi;
    int grp = tid >> 5, col = tid & 31;
    float a0 = 0.f, a1 = 0.f;
    for (int i = lo + grp; i < hi; i += 8) {
        uint32_t v = x[(size_t)i * 32 + col];
        a0 += bflo(v);
        a1 += bfhi(v);
    }
    __shared__ float red0[8][32], red1[8][32];
    red0[grp][col] = a0;
    red1[grp][col] = a1;
    __syncthreads();
    if (tid < 32) {
        float s0 = 0.f, s1 = 0.f;
        #pragma unroll
        for (int r = 0; r < 8; r++) { s0 += red0[r][tid]; s1 += red1[r][tid]; }
        float c = fmaxf((float)(hi - lo), 1.f);
        pooled[g * 64 + 2 * tid]     = s0 / c;
        pooled[g * 64 + 2 * tid + 1] = s1 / c;
    }
}

// ---------------- head ----------------
__global__ __launch_bounds__(256) void head_kernel(const float* __restrict__ xs,
                                                   const float* __restrict__ xt,
                                                   const float* __restrict__ Wlin,
                                                   const float* __restrict__ blin,
                                                   float* __restrict__ out) {
    int g = blockIdx.y;
    int c = blockIdx.x * 256 + threadIdx.x;
    __shared__ float z[64];
    if (threadIdx.x < 64) z[threadIdx.x] = xs[g * 64 + threadIdx.x] + xt[g * 64 + threadIdx.x];
    __syncthreads();
    float a0 = 0.f, a1 = 0.f, a2 = 0.f, a3 = 0.f;
    #pragma unroll
    for (int k = 0; k < 64; k += 4) {
        a0 += z[k]     * Wlin[(size_t)(k)     * Lout + c];
        a1 += z[k + 1] * Wlin[(size_t)(k + 1) * Lout + c];
        a2 += z[k + 2] * Wlin[(size_t)(k + 2) * Lout + c];
        a3 += z[k + 3] * Wlin[(size_t)(k + 3) * Lout + c];
    }
    float acc = (a0 + a1) + (a2 + a3) + blin[c];
    out[(size_t)g * Lout + c] = 1.f / (1.f + expf(-acc));
}

extern "C" void kernel_launch(void* const* d_in, const int* in_sizes, int n_in,
                              void* d_out, int out_size, void* d_ws, size_t ws_size,
                              hipStream_t stream) {
    size_t off = 0;
    auto alloc = [&](size_t bytes) -> void* {
        void* p = (char*)d_ws + off;
        off += (bytes + 255) & ~(size_t)255;
        return p;
    };
    uint32_t* hbuf   = (uint32_t*)alloc((size_t)Nn * 64 * 4);
    uint32_t* xbuf   = (uint32_t*)alloc((size_t)Nn * 64 * 4);
    float* ssrc      = (float*)alloc((size_t)Nn * 4);
    float* sdst      = (float*)alloc((size_t)Nn * 4);
    int*   row_ptr   = (int*)alloc((size_t)(Nn + 1) * 4);
    int*   csr       = (int*)alloc((size_t)Ecnt * 4);
    uint2* bkt_edges = (uint2*)alloc((size_t)Ecnt * 8);
    int*   bkt_cnt   = (int*)alloc((size_t)(NBKT + 1) * 4);
    int*   bkt_ptr   = (int*)alloc((size_t)(NBKT + 1) * 4);
    int*   bkt_cur   = (int*)alloc((size_t)(NBKT + 1) * 4);
    float* xs_mean   = (float*)alloc((size_t)Gn * 64 * 4);
    float* xt_mean   = (float*)alloc((size_t)Gn * 64 * 4);

    const int NW  = (Nn * 64 + 255) / 256;      // wave-per-node blocks
    const int GB  = (Nn + 63) / 64;             // gemm blocks (BM=64)
    const int EBC = (Ecnt + CHUNK - 1) / CHUNK; // partition blocks (391)

    auto run_side = [&](const float* x, const int* edges, const int* batch,
                        const float* W1, const float* a1s, const float* a1d, const float* b1,
                        const float* W2, const float* a2s, const float* a2d, const float* b2,
                        float* pooled) {
        const int* src = edges;
        const int* dst = edges + Ecnt;
        // CSR build via bucket partition
        hipMemsetAsync(bkt_cnt, 0, (size_t)NBKT * 4, stream);
        bkt_count<<<EBC, 256, 0, stream>>>(dst, bkt_cnt, Ecnt);
        bkt_scan<<<1, 512, 0, stream>>>(bkt_cnt, bkt_ptr, bkt_cur, row_ptr);
        bkt_scatter<<<EBC, 256, 0, stream>>>(src, dst, bkt_cur, bkt_edges, Ecnt);
        csr_finalize<<<NBKT, 256, 0, stream>>>(bkt_edges, bkt_ptr, row_ptr, csr, Nn);
        // layer 1: 256 -> 128 (fp32 A -> bf16 MFMA), scores fused
        mfma_gemm<2, 4, 128, false><<<GB, 256, 0, stream>>>(x, W1, hbuf, a1s, a1d, ssrc, sdst, Nn, Din);
        attn_agg<128><<<NW, 256, 0, stream>>>(hbuf, ssrc, sdst, row_ptr, csr, b1, xbuf, Nn);
        // layer 2: 128 -> 64 (bf16 A), scores fused
        mfma_gemm<2, 2, 64, true><<<GB, 256, 0, stream>>>(xbuf, W2, hbuf, a2s, a2d, ssrc, sdst, Nn, 128);
        attn_agg<64><<<NW, 256, 0, stream>>>(hbuf, ssrc, sdst, row_ptr, csr, b2, xbuf, Nn);
        pool_kernel<<<Gn, 256, 0, stream>>>(xbuf, batch, pooled, Nn);
    };

    const float* x_s = (const float*)d_in[0];
    const float* x_t = (const float*)d_in[1];
    const int* ei_s  = (const int*)d_in[2];
    const int* ei_t  = (const int*)d_in[3];
    const int* bat_s = (const int*)d_in[4];
    const int* bat_t = (const int*)d_in[5];

    run_side(x_s, ei_s, bat_s,
             (const float*)d_in[6], (const float*)d_in[7], (const float*)d_in[8], (const float*)d_in[9],
             (const float*)d_in[10], (const float*)d_in[11], (const float*)d_in[12], (const float*)d_in[13],
             xs_mean);
    run_side(x_t, ei_t, bat_t,
             (const float*)d_in[14], (const float*)d_in[15], (const float*)d_in[16], (const float*)d_in[17],
             (const float*)d_in[18], (const float*)d_in[19], (const float*)d_in[20], (const float*)d_in[21],
             xt_mean);

    head_kernel<<<dim3(Lout / 256, Gn), 256, 0, stream>>>(xs_mean, xt_mean,
                                        (const float*)d_in[22], (const float*)d_in[23],
                                        (float*)d_out);
}

// Round 9
// 269.340 us; speedup vs baseline: 5.8457x; 1.3003x over previous
//
#include <hip/hip_runtime.h>
#include <hip/hip_bf16.h>
#include <math.h>

constexpr int Nn   = 50000;
constexpr int Ecnt = 800000;
constexpr int Gn   = 128;
constexpr int Din  = 256;
constexpr int Lout = 1024;

constexpr int BKT_SH = 7;                       // 128 nodes per bucket
constexpr int NBKT   = (Nn + 127) >> BKT_SH;    // 391
constexpr int CHUNK  = 2048;                    // edges per partition block
constexpr size_t HS  = (size_t)Nn * 64;         // per-side h/x stride (dwords)

typedef __attribute__((ext_vector_type(8))) short short8;   // 8 bf16 (4 VGPRs)
typedef __attribute__((ext_vector_type(4))) float f32x4;    // MFMA accumulator

__device__ __forceinline__ float lrelu(float x) { return x >= 0.f ? x : 0.2f * x; }

__device__ __forceinline__ float bflo(uint32_t v) { return __uint_as_float(v << 16); }
__device__ __forceinline__ float bfhi(uint32_t v) { return __uint_as_float(v & 0xffff0000u); }
__device__ __forceinline__ uint32_t f2bf(float f) {
    uint32_t x = __float_as_uint(f);
    return (x + 0x7fffu + ((x >> 16) & 1u)) >> 16;
}
__device__ __forceinline__ uint32_t packbf(float lo, float hi) {
    return f2bf(lo) | (f2bf(hi) << 16);
}

// ================= CSR build (both sides per dispatch, side = blockIdx.y) =================
__global__ __launch_bounds__(256) void bkt_count2(const int* __restrict__ e0,
                                                  const int* __restrict__ e1,
                                                  int* __restrict__ bkt_cnt_b, int E) {
    int side = blockIdx.y;
    const int* dst = (side ? e1 : e0) + E;
    int* bkt_cnt = bkt_cnt_b + (size_t)side * (NBKT + 1);
    __shared__ int h[NBKT];
    for (int i = threadIdx.x; i < NBKT; i += 256) h[i] = 0;
    __syncthreads();
    int base = blockIdx.x * CHUNK;
    int end = min(base + CHUNK, E);
    for (int i = base + threadIdx.x; i < end; i += 256)
        atomicAdd(&h[dst[i] >> BKT_SH], 1);
    __syncthreads();
    for (int i = threadIdx.x; i < NBKT; i += 256) {
        int c = h[i];
        if (c) atomicAdd(&bkt_cnt[i], c);
    }
}

__global__ __launch_bounds__(512) void bkt_scan2(const int* __restrict__ bkt_cnt_b,
                                                 int* __restrict__ bkt_ptr_b,
                                                 int* __restrict__ bkt_cur_b,
                                                 int* __restrict__ row_ptr_b) {
    int side = blockIdx.x;
    const int* bkt_cnt = bkt_cnt_b + (size_t)side * (NBKT + 1);
    int* bkt_ptr = bkt_ptr_b + (size_t)side * (NBKT + 1);
    int* bkt_cur = bkt_cur_b + (size_t)side * (NBKT + 1);
    int* row_ptr = row_ptr_b + (size_t)side * (Nn + 1);
    __shared__ int buf[512];
    int t = threadIdx.x;
    int v = (t < NBKT) ? bkt_cnt[t] : 0;
    buf[t] = v;
    __syncthreads();
    for (int off = 1; off < 512; off <<= 1) {
        int x = (t >= off) ? buf[t - off] : 0;
        __syncthreads();
        buf[t] += x;
        __syncthreads();
    }
    if (t < NBKT) {
        int excl = buf[t] - v;
        bkt_ptr[t] = excl;
        bkt_cur[t] = excl;
    }
    if (t == 511) {
        bkt_ptr[NBKT] = buf[511];
        row_ptr[Nn]   = buf[511];
    }
}

__global__ __launch_bounds__(256) void bkt_scatter2(const int* __restrict__ e0,
                                                    const int* __restrict__ e1,
                                                    int* __restrict__ bkt_cur_b,
                                                    uint2* __restrict__ bkt_edges_b, int E) {
    int side = blockIdx.y;
    const int* src = side ? e1 : e0;
    const int* dst = src + E;
    int* bkt_cur = bkt_cur_b + (size_t)side * (NBKT + 1);
    uint2* bkt_edges = bkt_edges_b + (size_t)side * Ecnt;
    __shared__ int h[NBKT];
    __shared__ int cur[NBKT];
    for (int i = threadIdx.x; i < NBKT; i += 256) h[i] = 0;
    __syncthreads();
    int base = blockIdx.x * CHUNK;
    int end = min(base + CHUNK, E);
    for (int i = base + threadIdx.x; i < end; i += 256)
        atomicAdd(&h[dst[i] >> BKT_SH], 1);
    __syncthreads();
    for (int i = threadIdx.x; i < NBKT; i += 256) {
        int c = h[i];
        h[i] = c ? atomicAdd(&bkt_cur[i], c) : 0;
        cur[i] = 0;
    }
    __syncthreads();
    for (int i = base + threadIdx.x; i < end; i += 256) {
        int d = dst[i], b = d >> BKT_SH;
        int pos = h[b] + atomicAdd(&cur[b], 1);
        bkt_edges[pos] = make_uint2((unsigned)src[i], (unsigned)d);
    }
}

__global__ __launch_bounds__(256) void csr_finalize2(const uint2* __restrict__ bkt_edges_b,
                                                     const int* __restrict__ bkt_ptr_b,
                                                     int* __restrict__ row_ptr_b,
                                                     int* __restrict__ csr_b, int n) {
    int side = blockIdx.y;
    const uint2* bkt_edges = bkt_edges_b + (size_t)side * Ecnt;
    const int* bkt_ptr = bkt_ptr_b + (size_t)side * (NBKT + 1);
    int* row_ptr = row_ptr_b + (size_t)side * (Nn + 1);
    int* csr = csr_b + (size_t)side * Ecnt;
    int b = blockIdx.x;
    int base = bkt_ptr[b];
    int cnt  = bkt_ptr[b + 1] - base;
    __shared__ int hist[128], curs[128], sc[128];
    int t = threadIdx.x;
    if (t < 128) hist[t] = 0;
    __syncthreads();
    for (int i = t; i < cnt; i += 256)
        atomicAdd(&hist[bkt_edges[base + i].y & 127], 1);
    __syncthreads();
    if (t < 128) sc[t] = hist[t];
    __syncthreads();
    for (int off = 1; off < 128; off <<= 1) {
        int x = (t >= off && t < 128) ? sc[t - off] : 0;
        __syncthreads();
        if (t < 128) sc[t] += x;
        __syncthreads();
    }
    if (t < 128) {
        int excl = sc[t] - hist[t];
        int node = (b << BKT_SH) + t;
        if (node < n) row_ptr[node] = base + excl;
        curs[t] = excl;
    }
    __syncthreads();
    for (int i = t; i < cnt; i += 256) {
        uint2 e = bkt_edges[base + i];
        int pos = atomicAdd(&curs[e.y & 127], 1);
        csr[base + pos] = (int)e.x;
    }
}

// ---------------- MFMA bf16 GEMM + fused scores, both sides, reg double-buffer ----------------
template<int MF, int NF, int BN, bool BF16A>
__global__ __launch_bounds__(256) void mfma_gemm2(
        const void* __restrict__ A0, const void* __restrict__ A1,
        const float* __restrict__ B0, const float* __restrict__ B1,
        uint32_t* __restrict__ Cb, size_t cstride,
        const float* __restrict__ as0, const float* __restrict__ as1,
        const float* __restrict__ ad0, const float* __restrict__ ad1,
        float* __restrict__ ssrc_b, float* __restrict__ sdst_b,
        int M, int K) {
    __shared__ uint32_t Al[64][36];
    __shared__ uint32_t Bl[BN][36];
    __shared__ float sS[64][2], sD[64][2];
    int side = blockIdx.y;
    const void* Av = side ? A1 : A0;
    const float* B = side ? B1 : B0;
    const float* Asrc = side ? as1 : as0;
    const float* Adst = side ? ad1 : ad0;
    uint32_t* C = Cb + (size_t)side * cstride;
    float* ssrc = ssrc_b + (size_t)side * Nn;
    float* sdst = sdst_b + (size_t)side * Nn;

    int tid  = threadIdx.x;
    int lane = tid & 63;
    int wid  = tid >> 6;
    int wr = wid >> 1, wc = wid & 1;
    int bm = blockIdx.x * 64;

    int arow = tid >> 2, aq = tid & 3;
    bool avalid = (bm + arow) < M;
    constexpr int NPI = BN * 16 / 256;     // B pair-iters per thread: 8 (BN=128) / 4 (BN=64)

    float    fA[16];                       // fp32 A staging regs
    uint32_t uA[8];                        // bf16 A staging regs
    float    fB[NPI][4];

    auto LOADA = [&](int k0) {
        if constexpr (BF16A) {
            const uint32_t* A = (const uint32_t*)Av;
            if (avalid) {
                const uint32_t* p = A + (size_t)(bm + arow) * (K >> 1) + (k0 >> 1) + aq * 8;
                uint4 u0 = *(const uint4*)p;
                uint4 u1 = *(const uint4*)(p + 4);
                uA[0] = u0.x; uA[1] = u0.y; uA[2] = u0.z; uA[3] = u0.w;
                uA[4] = u1.x; uA[5] = u1.y; uA[6] = u1.z; uA[7] = u1.w;
            } else {
                #pragma unroll
                for (int i = 0; i < 8; i++) uA[i] = 0u;
            }
        } else {
            const float* A = (const float*)Av;
            if (avalid) {
                const float* p = A + (size_t)(bm + arow) * K + k0 + aq * 16;
                #pragma unroll
                for (int i = 0; i < 4; i++) {
                    float4 f = *(const float4*)(p + i * 4);
                    fA[4 * i] = f.x; fA[4 * i + 1] = f.y; fA[4 * i + 2] = f.z; fA[4 * i + 3] = f.w;
                }
            } else {
                #pragma unroll
                for (int i = 0; i < 16; i++) fA[i] = 0.f;
            }
        }
    };
    auto LOADB = [&](int k0) {
        #pragma unroll
        for (int it = 0; it < NPI; it++) {
            int pi = tid + it * 256;
            int n = pi & (BN - 1);
            int kp = pi / BN;                  // 0..15
            const float* p = B + (size_t)(k0 + 4 * kp) * BN + n;
            fB[it][0] = p[0];
            fB[it][1] = p[BN];
            fB[it][2] = p[2 * BN];
            fB[it][3] = p[3 * BN];
        }
    };
    auto WRITE = [&]() {
        if constexpr (BF16A) {
            uint4* dst = (uint4*)&Al[arow][aq * 8];
            dst[0] = make_uint4(uA[0], uA[1], uA[2], uA[3]);
            dst[1] = make_uint4(uA[4], uA[5], uA[6], uA[7]);
        } else {
            uint32_t d[8];
            #pragma unroll
            for (int i = 0; i < 8; i++) d[i] = packbf(fA[2 * i], fA[2 * i + 1]);
            uint4* dst = (uint4*)&Al[arow][aq * 8];
            dst[0] = make_uint4(d[0], d[1], d[2], d[3]);
            dst[1] = make_uint4(d[4], d[5], d[6], d[7]);
        }
        #pragma unroll
        for (int it = 0; it < NPI; it++) {
            int pi = tid + it * 256;
            int n = pi & (BN - 1);
            int kp = pi / BN;
            *(uint2*)&Bl[n][2 * kp] = make_uint2(packbf(fB[it][0], fB[it][1]),
                                                 packbf(fB[it][2], fB[it][3]));
        }
    };

    f32x4 acc[MF][NF];
    #pragma unroll
    for (int i = 0; i < MF; i++)
        #pragma unroll
        for (int j = 0; j < NF; j++) acc[i][j] = (f32x4){0.f, 0.f, 0.f, 0.f};

    LOADA(0); LOADB(0);
    const int T = K / 64;
    for (int t = 0; t < T; t++) {
        WRITE();
        __syncthreads();
        if (t + 1 < T) { LOADA((t + 1) * 64); LOADB((t + 1) * 64); }
        int lr = lane & 15, lk = lane >> 4;
        #pragma unroll
        for (int ks = 0; ks < 2; ks++) {
            short8 af[MF], bf[NF];
            #pragma unroll
            for (int mf = 0; mf < MF; mf++)
                af[mf] = *(const short8*)&Al[wr * (MF * 16) + mf * 16 + lr][ks * 16 + lk * 4];
            #pragma unroll
            for (int nf = 0; nf < NF; nf++)
                bf[nf] = *(const short8*)&Bl[wc * (NF * 16) + nf * 16 + lr][ks * 16 + lk * 4];
            #pragma unroll
            for (int mf = 0; mf < MF; mf++)
                #pragma unroll
                for (int nf = 0; nf < NF; nf++)
                    acc[mf][nf] = __builtin_amdgcn_mfma_f32_16x16x32_bf16(af[mf], bf[nf], acc[mf][nf], 0, 0, 0);
        }
        __syncthreads();
    }

    int lr = lane & 15, lg = lane >> 4;
    // fused scores
    {
        float a_s[NF], a_d[NF];
        #pragma unroll
        for (int nf = 0; nf < NF; nf++) {
            int col = wc * (NF * 16) + nf * 16 + lr;
            a_s[nf] = Asrc[col];
            a_d[nf] = Adst[col];
        }
        #pragma unroll
        for (int mf = 0; mf < MF; mf++) {
            #pragma unroll
            for (int j = 0; j < 4; j++) {
                float ps = 0.f, pd = 0.f;
                #pragma unroll
                for (int nf = 0; nf < NF; nf++) {
                    float v = acc[mf][nf][j];
                    ps += v * a_s[nf];
                    pd += v * a_d[nf];
                }
                #pragma unroll
                for (int o = 1; o < 16; o <<= 1) {
                    ps += __shfl_xor(ps, o);
                    pd += __shfl_xor(pd, o);
                }
                if (lr == 0) {
                    int rl = wr * (MF * 16) + mf * 16 + lg * 4 + j;
                    sS[rl][wc] = ps;
                    sD[rl][wc] = pd;
                }
            }
        }
    }
    // C write (bf16 packed via lane-pair shuffle)
    #pragma unroll
    for (int mf = 0; mf < MF; mf++) {
        #pragma unroll
        for (int nf = 0; nf < NF; nf++) {
            int col = wc * (NF * 16) + nf * 16 + lr;
            #pragma unroll
            for (int j = 0; j < 4; j++) {
                int row = bm + wr * (MF * 16) + mf * 16 + lg * 4 + j;
                float v = acc[mf][nf][j];
                float w = __shfl_xor(v, 1);
                if (!(lane & 1) && row < M)
                    C[(size_t)row * (BN >> 1) + (col >> 1)] = packbf(v, w);
            }
        }
    }
    __syncthreads();
    if (tid < 64) {
        int row = bm + tid;
        if (row < M) {
            ssrc[row] = sS[tid][0] + sS[tid][1];
            sdst[row] = sD[tid][0] + sD[tid][1];
        }
    }
}

// ---------------- attention softmax + aggregation (one wave per dst node, both sides) ----------------
template<int F>
__global__ __launch_bounds__(256) void attn_agg2(const uint32_t* __restrict__ hb,
        const float* __restrict__ ssrc_b, const float* __restrict__ sdst_b,
        const int* __restrict__ row_ptr_b, const int* __restrict__ csr_b,
        const float* __restrict__ bias0, const float* __restrict__ bias1,
        uint32_t* __restrict__ xout_b, int n) {
    int side = blockIdx.y;
    const uint32_t* h = hb + (size_t)side * HS;
    const float* ssrc = ssrc_b + (size_t)side * Nn;
    const float* sdst = sdst_b + (size_t)side * Nn;
    const int* row_ptr = row_ptr_b + (size_t)side * (Nn + 1);
    const int* csr_src = csr_b + (size_t)side * Ecnt;
    const float* bias = side ? bias1 : bias0;
    uint32_t* xout = xout_b + (size_t)side * HS;

    int wid = (blockIdx.x * blockDim.x + threadIdx.x) >> 6;
    int lane = threadIdx.x & 63;
    if (wid >= n) return;
    int beg = row_ptr[wid], end = row_ptr[wid + 1];
    int deg = end - beg;
    float sd = sdst[wid];
    float eself = lrelu(ssrc[wid] + sd);
    constexpr int RU = F / 2;

    if (deg <= 64) {
        int p = beg + lane;
        bool act = p < end;
        int s = act ? csr_src[p] : 0;
        float e = act ? lrelu(ssrc[s] + sd) : -1e30f;
        float m = fmaxf(eself, e);
        #pragma unroll
        for (int o = 32; o; o >>= 1) m = fmaxf(m, __shfl_xor(m, o));
        float ex = act ? __expf(e - m) : 0.f;
        float dsum = ex;
        #pragma unroll
        for (int o = 32; o; o >>= 1) dsum += __shfl_xor(dsum, o);
        float exself = __expf(eself - m);
        dsum += exself;
        float inv = 1.f / dsum;
        float w = ex * inv;
        float wself = exself * inv;

        if constexpr (F == 128) {
            uint32_t v = h[((size_t)wid << 6) + lane];
            float acc0 = wself * bflo(v), acc1 = wself * bfhi(v);
            int j = 0;
            for (; j + 3 < deg; j += 4) {
                float w0 = __shfl(w, j),     w1 = __shfl(w, j + 1);
                float w2 = __shfl(w, j + 2), w3 = __shfl(w, j + 3);
                int   s0 = __shfl(s, j),     s1 = __shfl(s, j + 1);
                int   s2 = __shfl(s, j + 2), s3 = __shfl(s, j + 3);
                uint32_t u0 = h[((size_t)s0 << 6) + lane];
                uint32_t u1 = h[((size_t)s1 << 6) + lane];
                uint32_t u2 = h[((size_t)s2 << 6) + lane];
                uint32_t u3 = h[((size_t)s3 << 6) + lane];
                acc0 += w0 * bflo(u0) + w1 * bflo(u1) + w2 * bflo(u2) + w3 * bflo(u3);
                acc1 += w0 * bfhi(u0) + w1 * bfhi(u1) + w2 * bfhi(u2) + w3 * bfhi(u3);
            }
            for (; j < deg; ++j) {
                float wj = __shfl(w, j);
                int sj   = __shfl(s, j);
                uint32_t u = h[((size_t)sj << 6) + lane];
                acc0 += wj * bflo(u);
                acc1 += wj * bfhi(u);
            }
            float r0 = fmaxf(acc0 + bias[2 * lane], 0.f);
            float r1 = fmaxf(acc1 + bias[2 * lane + 1], 0.f);
            xout[((size_t)wid << 6) + lane] = packbf(r0, r1);
        } else {
            int half = lane >> 5, i = lane & 31;
            float acc0 = 0.f, acc1 = 0.f;
            if (half == 0) {
                uint32_t v = h[((size_t)wid << 5) + i];
                acc0 = wself * bflo(v);
                acc1 = wself * bfhi(v);
            }
            int j = half;
            for (; j + 6 < deg; j += 8) {
                float w0 = __shfl(w, j),     w1 = __shfl(w, j + 2);
                float w2 = __shfl(w, j + 4), w3 = __shfl(w, j + 6);
                int   s0 = __shfl(s, j),     s1 = __shfl(s, j + 2);
                int   s2 = __shfl(s, j + 4), s3 = __shfl(s, j + 6);
                uint32_t u0 = h[((size_t)s0 << 5) + i];
                uint32_t u1 = h[((size_t)s1 << 5) + i];
                uint32_t u2 = h[((size_t)s2 << 5) + i];
                uint32_t u3 = h[((size_t)s3 << 5) + i];
                acc0 += w0 * bflo(u0) + w1 * bflo(u1) + w2 * bflo(u2) + w3 * bflo(u3);
                acc1 += w0 * bfhi(u0) + w1 * bfhi(u1) + w2 * bfhi(u2) + w3 * bfhi(u3);
            }
            for (; j < deg; j += 2) {
                float wj = __shfl(w, j);
                int sj   = __shfl(s, j);
                uint32_t u = h[((size_t)sj << 5) + i];
                acc0 += wj * bflo(u);
                acc1 += wj * bfhi(u);
            }
            acc0 += __shfl_xor(acc0, 32);
            acc1 += __shfl_xor(acc1, 32);
            if (half == 0) {
                float r0 = fmaxf(acc0 + bias[2 * i], 0.f);
                float r1 = fmaxf(acc1 + bias[2 * i + 1], 0.f);
                xout[((size_t)wid << 5) + i] = packbf(r0, r1);
            }
        }
        return;
    }

    // generic path (deg > 64)
    float m = eself;
    for (int p = beg + lane; p < end; p += 64)
        m = fmaxf(m, lrelu(ssrc[csr_src[p]] + sd));
    #pragma unroll
    for (int o = 32; o; o >>= 1) m = fmaxf(m, __shfl_xor(m, o));
    float dsum = (lane == 0) ? __expf(eself - m) : 0.f;
    for (int p = beg + lane; p < end; p += 64)
        dsum += __expf(lrelu(ssrc[csr_src[p]] + sd) - m);
    #pragma unroll
    for (int o = 32; o; o >>= 1) dsum += __shfl_xor(dsum, o);
    float inv = 1.f / dsum;
    float wself = __expf(eself - m) * inv;

    if constexpr (F == 128) {
        uint32_t v = h[(size_t)wid * RU + lane];
        float acc0 = wself * bflo(v), acc1 = wself * bfhi(v);
        for (int p = beg; p < end; ++p) {
            int s0 = csr_src[p];
            uint32_t v0 = h[(size_t)s0 * RU + lane];
            float w0 = __expf(lrelu(ssrc[s0] + sd) - m) * inv;
            acc0 += w0 * bflo(v0);
            acc1 += w0 * bfhi(v0);
        }
        float r0 = fmaxf(acc0 + bias[2 * lane], 0.f);
        float r1 = fmaxf(acc1 + bias[2 * lane + 1], 0.f);
        xout[(size_t)wid * RU + lane] = packbf(r0, r1);
    } else {
        int half = lane >> 5, i = lane & 31;
        float acc0 = 0.f, acc1 = 0.f;
        if (half == 0) {
            uint32_t v = h[(size_t)wid * RU + i];
            acc0 = wself * bflo(v);
            acc1 = wself * bfhi(v);
        }
        for (int p = beg + half; p < end; p += 2) {
            int s0 = csr_src[p];
            uint32_t v = h[(size_t)s0 * RU + i];
            float w0 = __expf(lrelu(ssrc[s0] + sd) - m) * inv;
            acc0 += w0 * bflo(v);
            acc1 += w0 * bfhi(v);
        }
        acc0 += __shfl_xor(acc0, 32);
        acc1 += __shfl_xor(acc1, 32);
        if (half == 0) {
            float r0 = fmaxf(acc0 + bias[2 * i], 0.f);
            float r1 = fmaxf(acc1 + bias[2 * i + 1], 0.f);
            xout[(size_t)wid * RU + i] = packbf(r0, r1);
        }
    }
}

// ---------------- mean pool (sorted batch), both sides ----------------
__global__ __launch_bounds__(256) void pool2(const uint32_t* __restrict__ xb,
                                             const int* __restrict__ bat0,
                                             const int* __restrict__ bat1,
                                             float* __restrict__ pooled_b, int n) {
    int side = blockIdx.y;
    const uint32_t* x = xb + (size_t)side * HS;
    const int* batch = side ? bat1 : bat0;
    float* pooled = pooled_b + (size_t)side * Gn * 64;
    int g = blockIdx.x;
    int tid = threadIdx.x;
    __shared__ int s_lo, s_hi;
    if (tid == 0) {
        int lo = 0, hi = n;
        while (lo < hi) { int mid = (lo + hi) >> 1; if (batch[mid] < g) lo = mid + 1; else hi = mid; }
        s_lo = lo;
        int lo2 = lo, hi2 = n;
        while (lo2 < hi2) { int mid = (lo2 + hi2) >> 1; if (batch[mid] < g + 1) lo2 = mid + 1; else hi2 = mid; }
        s_hi = lo2;
    }
    __syncthreads();
    int lo = s_lo, hi = s_hi;
    int grp = tid >> 5, col = tid & 31;
    float a0 = 0.f, a1 = 0.f;
    for (int i = lo + grp; i < hi; i += 8) {
        uint32_t v = x[(size_t)i * 32 + col];
        a0 += bflo(v);
        a1 += bfhi(v);
    }
    __shared__ float red0[8][32], red1[8][32];
    red0[grp][col] = a0;
    red1[grp][col] = a1;
    __syncthreads();
    if (tid < 32) {
        float s0 = 0.f, s1 = 0.f;
        #pragma unroll
        for (int r = 0; r < 8; r++) { s0 += red0[r][tid]; s1 += red1[r][tid]; }
        float c = fmaxf((float)(hi - lo), 1.f);
        pooled[g * 64 + 2 * tid]     = s0 / c;
        pooled[g * 64 + 2 * tid + 1] = s1 / c;
    }
}

// ---------------- head ----------------
__global__ __launch_bounds__(256) void head_kernel(const float* __restrict__ xs,
                                                   const float* __restrict__ xt,
                                                   const float* __restrict__ Wlin,
                                                   const float* __restrict__ blin,
                                                   float* __restrict__ out) {
    int g = blockIdx.y;
    int c = blockIdx.x * 256 + threadIdx.x;
    __shared__ float z[64];
    if (threadIdx.x < 64) z[threadIdx.x] = xs[g * 64 + threadIdx.x] + xt[g * 64 + threadIdx.x];
    __syncthreads();
    float a0 = 0.f, a1 = 0.f, a2 = 0.f, a3 = 0.f;
    #pragma unroll
    for (int k = 0; k < 64; k += 4) {
        a0 += z[k]     * Wlin[(size_t)(k)     * Lout + c];
        a1 += z[k + 1] * Wlin[(size_t)(k + 1) * Lout + c];
        a2 += z[k + 2] * Wlin[(size_t)(k + 2) * Lout + c];
        a3 += z[k + 3] * Wlin[(size_t)(k + 3) * Lout + c];
    }
    float acc = (a0 + a1) + (a2 + a3) + blin[c];
    out[(size_t)g * Lout + c] = 1.f / (1.f + expf(-acc));
}

extern "C" void kernel_launch(void* const* d_in, const int* in_sizes, int n_in,
                              void* d_out, int out_size, void* d_ws, size_t ws_size,
                              hipStream_t stream) {
    size_t off = 0;
    auto alloc = [&](size_t bytes) -> void* {
        void* p = (char*)d_ws + off;
        off += (bytes + 255) & ~(size_t)255;
        return p;
    };
    uint32_t* hbuf   = (uint32_t*)alloc(2 * HS * 4);
    uint32_t* xbuf   = (uint32_t*)alloc(2 * HS * 4);
    float* ssrc      = (float*)alloc(2 * (size_t)Nn * 4);
    float* sdst      = (float*)alloc(2 * (size_t)Nn * 4);
    int*   row_ptr   = (int*)alloc(2 * (size_t)(Nn + 1) * 4);
    int*   csr       = (int*)alloc(2 * (size_t)Ecnt * 4);
    uint2* bkt_edges = (uint2*)alloc(2 * (size_t)Ecnt * 8);
    int*   bkt_cnt   = (int*)alloc(2 * (size_t)(NBKT + 1) * 4);
    int*   bkt_ptr   = (int*)alloc(2 * (size_t)(NBKT + 1) * 4);
    int*   bkt_cur   = (int*)alloc(2 * (size_t)(NBKT + 1) * 4);
    float* pooled    = (float*)alloc(2 * (size_t)Gn * 64 * 4);

    const int NW  = (Nn * 64 + 255) / 256;      // wave-per-node blocks
    const int GB  = (Nn + 63) / 64;             // gemm blocks (BM=64)
    const int EBC = (Ecnt + CHUNK - 1) / CHUNK; // partition blocks (391)

    const float* x_s = (const float*)d_in[0];
    const float* x_t = (const float*)d_in[1];
    const int* ei_s  = (const int*)d_in[2];
    const int* ei_t  = (const int*)d_in[3];
    const int* bat_s = (const int*)d_in[4];
    const int* bat_t = (const int*)d_in[5];
    const float *Ws1 = (const float*)d_in[6],  *as1s = (const float*)d_in[7],
                *as1d = (const float*)d_in[8],  *bs1 = (const float*)d_in[9];
    const float *Ws2 = (const float*)d_in[10], *as2s = (const float*)d_in[11],
                *as2d = (const float*)d_in[12], *bs2 = (const float*)d_in[13];
    const float *Wt1 = (const float*)d_in[14], *at1s = (const float*)d_in[15],
                *at1d = (const float*)d_in[16], *bt1 = (const float*)d_in[17];
    const float *Wt2 = (const float*)d_in[18], *at2s = (const float*)d_in[19],
                *at2d = (const float*)d_in[20], *bt2 = (const float*)d_in[21];
    const float *Wlin = (const float*)d_in[22], *blin = (const float*)d_in[23];

    // ---- CSR build (both sides) ----
    hipMemsetAsync(bkt_cnt, 0, 2 * (size_t)(NBKT + 1) * 4, stream);
    bkt_count2<<<dim3(EBC, 2), 256, 0, stream>>>(ei_s, ei_t, bkt_cnt, Ecnt);
    bkt_scan2<<<2, 512, 0, stream>>>(bkt_cnt, bkt_ptr, bkt_cur, row_ptr);
    bkt_scatter2<<<dim3(EBC, 2), 256, 0, stream>>>(ei_s, ei_t, bkt_cur, bkt_edges, Ecnt);
    csr_finalize2<<<dim3(NBKT, 2), 256, 0, stream>>>(bkt_edges, bkt_ptr, row_ptr, csr, Nn);
    // ---- layer 1: 256 -> 128 (fp32 A), scores fused ----
    mfma_gemm2<2, 4, 128, false><<<dim3(GB, 2), 256, 0, stream>>>(
        x_s, x_t, Ws1, Wt1, hbuf, HS, as1s, at1s, as1d, at1d, ssrc, sdst, Nn, Din);
    attn_agg2<128><<<dim3(NW, 2), 256, 0, stream>>>(hbuf, ssrc, sdst, row_ptr, csr, bs1, bt1, xbuf, Nn);
    // ---- layer 2: 128 -> 64 (bf16 A), scores fused ----
    mfma_gemm2<2, 2, 64, true><<<dim3(GB, 2), 256, 0, stream>>>(
        xbuf, xbuf + HS, Ws2, Wt2, hbuf, HS, as2s, at2s, as2d, at2d, ssrc, sdst, Nn, 128);
    attn_agg2<64><<<dim3(NW, 2), 256, 0, stream>>>(hbuf, ssrc, sdst, row_ptr, csr, bs2, bt2, xbuf, Nn);
    // ---- pool + head ----
    pool2<<<dim3(Gn, 2), 256, 0, stream>>>(xbuf, bat_s, bat_t, pooled, Nn);
    head_kernel<<<dim3(Lout / 256, Gn), 256, 0, stream>>>(pooled, pooled + (size_t)Gn * 64,
                                                          Wlin, blin, (float*)d_out);
}

// Round 10
// 269.064 us; speedup vs baseline: 5.8517x; 1.0010x over previous
//
#include <hip/hip_runtime.h>
#include <hip/hip_bf16.h>
#include <math.h>

constexpr int Nn   = 50000;
constexpr int Ecnt = 800000;
constexpr int Gn   = 128;
constexpr int Din  = 256;
constexpr int Lout = 1024;

constexpr int BKT_SH = 7;                       // 128 nodes per bucket
constexpr int NBKT   = (Nn + 127) >> BKT_SH;    // 391
constexpr int CHUNK  = 2048;                    // edges per partition block
constexpr size_t HS  = (size_t)Nn * 64;         // per-side h/x stride (dwords)

typedef __attribute__((ext_vector_type(8))) short short8;   // 8 bf16 (4 VGPRs)
typedef __attribute__((ext_vector_type(4))) float f32x4;    // MFMA accumulator

__device__ __forceinline__ float lrelu(float x) { return x >= 0.f ? x : 0.2f * x; }

__device__ __forceinline__ float bflo(uint32_t v) { return __uint_as_float(v << 16); }
__device__ __forceinline__ float bfhi(uint32_t v) { return __uint_as_float(v & 0xffff0000u); }
__device__ __forceinline__ uint32_t f2bf(float f) {
    uint32_t x = __float_as_uint(f);
    return (x + 0x7fffu + ((x >> 16) & 1u)) >> 16;
}
__device__ __forceinline__ uint32_t packbf(float lo, float hi) {
    return f2bf(lo) | (f2bf(hi) << 16);
}

// ================= CSR build (both sides per dispatch, side = blockIdx.y) =================
__global__ __launch_bounds__(256) void bkt_count2(const int* __restrict__ e0,
                                                  const int* __restrict__ e1,
                                                  int* __restrict__ bkt_cnt_b, int E) {
    int side = blockIdx.y;
    const int* dst = (side ? e1 : e0) + E;
    int* bkt_cnt = bkt_cnt_b + (size_t)side * (NBKT + 1);
    __shared__ int h[NBKT];
    for (int i = threadIdx.x; i < NBKT; i += 256) h[i] = 0;
    __syncthreads();
    int base = blockIdx.x * CHUNK;
    int end = min(base + CHUNK, E);
    for (int i = base + threadIdx.x; i < end; i += 256)
        atomicAdd(&h[dst[i] >> BKT_SH], 1);
    __syncthreads();
    for (int i = threadIdx.x; i < NBKT; i += 256) {
        int c = h[i];
        if (c) atomicAdd(&bkt_cnt[i], c);
    }
}

__global__ __launch_bounds__(512) void bkt_scan2(const int* __restrict__ bkt_cnt_b,
                                                 int* __restrict__ bkt_ptr_b,
                                                 int* __restrict__ bkt_cur_b,
                                                 int* __restrict__ row_ptr_b) {
    int side = blockIdx.x;
    const int* bkt_cnt = bkt_cnt_b + (size_t)side * (NBKT + 1);
    int* bkt_ptr = bkt_ptr_b + (size_t)side * (NBKT + 1);
    int* bkt_cur = bkt_cur_b + (size_t)side * (NBKT + 1);
    int* row_ptr = row_ptr_b + (size_t)side * (Nn + 1);
    __shared__ int buf[512];
    int t = threadIdx.x;
    int v = (t < NBKT) ? bkt_cnt[t] : 0;
    buf[t] = v;
    __syncthreads();
    for (int off = 1; off < 512; off <<= 1) {
        int x = (t >= off) ? buf[t - off] : 0;
        __syncthreads();
        buf[t] += x;
        __syncthreads();
    }
    if (t < NBKT) {
        int excl = buf[t] - v;
        bkt_ptr[t] = excl;
        bkt_cur[t] = excl;
    }
    if (t == 511) {
        bkt_ptr[NBKT] = buf[511];
        row_ptr[Nn]   = buf[511];
    }
}

__global__ __launch_bounds__(256) void bkt_scatter2(const int* __restrict__ e0,
                                                    const int* __restrict__ e1,
                                                    int* __restrict__ bkt_cur_b,
                                                    uint2* __restrict__ bkt_edges_b, int E) {
    int side = blockIdx.y;
    const int* src = side ? e1 : e0;
    const int* dst = src + E;
    int* bkt_cur = bkt_cur_b + (size_t)side * (NBKT + 1);
    uint2* bkt_edges = bkt_edges_b + (size_t)side * Ecnt;
    __shared__ int h[NBKT];
    __shared__ int cur[NBKT];
    for (int i = threadIdx.x; i < NBKT; i += 256) h[i] = 0;
    __syncthreads();
    int base = blockIdx.x * CHUNK;
    int end = min(base + CHUNK, E);
    for (int i = base + threadIdx.x; i < end; i += 256)
        atomicAdd(&h[dst[i] >> BKT_SH], 1);
    __syncthreads();
    for (int i = threadIdx.x; i < NBKT; i += 256) {
        int c = h[i];
        h[i] = c ? atomicAdd(&bkt_cur[i], c) : 0;
        cur[i] = 0;
    }
    __syncthreads();
    for (int i = base + threadIdx.x; i < end; i += 256) {
        int d = dst[i], b = d >> BKT_SH;
        int pos = h[b] + atomicAdd(&cur[b], 1);
        bkt_edges[pos] = make_uint2((unsigned)src[i], (unsigned)d);
    }
}

__global__ __launch_bounds__(256) void csr_finalize2(const uint2* __restrict__ bkt_edges_b,
                                                     const int* __restrict__ bkt_ptr_b,
                                                     int* __restrict__ row_ptr_b,
                                                     int* __restrict__ csr_b, int n) {
    int side = blockIdx.y;
    const uint2* bkt_edges = bkt_edges_b + (size_t)side * Ecnt;
    const int* bkt_ptr = bkt_ptr_b + (size_t)side * (NBKT + 1);
    int* row_ptr = row_ptr_b + (size_t)side * (Nn + 1);
    int* csr = csr_b + (size_t)side * Ecnt;
    int b = blockIdx.x;
    int base = bkt_ptr[b];
    int cnt  = bkt_ptr[b + 1] - base;
    __shared__ int hist[128], curs[128], sc[128];
    int t = threadIdx.x;
    if (t < 128) hist[t] = 0;
    __syncthreads();
    for (int i = t; i < cnt; i += 256)
        atomicAdd(&hist[bkt_edges[base + i].y & 127], 1);
    __syncthreads();
    if (t < 128) sc[t] = hist[t];
    __syncthreads();
    for (int off = 1; off < 128; off <<= 1) {
        int x = (t >= off && t < 128) ? sc[t - off] : 0;
        __syncthreads();
        if (t < 128) sc[t] += x;
        __syncthreads();
    }
    if (t < 128) {
        int excl = sc[t] - hist[t];
        int node = (b << BKT_SH) + t;
        if (node < n) row_ptr[node] = base + excl;
        curs[t] = excl;
    }
    __syncthreads();
    for (int i = t; i < cnt; i += 256) {
        uint2 e = bkt_edges[base + i];
        int pos = atomicAdd(&curs[e.y & 127], 1);
        csr[base + pos] = (int)e.x;
    }
}

// ---------------- MFMA bf16 GEMM + fused scores, both sides, reg double-buffer ----------------
template<int MF, int NF, int BN, bool BF16A>
__global__ __launch_bounds__(256) void mfma_gemm2(
        const void* __restrict__ A0, const void* __restrict__ A1,
        const float* __restrict__ B0, const float* __restrict__ B1,
        uint32_t* __restrict__ Cb, size_t cstride,
        const float* __restrict__ as0, const float* __restrict__ as1,
        const float* __restrict__ ad0, const float* __restrict__ ad1,
        float* __restrict__ ssrc_b, float* __restrict__ sdst_b,
        int M, int K) {
    __shared__ uint32_t Al[64][36];
    __shared__ uint32_t Bl[BN][36];
    __shared__ float sS[64][2], sD[64][2];
    int side = blockIdx.y;
    const void* Av = side ? A1 : A0;
    const float* B = side ? B1 : B0;
    const float* Asrc = side ? as1 : as0;
    const float* Adst = side ? ad1 : ad0;
    uint32_t* C = Cb + (size_t)side * cstride;
    float* ssrc = ssrc_b + (size_t)side * Nn;
    float* sdst = sdst_b + (size_t)side * Nn;

    int tid  = threadIdx.x;
    int lane = tid & 63;
    int wid  = tid >> 6;
    int wr = wid >> 1, wc = wid & 1;
    int bm = blockIdx.x * 64;

    int arow = tid >> 2, aq = tid & 3;
    bool avalid = (bm + arow) < M;
    constexpr int NPI = BN * 16 / 256;

    float    fA[16];
    uint32_t uA[8];
    float    fB[NPI][4];

    auto LOADA = [&](int k0) {
        if constexpr (BF16A) {
            const uint32_t* A = (const uint32_t*)Av;
            if (avalid) {
                const uint32_t* p = A + (size_t)(bm + arow) * (K >> 1) + (k0 >> 1) + aq * 8;
                uint4 u0 = *(const uint4*)p;
                uint4 u1 = *(const uint4*)(p + 4);
                uA[0] = u0.x; uA[1] = u0.y; uA[2] = u0.z; uA[3] = u0.w;
                uA[4] = u1.x; uA[5] = u1.y; uA[6] = u1.z; uA[7] = u1.w;
            } else {
                #pragma unroll
                for (int i = 0; i < 8; i++) uA[i] = 0u;
            }
        } else {
            const float* A = (const float*)Av;
            if (avalid) {
                const float* p = A + (size_t)(bm + arow) * K + k0 + aq * 16;
                #pragma unroll
                for (int i = 0; i < 4; i++) {
                    float4 f = *(const float4*)(p + i * 4);
                    fA[4 * i] = f.x; fA[4 * i + 1] = f.y; fA[4 * i + 2] = f.z; fA[4 * i + 3] = f.w;
                }
            } else {
                #pragma unroll
                for (int i = 0; i < 16; i++) fA[i] = 0.f;
            }
        }
    };
    auto LOADB = [&](int k0) {
        #pragma unroll
        for (int it = 0; it < NPI; it++) {
            int pi = tid + it * 256;
            int n = pi & (BN - 1);
            int kp = pi / BN;
            const float* p = B + (size_t)(k0 + 4 * kp) * BN + n;
            fB[it][0] = p[0];
            fB[it][1] = p[BN];
            fB[it][2] = p[2 * BN];
            fB[it][3] = p[3 * BN];
        }
    };
    auto WRITE = [&]() {
        if constexpr (BF16A) {
            uint4* dst = (uint4*)&Al[arow][aq * 8];
            dst[0] = make_uint4(uA[0], uA[1], uA[2], uA[3]);
            dst[1] = make_uint4(uA[4], uA[5], uA[6], uA[7]);
        } else {
            uint32_t d[8];
            #pragma unroll
            for (int i = 0; i < 8; i++) d[i] = packbf(fA[2 * i], fA[2 * i + 1]);
            uint4* dst = (uint4*)&Al[arow][aq * 8];
            dst[0] = make_uint4(d[0], d[1], d[2], d[3]);
            dst[1] = make_uint4(d[4], d[5], d[6], d[7]);
        }
        #pragma unroll
        for (int it = 0; it < NPI; it++) {
            int pi = tid + it * 256;
            int n = pi & (BN - 1);
            int kp = pi / BN;
            *(uint2*)&Bl[n][2 * kp] = make_uint2(packbf(fB[it][0], fB[it][1]),
                                                 packbf(fB[it][2], fB[it][3]));
        }
    };

    f32x4 acc[MF][NF];
    #pragma unroll
    for (int i = 0; i < MF; i++)
        #pragma unroll
        for (int j = 0; j < NF; j++) acc[i][j] = (f32x4){0.f, 0.f, 0.f, 0.f};

    LOADA(0); LOADB(0);
    const int T = K / 64;
    for (int t = 0; t < T; t++) {
        WRITE();
        __syncthreads();
        if (t + 1 < T) { LOADA((t + 1) * 64); LOADB((t + 1) * 64); }
        int lr = lane & 15, lk = lane >> 4;
        #pragma unroll
        for (int ks = 0; ks < 2; ks++) {
            short8 af[MF], bf[NF];
            #pragma unroll
            for (int mf = 0; mf < MF; mf++)
                af[mf] = *(const short8*)&Al[wr * (MF * 16) + mf * 16 + lr][ks * 16 + lk * 4];
            #pragma unroll
            for (int nf = 0; nf < NF; nf++)
                bf[nf] = *(const short8*)&Bl[wc * (NF * 16) + nf * 16 + lr][ks * 16 + lk * 4];
            #pragma unroll
            for (int mf = 0; mf < MF; mf++)
                #pragma unroll
                for (int nf = 0; nf < NF; nf++)
                    acc[mf][nf] = __builtin_amdgcn_mfma_f32_16x16x32_bf16(af[mf], bf[nf], acc[mf][nf], 0, 0, 0);
        }
        __syncthreads();
    }

    int lr = lane & 15, lg = lane >> 4;
    {
        float a_s[NF], a_d[NF];
        #pragma unroll
        for (int nf = 0; nf < NF; nf++) {
            int col = wc * (NF * 16) + nf * 16 + lr;
            a_s[nf] = Asrc[col];
            a_d[nf] = Adst[col];
        }
        #pragma unroll
        for (int mf = 0; mf < MF; mf++) {
            #pragma unroll
            for (int j = 0; j < 4; j++) {
                float ps = 0.f, pd = 0.f;
                #pragma unroll
                for (int nf = 0; nf < NF; nf++) {
                    float v = acc[mf][nf][j];
                    ps += v * a_s[nf];
                    pd += v * a_d[nf];
                }
                #pragma unroll
                for (int o = 1; o < 16; o <<= 1) {
                    ps += __shfl_xor(ps, o);
                    pd += __shfl_xor(pd, o);
                }
                if (lr == 0) {
                    int rl = wr * (MF * 16) + mf * 16 + lg * 4 + j;
                    sS[rl][wc] = ps;
                    sD[rl][wc] = pd;
                }
            }
        }
    }
    #pragma unroll
    for (int mf = 0; mf < MF; mf++) {
        #pragma unroll
        for (int nf = 0; nf < NF; nf++) {
            int col = wc * (NF * 16) + nf * 16 + lr;
            #pragma unroll
            for (int j = 0; j < 4; j++) {
                int row = bm + wr * (MF * 16) + mf * 16 + lg * 4 + j;
                float v = acc[mf][nf][j];
                float w = __shfl_xor(v, 1);
                if (!(lane & 1) && row < M)
                    C[(size_t)row * (BN >> 1) + (col >> 1)] = packbf(v, w);
            }
        }
    }
    __syncthreads();
    if (tid < 64) {
        int row = bm + tid;
        if (row < M) {
            ssrc[row] = sS[tid][0] + sS[tid][1];
            sdst[row] = sD[tid][0] + sD[tid][1];
        }
    }
}

// ---------------- attention softmax + aggregation (one wave per dst node, both sides) ----------------
// Fast path: lane-parallel softmax once; uint2 gathers so a wave covers 2 (F=128) or 4 (F=64)
// edges per memory instruction; 2x unroll keeps loads in flight.
template<int F>
__global__ __launch_bounds__(256) void attn_agg2(const uint32_t* __restrict__ hb,
        const float* __restrict__ ssrc_b, const float* __restrict__ sdst_b,
        const int* __restrict__ row_ptr_b, const int* __restrict__ csr_b,
        const float* __restrict__ bias0, const float* __restrict__ bias1,
        uint32_t* __restrict__ xout_b, int n) {
    int side = blockIdx.y;
    const uint32_t* h = hb + (size_t)side * HS;
    const float* ssrc = ssrc_b + (size_t)side * Nn;
    const float* sdst = sdst_b + (size_t)side * Nn;
    const int* row_ptr = row_ptr_b + (size_t)side * (Nn + 1);
    const int* csr_src = csr_b + (size_t)side * Ecnt;
    const float* bias = side ? bias1 : bias0;
    uint32_t* xout = xout_b + (size_t)side * HS;

    int wid = (blockIdx.x * blockDim.x + threadIdx.x) >> 6;
    int lane = threadIdx.x & 63;
    if (wid >= n) return;
    int beg = row_ptr[wid], end = row_ptr[wid + 1];
    int deg = end - beg;
    float sd = sdst[wid];
    float eself = lrelu(ssrc[wid] + sd);
    constexpr int RU = F / 2;

    if (deg <= 64) {
        int p = beg + lane;
        bool act = p < end;
        int s = act ? csr_src[p] : 0;
        float e = act ? lrelu(ssrc[s] + sd) : -1e30f;
        float m = fmaxf(eself, e);
        #pragma unroll
        for (int o = 32; o; o >>= 1) m = fmaxf(m, __shfl_xor(m, o));
        float ex = act ? __expf(e - m) : 0.f;
        float dsum = ex;
        #pragma unroll
        for (int o = 32; o; o >>= 1) dsum += __shfl_xor(dsum, o);
        float exself = __expf(eself - m);
        dsum += exself;
        float inv = 1.f / dsum;
        float w = ex * inv;
        float wself = exself * inv;

        if constexpr (F == 128) {
            // half-wave per edge: lane = (half, i), lane i owns dwords 2i,2i+1 (4 feats)
            int half = lane >> 5, i = lane & 31;
            float a0 = 0.f, a1 = 0.f, a2 = 0.f, a3 = 0.f;
            if (half == 0) {
                uint2 v = *(const uint2*)(h + ((size_t)wid << 6) + 2 * i);
                a0 = wself * bflo(v.x); a1 = wself * bfhi(v.x);
                a2 = wself * bflo(v.y); a3 = wself * bfhi(v.y);
            }
            int j = half;
            for (; j + 2 < deg; j += 4) {
                float w0 = __shfl(w, j), w1 = __shfl(w, j + 2);
                int   s0 = __shfl(s, j), s1 = __shfl(s, j + 2);
                uint2 u0 = *(const uint2*)(h + ((size_t)s0 << 6) + 2 * i);
                uint2 u1 = *(const uint2*)(h + ((size_t)s1 << 6) + 2 * i);
                a0 += w0 * bflo(u0.x) + w1 * bflo(u1.x);
                a1 += w0 * bfhi(u0.x) + w1 * bfhi(u1.x);
                a2 += w0 * bflo(u0.y) + w1 * bflo(u1.y);
                a3 += w0 * bfhi(u0.y) + w1 * bfhi(u1.y);
            }
            for (; j < deg; j += 2) {
                float w0 = __shfl(w, j);
                int   s0 = __shfl(s, j);
                uint2 u0 = *(const uint2*)(h + ((size_t)s0 << 6) + 2 * i);
                a0 += w0 * bflo(u0.x); a1 += w0 * bfhi(u0.x);
                a2 += w0 * bflo(u0.y); a3 += w0 * bfhi(u0.y);
            }
            a0 += __shfl_xor(a0, 32); a1 += __shfl_xor(a1, 32);
            a2 += __shfl_xor(a2, 32); a3 += __shfl_xor(a3, 32);
            if (half == 0) {
                float r0 = fmaxf(a0 + bias[4 * i], 0.f);
                float r1 = fmaxf(a1 + bias[4 * i + 1], 0.f);
                float r2 = fmaxf(a2 + bias[4 * i + 2], 0.f);
                float r3 = fmaxf(a3 + bias[4 * i + 3], 0.f);
                *(uint2*)(xout + ((size_t)wid << 6) + 2 * i) = make_uint2(packbf(r0, r1), packbf(r2, r3));
            }
        } else {
            // quarter-wave per edge: lane = (q, i), lane i owns dwords 2i,2i+1 (4 feats)
            int q = lane >> 4, i = lane & 15;
            float a0 = 0.f, a1 = 0.f, a2 = 0.f, a3 = 0.f;
            if (q == 0) {
                uint2 v = *(const uint2*)(h + ((size_t)wid << 5) + 2 * i);
                a0 = wself * bflo(v.x); a1 = wself * bfhi(v.x);
                a2 = wself * bflo(v.y); a3 = wself * bfhi(v.y);
            }
            int j = q;
            for (; j + 4 < deg; j += 8) {
                float w0 = __shfl(w, j), w1 = __shfl(w, j + 4);
                int   s0 = __shfl(s, j), s1 = __shfl(s, j + 4);
                uint2 u0 = *(const uint2*)(h + ((size_t)s0 << 5) + 2 * i);
                uint2 u1 = *(const uint2*)(h + ((size_t)s1 << 5) + 2 * i);
                a0 += w0 * bflo(u0.x) + w1 * bflo(u1.x);
                a1 += w0 * bfhi(u0.x) + w1 * bfhi(u1.x);
                a2 += w0 * bflo(u0.y) + w1 * bflo(u1.y);
                a3 += w0 * bfhi(u0.y) + w1 * bfhi(u1.y);
            }
            for (; j < deg; j += 4) {
                float w0 = __shfl(w, j);
                int   s0 = __shfl(s, j);
                uint2 u0 = *(const uint2*)(h + ((size_t)s0 << 5) + 2 * i);
                a0 += w0 * bflo(u0.x); a1 += w0 * bfhi(u0.x);
                a2 += w0 * bflo(u0.y); a3 += w0 * bfhi(u0.y);
            }
            a0 += __shfl_xor(a0, 16); a1 += __shfl_xor(a1, 16);
            a2 += __shfl_xor(a2, 16); a3 += __shfl_xor(a3, 16);
            a0 += __shfl_xor(a0, 32); a1 += __shfl_xor(a1, 32);
            a2 += __shfl_xor(a2, 32); a3 += __shfl_xor(a3, 32);
            if (q == 0) {
                float r0 = fmaxf(a0 + bias[4 * i], 0.f);
                float r1 = fmaxf(a1 + bias[4 * i + 1], 0.f);
                float r2 = fmaxf(a2 + bias[4 * i + 2], 0.f);
                float r3 = fmaxf(a3 + bias[4 * i + 3], 0.f);
                *(uint2*)(xout + ((size_t)wid << 5) + 2 * i) = make_uint2(packbf(r0, r1), packbf(r2, r3));
            }
        }
        return;
    }

    // generic path (deg > 64)
    float m = eself;
    for (int p = beg + lane; p < end; p += 64)
        m = fmaxf(m, lrelu(ssrc[csr_src[p]] + sd));
    #pragma unroll
    for (int o = 32; o; o >>= 1) m = fmaxf(m, __shfl_xor(m, o));
    float dsum = (lane == 0) ? __expf(eself - m) : 0.f;
    for (int p = beg + lane; p < end; p += 64)
        dsum += __expf(lrelu(ssrc[csr_src[p]] + sd) - m);
    #pragma unroll
    for (int o = 32; o; o >>= 1) dsum += __shfl_xor(dsum, o);
    float inv = 1.f / dsum;
    float wself = __expf(eself - m) * inv;

    if constexpr (F == 128) {
        uint32_t v = h[(size_t)wid * RU + lane];
        float acc0 = wself * bflo(v), acc1 = wself * bfhi(v);
        for (int p = beg; p < end; ++p) {
            int s0 = csr_src[p];
            uint32_t v0 = h[(size_t)s0 * RU + lane];
            float w0 = __expf(lrelu(ssrc[s0] + sd) - m) * inv;
            acc0 += w0 * bflo(v0);
            acc1 += w0 * bfhi(v0);
        }
        float r0 = fmaxf(acc0 + bias[2 * lane], 0.f);
        float r1 = fmaxf(acc1 + bias[2 * lane + 1], 0.f);
        xout[(size_t)wid * RU + lane] = packbf(r0, r1);
    } else {
        int half = lane >> 5, i = lane & 31;
        float acc0 = 0.f, acc1 = 0.f;
        if (half == 0) {
            uint32_t v = h[(size_t)wid * RU + i];
            acc0 = wself * bflo(v);
            acc1 = wself * bfhi(v);
        }
        for (int p = beg + half; p < end; p += 2) {
            int s0 = csr_src[p];
            uint32_t v = h[(size_t)s0 * RU + i];
            float w0 = __expf(lrelu(ssrc[s0] + sd) - m) * inv;
            acc0 += w0 * bflo(v);
            acc1 += w0 * bfhi(v);
        }
        acc0 += __shfl_xor(acc0, 32);
        acc1 += __shfl_xor(acc1, 32);
        if (half == 0) {
            float r0 = fmaxf(acc0 + bias[2 * i], 0.f);
            float r1 = fmaxf(acc1 + bias[2 * i + 1], 0.f);
            xout[(size_t)wid * RU + i] = packbf(r0, r1);
        }
    }
}

// ---------------- mean pool (sorted batch), both sides ----------------
__global__ __launch_bounds__(256) void pool2(const uint32_t* __restrict__ xb,
                                             const int* __restrict__ bat0,
                                             const int* __restrict__ bat1,
                                             float* __restrict__ pooled_b, int n) {
    int side = blockIdx.y;
    const uint32_t* x = xb + (size_t)side * HS;
    const int* batch = side ? bat1 : bat0;
    float* pooled = pooled_b + (size_t)side * Gn * 64;
    int g = blockIdx.x;
    int tid = threadIdx.x;
    __shared__ int s_lo, s_hi;
    if (tid == 0) {
        int lo = 0, hi = n;
        while (lo < hi) { int mid = (lo + hi) >> 1; if (batch[mid] < g) lo = mid + 1; else hi = mid; }
        s_lo = lo;
        int lo2 = lo, hi2 = n;
        while (lo2 < hi2) { int mid = (lo2 + hi2) >> 1; if (batch[mid] < g + 1) lo2 = mid + 1; else hi2 = mid; }
        s_hi = lo2;
    }
    __syncthreads();
    int lo = s_lo, hi = s_hi;
    int grp = tid >> 5, col = tid & 31;
    float a0 = 0.f, a1 = 0.f;
    for (int i = lo + grp; i < hi; i += 8) {
        uint32_t v = x[(size_t)i * 32 + col];
        a0 += bflo(v);
        a1 += bfhi(v);
    }
    __shared__ float red0[8][32], red1[8][32];
    red0[grp][col] = a0;
    red1[grp][col] = a1;
    __syncthreads();
    if (tid < 32) {
        float s0 = 0.f, s1 = 0.f;
        #pragma unroll
        for (int r = 0; r < 8; r++) { s0 += red0[r][tid]; s1 += red1[r][tid]; }
        float c = fmaxf((float)(hi - lo), 1.f);
        pooled[g * 64 + 2 * tid]     = s0 / c;
        pooled[g * 64 + 2 * tid + 1] = s1 / c;
    }
}

// ---------------- head ----------------
__global__ __launch_bounds__(256) void head_kernel(const float* __restrict__ xs,
                                                   const float* __restrict__ xt,
                                                   const float* __restrict__ Wlin,
                                                   const float* __restrict__ blin,
                                                   float* __restrict__ out) {
    int g = blockIdx.y;
    int c = blockIdx.x * 256 + threadIdx.x;
    __shared__ float z[64];
    if (threadIdx.x < 64) z[threadIdx.x] = xs[g * 64 + threadIdx.x] + xt[g * 64 + threadIdx.x];
    __syncthreads();
    float a0 = 0.f, a1 = 0.f, a2 = 0.f, a3 = 0.f;
    #pragma unroll
    for (int k = 0; k < 64; k += 4) {
        a0 += z[k]     * Wlin[(size_t)(k)     * Lout + c];
        a1 += z[k + 1] * Wlin[(size_t)(k + 1) * Lout + c];
        a2 += z[k + 2] * Wlin[(size_t)(k + 2) * Lout + c];
        a3 += z[k + 3] * Wlin[(size_t)(k + 3) * Lout + c];
    }
    float acc = (a0 + a1) + (a2 + a3) + blin[c];
    out[(size_t)g * Lout + c] = 1.f / (1.f + expf(-acc));
}

extern "C" void kernel_launch(void* const* d_in, const int* in_sizes, int n_in,
                              void* d_out, int out_size, void* d_ws, size_t ws_size,
                              hipStream_t stream) {
    size_t off = 0;
    auto alloc = [&](size_t bytes) -> void* {
        void* p = (char*)d_ws + off;
        off += (bytes + 255) & ~(size_t)255;
        return p;
    };
    uint32_t* hbuf   = (uint32_t*)alloc(2 * HS * 4);
    uint32_t* xbuf   = (uint32_t*)alloc(2 * HS * 4);
    float* ssrc      = (float*)alloc(2 * (size_t)Nn * 4);
    float* sdst      = (float*)alloc(2 * (size_t)Nn * 4);
    int*   row_ptr   = (int*)alloc(2 * (size_t)(Nn + 1) * 4);
    int*   csr       = (int*)alloc(2 * (size_t)Ecnt * 4);
    uint2* bkt_edges = (uint2*)alloc(2 * (size_t)Ecnt * 8);
    int*   bkt_cnt   = (int*)alloc(2 * (size_t)(NBKT + 1) * 4);
    int*   bkt_ptr   = (int*)alloc(2 * (size_t)(NBKT + 1) * 4);
    int*   bkt_cur   = (int*)alloc(2 * (size_t)(NBKT + 1) * 4);
    float* pooled    = (float*)alloc(2 * (size_t)Gn * 64 * 4);

    const int NW  = (Nn * 64 + 255) / 256;
    const int GB  = (Nn + 63) / 64;
    const int EBC = (Ecnt + CHUNK - 1) / CHUNK;

    const float* x_s = (const float*)d_in[0];
    const float* x_t = (const float*)d_in[1];
    const int* ei_s  = (const int*)d_in[2];
    const int* ei_t  = (const int*)d_in[3];
    const int* bat_s = (const int*)d_in[4];
    const int* bat_t = (const int*)d_in[5];
    const float *Ws1 = (const float*)d_in[6],  *as1s = (const float*)d_in[7],
                *as1d = (const float*)d_in[8],  *bs1 = (const float*)d_in[9];
    const float *Ws2 = (const float*)d_in[10], *as2s = (const float*)d_in[11],
                *as2d = (const float*)d_in[12], *bs2 = (const float*)d_in[13];
    const float *Wt1 = (const float*)d_in[14], *at1s = (const float*)d_in[15],
                *at1d = (const float*)d_in[16], *bt1 = (const float*)d_in[17];
    const float *Wt2 = (const float*)d_in[18], *at2s = (const float*)d_in[19],
                *at2d = (const float*)d_in[20], *bt2 = (const float*)d_in[21];
    const float *Wlin = (const float*)d_in[22], *blin = (const float*)d_in[23];

    // ---- CSR build (both sides) ----
    hipMemsetAsync(bkt_cnt, 0, 2 * (size_t)(NBKT + 1) * 4, stream);
    bkt_count2<<<dim3(EBC, 2), 256, 0, stream>>>(ei_s, ei_t, bkt_cnt, Ecnt);
    bkt_scan2<<<2, 512, 0, stream>>>(bkt_cnt, bkt_ptr, bkt_cur, row_ptr);
    bkt_scatter2<<<dim3(EBC, 2), 256, 0, stream>>>(ei_s, ei_t, bkt_cur, bkt_edges, Ecnt);
    csr_finalize2<<<dim3(NBKT, 2), 256, 0, stream>>>(bkt_edges, bkt_ptr, row_ptr, csr, Nn);
    // ---- layer 1: 256 -> 128 (fp32 A), scores fused ----
    mfma_gemm2<2, 4, 128, false><<<dim3(GB, 2), 256, 0, stream>>>(
        x_s, x_t, Ws1, Wt1, hbuf, HS, as1s, at1s, as1d, at1d, ssrc, sdst, Nn, Din);
    attn_agg2<128><<<dim3(NW, 2), 256, 0, stream>>>(hbuf, ssrc, sdst, row_ptr, csr, bs1, bt1, xbuf, Nn);
    // ---- layer 2: 128 -> 64 (bf16 A), scores fused ----
    mfma_gemm2<2, 2, 64, true><<<dim3(GB, 2), 256, 0, stream>>>(
        xbuf, xbuf + HS, Ws2, Wt2, hbuf, HS, as2s, at2s, as2d, at2d, ssrc, sdst, Nn, 128);
    attn_agg2<64><<<dim3(NW, 2), 256, 0, stream>>>(hbuf, ssrc, sdst, row_ptr, csr, bs2, bt2, xbuf, Nn);
    // ---- pool + head ----
    pool2<<<dim3(Gn, 2), 256, 0, stream>>>(xbuf, bat_s, bat_t, pooled, Nn);
    head_kernel<<<dim3(Lout / 256, Gn), 256, 0, stream>>>(pooled, pooled + (size_t)Gn * 64,
                                                          Wlin, blin, (float*)d_out);
}

// Round 11
// 250.265 us; speedup vs baseline: 6.2913x; 1.0751x over previous
//
#include <hip/hip_runtime.h>
#include <hip/hip_bf16.h>
#include <math.h>

constexpr int Nn   = 50000;
constexpr int Ecnt = 800000;
constexpr int Gn   = 128;
constexpr int Din  = 256;
constexpr int Lout = 1024;

constexpr int BKT_SH = 7;                       // 128 nodes per bucket
constexpr int NBKT   = (Nn + 127) >> BKT_SH;    // 391
constexpr int CHUNK  = 4096;                    // edges per partition block
constexpr int EBC    = (Ecnt + CHUNK - 1) / CHUNK;  // 196
constexpr size_t HS  = (size_t)Nn * 64;         // per-side h/x stride (dwords)

typedef __attribute__((ext_vector_type(8))) short short8;   // 8 bf16 (4 VGPRs)
typedef __attribute__((ext_vector_type(4))) float f32x4;    // MFMA accumulator

__device__ __forceinline__ float lrelu(float x) { return x >= 0.f ? x : 0.2f * x; }

__device__ __forceinline__ float bflo(uint32_t v) { return __uint_as_float(v << 16); }
__device__ __forceinline__ float bfhi(uint32_t v) { return __uint_as_float(v & 0xffff0000u); }
__device__ __forceinline__ uint32_t f2bf(float f) {
    uint32_t x = __float_as_uint(f);
    return (x + 0x7fffu + ((x >> 16) & 1u)) >> 16;
}
__device__ __forceinline__ uint32_t packbf(float lo, float hi) {
    return f2bf(lo) | (f2bf(hi) << 16);
}

// ================= CSR build helpers (side = blockIdx.y) =================
__global__ __launch_bounds__(512) void bkt_scan2(const int* __restrict__ bkt_cnt_b,
                                                 int* __restrict__ bkt_ptr_b,
                                                 int* __restrict__ bkt_cur_b,
                                                 int* __restrict__ row_ptr_b) {
    int side = blockIdx.x;
    const int* bkt_cnt = bkt_cnt_b + (size_t)side * (NBKT + 1);
    int* bkt_ptr = bkt_ptr_b + (size_t)side * (NBKT + 1);
    int* bkt_cur = bkt_cur_b + (size_t)side * (NBKT + 1);
    int* row_ptr = row_ptr_b + (size_t)side * (Nn + 1);
    __shared__ int buf[512];
    int t = threadIdx.x;
    int v = (t < NBKT) ? bkt_cnt[t] : 0;
    buf[t] = v;
    __syncthreads();
    for (int off = 1; off < 512; off <<= 1) {
        int x = (t >= off) ? buf[t - off] : 0;
        __syncthreads();
        buf[t] += x;
        __syncthreads();
    }
    if (t < NBKT) {
        int excl = buf[t] - v;
        bkt_ptr[t] = excl;
        bkt_cur[t] = excl;
    }
    if (t == 511) {
        bkt_ptr[NBKT] = buf[511];
        row_ptr[Nn]   = buf[511];
    }
}

// scatter: packed record = src | ((dst&127)<<16)   (src < 65536)
__global__ __launch_bounds__(256) void bkt_scatter2(const int* __restrict__ e0,
                                                    const int* __restrict__ e1,
                                                    int* __restrict__ bkt_cur_b,
                                                    uint32_t* __restrict__ bkt_edges_b, int E) {
    int side = blockIdx.y;
    const int* src = side ? e1 : e0;
    const int* dst = src + E;
    int* bkt_cur = bkt_cur_b + (size_t)side * (NBKT + 1);
    uint32_t* bkt_edges = bkt_edges_b + (size_t)side * Ecnt;
    __shared__ int h[NBKT];
    __shared__ int cur[NBKT];
    for (int i = threadIdx.x; i < NBKT; i += 256) h[i] = 0;
    __syncthreads();
    int base = blockIdx.x * CHUNK;
    int end = min(base + CHUNK, E);
    for (int i = base + threadIdx.x; i < end; i += 256)
        atomicAdd(&h[dst[i] >> BKT_SH], 1);
    __syncthreads();
    for (int i = threadIdx.x; i < NBKT; i += 256) {
        int c = h[i];
        h[i] = c ? atomicAdd(&bkt_cur[i], c) : 0;
        cur[i] = 0;
    }
    __syncthreads();
    for (int i = base + threadIdx.x; i < end; i += 256) {
        int d = dst[i], b = d >> BKT_SH;
        int pos = h[b] + atomicAdd(&cur[b], 1);
        bkt_edges[pos] = (uint32_t)src[i] | ((uint32_t)(d & 127) << 16);
    }
}

__global__ __launch_bounds__(256) void csr_finalize2(const uint32_t* __restrict__ bkt_edges_b,
                                                     const int* __restrict__ bkt_ptr_b,
                                                     int* __restrict__ row_ptr_b,
                                                     int* __restrict__ csr_b, int n) {
    int side = blockIdx.y;
    const uint32_t* bkt_edges = bkt_edges_b + (size_t)side * Ecnt;
    const int* bkt_ptr = bkt_ptr_b + (size_t)side * (NBKT + 1);
    int* row_ptr = row_ptr_b + (size_t)side * (Nn + 1);
    int* csr = csr_b + (size_t)side * Ecnt;
    int b = blockIdx.x;
    int base = bkt_ptr[b];
    int cnt  = bkt_ptr[b + 1] - base;
    __shared__ int hist[128], curs[128], sc[128];
    int t = threadIdx.x;
    if (t < 128) hist[t] = 0;
    __syncthreads();
    for (int i = t; i < cnt; i += 256)
        atomicAdd(&hist[(bkt_edges[base + i] >> 16) & 127], 1);
    __syncthreads();
    if (t < 128) sc[t] = hist[t];
    __syncthreads();
    for (int off = 1; off < 128; off <<= 1) {
        int x = (t >= off && t < 128) ? sc[t - off] : 0;
        __syncthreads();
        if (t < 128) sc[t] += x;
        __syncthreads();
    }
    if (t < 128) {
        int excl = sc[t] - hist[t];
        int node = (b << BKT_SH) + t;
        if (node < n) row_ptr[node] = base + excl;
        curs[t] = excl;
    }
    __syncthreads();
    for (int i = t; i < cnt; i += 256) {
        uint32_t e = bkt_edges[base + i];
        int pos = atomicAdd(&curs[(e >> 16) & 127], 1);
        csr[base + pos] = (int)(e & 0xFFFFu);
    }
}

// ---------------- MFMA bf16 GEMM + fused scores (+ optional fused bucket-count) ----------------
template<int MF, int NF, int BN, bool BF16A, bool FUSE_COUNT>
__global__ __launch_bounds__(256) void mfma_gemm2(
        const void* __restrict__ A0, const void* __restrict__ A1,
        const float* __restrict__ B0, const float* __restrict__ B1,
        uint32_t* __restrict__ Cb, size_t cstride,
        const float* __restrict__ as0, const float* __restrict__ as1,
        const float* __restrict__ ad0, const float* __restrict__ ad1,
        float* __restrict__ ssrc_b, float* __restrict__ sdst_b,
        int M, int K,
        const int* __restrict__ e0, const int* __restrict__ e1,
        int* __restrict__ bkt_cnt_b) {
    __shared__ uint32_t Al[64][36];
    __shared__ uint32_t Bl[BN][36];
    __shared__ float sS[64][2], sD[64][2];
    int side = blockIdx.y;

    if constexpr (FUSE_COUNT) {
        int gb = (M + 63) >> 6;
        if ((int)blockIdx.x >= gb) {
            // bucket-count path (LDS aliased onto Al)
            int chunk = blockIdx.x - gb;
            const int* dst = (side ? e1 : e0) + Ecnt;
            int* bkt_cnt = bkt_cnt_b + (size_t)side * (NBKT + 1);
            int* hh = (int*)&Al[0][0];
            for (int i = threadIdx.x; i < NBKT; i += 256) hh[i] = 0;
            __syncthreads();
            int base = chunk * CHUNK;
            int end = min(base + CHUNK, Ecnt);
            for (int i = base + threadIdx.x; i < end; i += 256)
                atomicAdd(&hh[dst[i] >> BKT_SH], 1);
            __syncthreads();
            for (int i = threadIdx.x; i < NBKT; i += 256) {
                int c = hh[i];
                if (c) atomicAdd(&bkt_cnt[i], c);
            }
            return;
        }
    }

    const void* Av = side ? A1 : A0;
    const float* B = side ? B1 : B0;
    const float* Asrc = side ? as1 : as0;
    const float* Adst = side ? ad1 : ad0;
    uint32_t* C = Cb + (size_t)side * cstride;
    float* ssrc = ssrc_b + (size_t)side * Nn;
    float* sdst = sdst_b + (size_t)side * Nn;

    int tid  = threadIdx.x;
    int lane = tid & 63;
    int wid  = tid >> 6;
    int wr = wid >> 1, wc = wid & 1;
    int bm = blockIdx.x * 64;

    int arow = tid >> 2, aq = tid & 3;
    bool avalid = (bm + arow) < M;
    constexpr int NPI = BN * 16 / 256;

    float    fA[16];
    uint32_t uA[8];
    float    fB[NPI][4];

    auto LOADA = [&](int k0) {
        if constexpr (BF16A) {
            const uint32_t* A = (const uint32_t*)Av;
            if (avalid) {
                const uint32_t* p = A + (size_t)(bm + arow) * (K >> 1) + (k0 >> 1) + aq * 8;
                uint4 u0 = *(const uint4*)p;
                uint4 u1 = *(const uint4*)(p + 4);
                uA[0] = u0.x; uA[1] = u0.y; uA[2] = u0.z; uA[3] = u0.w;
                uA[4] = u1.x; uA[5] = u1.y; uA[6] = u1.z; uA[7] = u1.w;
            } else {
                #pragma unroll
                for (int i = 0; i < 8; i++) uA[i] = 0u;
            }
        } else {
            const float* A = (const float*)Av;
            if (avalid) {
                const float* p = A + (size_t)(bm + arow) * K + k0 + aq * 16;
                #pragma unroll
                for (int i = 0; i < 4; i++) {
                    float4 f = *(const float4*)(p + i * 4);
                    fA[4 * i] = f.x; fA[4 * i + 1] = f.y; fA[4 * i + 2] = f.z; fA[4 * i + 3] = f.w;
                }
            } else {
                #pragma unroll
                for (int i = 0; i < 16; i++) fA[i] = 0.f;
            }
        }
    };
    auto LOADB = [&](int k0) {
        #pragma unroll
        for (int it = 0; it < NPI; it++) {
            int pi = tid + it * 256;
            int n = pi & (BN - 1);
            int kp = pi / BN;
            const float* p = B + (size_t)(k0 + 4 * kp) * BN + n;
            fB[it][0] = p[0];
            fB[it][1] = p[BN];
            fB[it][2] = p[2 * BN];
            fB[it][3] = p[3 * BN];
        }
    };
    auto WRITE = [&]() {
        if constexpr (BF16A) {
            uint4* dst = (uint4*)&Al[arow][aq * 8];
            dst[0] = make_uint4(uA[0], uA[1], uA[2], uA[3]);
            dst[1] = make_uint4(uA[4], uA[5], uA[6], uA[7]);
        } else {
            uint32_t d[8];
            #pragma unroll
            for (int i = 0; i < 8; i++) d[i] = packbf(fA[2 * i], fA[2 * i + 1]);
            uint4* dst = (uint4*)&Al[arow][aq * 8];
            dst[0] = make_uint4(d[0], d[1], d[2], d[3]);
            dst[1] = make_uint4(d[4], d[5], d[6], d[7]);
        }
        #pragma unroll
        for (int it = 0; it < NPI; it++) {
            int pi = tid + it * 256;
            int n = pi & (BN - 1);
            int kp = pi / BN;
            *(uint2*)&Bl[n][2 * kp] = make_uint2(packbf(fB[it][0], fB[it][1]),
                                                 packbf(fB[it][2], fB[it][3]));
        }
    };

    f32x4 acc[MF][NF];
    #pragma unroll
    for (int i = 0; i < MF; i++)
        #pragma unroll
        for (int j = 0; j < NF; j++) acc[i][j] = (f32x4){0.f, 0.f, 0.f, 0.f};

    LOADA(0); LOADB(0);
    const int T = K / 64;
    for (int t = 0; t < T; t++) {
        WRITE();
        __syncthreads();
        if (t + 1 < T) { LOADA((t + 1) * 64); LOADB((t + 1) * 64); }
        int lr = lane & 15, lk = lane >> 4;
        #pragma unroll
        for (int ks = 0; ks < 2; ks++) {
            short8 af[MF], bf[NF];
            #pragma unroll
            for (int mf = 0; mf < MF; mf++)
                af[mf] = *(const short8*)&Al[wr * (MF * 16) + mf * 16 + lr][ks * 16 + lk * 4];
            #pragma unroll
            for (int nf = 0; nf < NF; nf++)
                bf[nf] = *(const short8*)&Bl[wc * (NF * 16) + nf * 16 + lr][ks * 16 + lk * 4];
            #pragma unroll
            for (int mf = 0; mf < MF; mf++)
                #pragma unroll
                for (int nf = 0; nf < NF; nf++)
                    acc[mf][nf] = __builtin_amdgcn_mfma_f32_16x16x32_bf16(af[mf], bf[nf], acc[mf][nf], 0, 0, 0);
        }
        __syncthreads();
    }

    int lr = lane & 15, lg = lane >> 4;
    {
        float a_s[NF], a_d[NF];
        #pragma unroll
        for (int nf = 0; nf < NF; nf++) {
            int col = wc * (NF * 16) + nf * 16 + lr;
            a_s[nf] = Asrc[col];
            a_d[nf] = Adst[col];
        }
        #pragma unroll
        for (int mf = 0; mf < MF; mf++) {
            #pragma unroll
            for (int j = 0; j < 4; j++) {
                float ps = 0.f, pd = 0.f;
                #pragma unroll
                for (int nf = 0; nf < NF; nf++) {
                    float v = acc[mf][nf][j];
                    ps += v * a_s[nf];
                    pd += v * a_d[nf];
                }
                #pragma unroll
                for (int o = 1; o < 16; o <<= 1) {
                    ps += __shfl_xor(ps, o);
                    pd += __shfl_xor(pd, o);
                }
                if (lr == 0) {
                    int rl = wr * (MF * 16) + mf * 16 + lg * 4 + j;
                    sS[rl][wc] = ps;
                    sD[rl][wc] = pd;
                }
            }
        }
    }
    #pragma unroll
    for (int mf = 0; mf < MF; mf++) {
        #pragma unroll
        for (int nf = 0; nf < NF; nf++) {
            int col = wc * (NF * 16) + nf * 16 + lr;
            #pragma unroll
            for (int j = 0; j < 4; j++) {
                int row = bm + wr * (MF * 16) + mf * 16 + lg * 4 + j;
                float v = acc[mf][nf][j];
                float w = __shfl_xor(v, 1);
                if (!(lane & 1) && row < M)
                    C[(size_t)row * (BN >> 1) + (col >> 1)] = packbf(v, w);
            }
        }
    }
    __syncthreads();
    if (tid < 64) {
        int row = bm + tid;
        if (row < M) {
            ssrc[row] = sS[tid][0] + sS[tid][1];
            sdst[row] = sD[tid][0] + sD[tid][1];
        }
    }
}

// ---------------- attention softmax + aggregation (one wave per dst node, both sides) ----------------
// Fast path: lane-parallel softmax once; uint2 gathers (2/4 edges per instr) AND 4 loads in
// flight per iteration (8 edges F=128 / 16 edges F=64) for latency hiding.
template<int F>
__global__ __launch_bounds__(256) void attn_agg2(const uint32_t* __restrict__ hb,
        const float* __restrict__ ssrc_b, const float* __restrict__ sdst_b,
        const int* __restrict__ row_ptr_b, const int* __restrict__ csr_b,
        const float* __restrict__ bias0, const float* __restrict__ bias1,
        uint32_t* __restrict__ xout_b, int n) {
    int side = blockIdx.y;
    const uint32_t* h = hb + (size_t)side * HS;
    const float* ssrc = ssrc_b + (size_t)side * Nn;
    const float* sdst = sdst_b + (size_t)side * Nn;
    const int* row_ptr = row_ptr_b + (size_t)side * (Nn + 1);
    const int* csr_src = csr_b + (size_t)side * Ecnt;
    const float* bias = side ? bias1 : bias0;
    uint32_t* xout = xout_b + (size_t)side * HS;

    int wid = (blockIdx.x * blockDim.x + threadIdx.x) >> 6;
    int lane = threadIdx.x & 63;
    if (wid >= n) return;
    int beg = row_ptr[wid], end = row_ptr[wid + 1];
    int deg = end - beg;
    float sd = sdst[wid];
    float eself = lrelu(ssrc[wid] + sd);
    constexpr int RU = F / 2;

    if (deg <= 64) {
        int p = beg + lane;
        bool act = p < end;
        int s = act ? csr_src[p] : 0;
        float e = act ? lrelu(ssrc[s] + sd) : -1e30f;
        float m = fmaxf(eself, e);
        #pragma unroll
        for (int o = 32; o; o >>= 1) m = fmaxf(m, __shfl_xor(m, o));
        float ex = act ? __expf(e - m) : 0.f;
        float dsum = ex;
        #pragma unroll
        for (int o = 32; o; o >>= 1) dsum += __shfl_xor(dsum, o);
        float exself = __expf(eself - m);
        dsum += exself;
        float inv = 1.f / dsum;
        float w = ex * inv;
        float wself = exself * inv;

        if constexpr (F == 128) {
            // half-wave per edge: lane = (half, i); lane i owns dwords 2i,2i+1 (4 feats)
            int half = lane >> 5, i = lane & 31;
            float a0 = 0.f, a1 = 0.f, a2 = 0.f, a3 = 0.f;
            if (half == 0) {
                uint2 v = *(const uint2*)(h + ((size_t)wid << 6) + 2 * i);
                a0 = wself * bflo(v.x); a1 = wself * bfhi(v.x);
                a2 = wself * bflo(v.y); a3 = wself * bfhi(v.y);
            }
            int j = half;
            for (; j + 6 < deg; j += 8) {
                float w0 = __shfl(w, j),     w1 = __shfl(w, j + 2);
                float w2 = __shfl(w, j + 4), w3 = __shfl(w, j + 6);
                int   s0 = __shfl(s, j),     s1 = __shfl(s, j + 2);
                int   s2 = __shfl(s, j + 4), s3 = __shfl(s, j + 6);
                uint2 u0 = *(const uint2*)(h + ((size_t)s0 << 6) + 2 * i);
                uint2 u1 = *(const uint2*)(h + ((size_t)s1 << 6) + 2 * i);
                uint2 u2 = *(const uint2*)(h + ((size_t)s2 << 6) + 2 * i);
                uint2 u3 = *(const uint2*)(h + ((size_t)s3 << 6) + 2 * i);
                a0 += w0 * bflo(u0.x) + w1 * bflo(u1.x) + w2 * bflo(u2.x) + w3 * bflo(u3.x);
                a1 += w0 * bfhi(u0.x) + w1 * bfhi(u1.x) + w2 * bfhi(u2.x) + w3 * bfhi(u3.x);
                a2 += w0 * bflo(u0.y) + w1 * bflo(u1.y) + w2 * bflo(u2.y) + w3 * bflo(u3.y);
                a3 += w0 * bfhi(u0.y) + w1 * bfhi(u1.y) + w2 * bfhi(u2.y) + w3 * bfhi(u3.y);
            }
            for (; j < deg; j += 2) {
                float w0 = __shfl(w, j);
                int   s0 = __shfl(s, j);
                uint2 u0 = *(const uint2*)(h + ((size_t)s0 << 6) + 2 * i);
                a0 += w0 * bflo(u0.x); a1 += w0 * bfhi(u0.x);
                a2 += w0 * bflo(u0.y); a3 += w0 * bfhi(u0.y);
            }
            a0 += __shfl_xor(a0, 32); a1 += __shfl_xor(a1, 32);
            a2 += __shfl_xor(a2, 32); a3 += __shfl_xor(a3, 32);
            if (half == 0) {
                float r0 = fmaxf(a0 + bias[4 * i], 0.f);
                float r1 = fmaxf(a1 + bias[4 * i + 1], 0.f);
                float r2 = fmaxf(a2 + bias[4 * i + 2], 0.f);
                float r3 = fmaxf(a3 + bias[4 * i + 3], 0.f);
                *(uint2*)(xout + ((size_t)wid << 6) + 2 * i) = make_uint2(packbf(r0, r1), packbf(r2, r3));
            }
        } else {
            // quarter-wave per edge: lane = (q, i); lane i owns dwords 2i,2i+1 (4 feats)
            int q = lane >> 4, i = lane & 15;
            float a0 = 0.f, a1 = 0.f, a2 = 0.f, a3 = 0.f;
            if (q == 0) {
                uint2 v = *(const uint2*)(h + ((size_t)wid << 5) + 2 * i);
                a0 = wself * bflo(v.x); a1 = wself * bfhi(v.x);
                a2 = wself * bflo(v.y); a3 = wself * bfhi(v.y);
            }
            int j = q;
            for (; j + 12 < deg; j += 16) {
                float w0 = __shfl(w, j),     w1 = __shfl(w, j + 4);
                float w2 = __shfl(w, j + 8), w3 = __shfl(w, j + 12);
                int   s0 = __shfl(s, j),     s1 = __shfl(s, j + 4);
                int   s2 = __shfl(s, j + 8), s3 = __shfl(s, j + 12);
                uint2 u0 = *(const uint2*)(h + ((size_t)s0 << 5) + 2 * i);
                uint2 u1 = *(const uint2*)(h + ((size_t)s1 << 5) + 2 * i);
                uint2 u2 = *(const uint2*)(h + ((size_t)s2 << 5) + 2 * i);
                uint2 u3 = *(const uint2*)(h + ((size_t)s3 << 5) + 2 * i);
                a0 += w0 * bflo(u0.x) + w1 * bflo(u1.x) + w2 * bflo(u2.x) + w3 * bflo(u3.x);
                a1 += w0 * bfhi(u0.x) + w1 * bfhi(u1.x) + w2 * bfhi(u2.x) + w3 * bfhi(u3.x);
                a2 += w0 * bflo(u0.y) + w1 * bflo(u1.y) + w2 * bflo(u2.y) + w3 * bflo(u3.y);
                a3 += w0 * bfhi(u0.y) + w1 * bfhi(u1.y) + w2 * bfhi(u2.y) + w3 * bfhi(u3.y);
            }
            for (; j < deg; j += 4) {
                float w0 = __shfl(w, j);
                int   s0 = __shfl(s, j);
                uint2 u0 = *(const uint2*)(h + ((size_t)s0 << 5) + 2 * i);
                a0 += w0 * bflo(u0.x); a1 += w0 * bfhi(u0.x);
                a2 += w0 * bflo(u0.y); a3 += w0 * bfhi(u0.y);
            }
            a0 += __shfl_xor(a0, 16); a1 += __shfl_xor(a1, 16);
            a2 += __shfl_xor(a2, 16); a3 += __shfl_xor(a3, 16);
            a0 += __shfl_xor(a0, 32); a1 += __shfl_xor(a1, 32);
            a2 += __shfl_xor(a2, 32); a3 += __shfl_xor(a3, 32);
            if (q == 0) {
                float r0 = fmaxf(a0 + bias[4 * i], 0.f);
                float r1 = fmaxf(a1 + bias[4 * i + 1], 0.f);
                float r2 = fmaxf(a2 + bias[4 * i + 2], 0.f);
                float r3 = fmaxf(a3 + bias[4 * i + 3], 0.f);
                *(uint2*)(xout + ((size_t)wid << 5) + 2 * i) = make_uint2(packbf(r0, r1), packbf(r2, r3));
            }
        }
        return;
    }

    // generic path (deg > 64)
    float m = eself;
    for (int p = beg + lane; p < end; p += 64)
        m = fmaxf(m, lrelu(ssrc[csr_src[p]] + sd));
    #pragma unroll
    for (int o = 32; o; o >>= 1) m = fmaxf(m, __shfl_xor(m, o));
    float dsum = (lane == 0) ? __expf(eself - m) : 0.f;
    for (int p = beg + lane; p < end; p += 64)
        dsum += __expf(lrelu(ssrc[csr_src[p]] + sd) - m);
    #pragma unroll
    for (int o = 32; o; o >>= 1) dsum += __shfl_xor(dsum, o);
    float inv = 1.f / dsum;
    float wself = __expf(eself - m) * inv;

    if constexpr (F == 128) {
        uint32_t v = h[(size_t)wid * RU + lane];
        float acc0 = wself * bflo(v), acc1 = wself * bfhi(v);
        for (int p = beg; p < end; ++p) {
            int s0 = csr_src[p];
            uint32_t v0 = h[(size_t)s0 * RU + lane];
            float w0 = __expf(lrelu(ssrc[s0] + sd) - m) * inv;
            acc0 += w0 * bflo(v0);
            acc1 += w0 * bfhi(v0);
        }
        float r0 = fmaxf(acc0 + bias[2 * lane], 0.f);
        float r1 = fmaxf(acc1 + bias[2 * lane + 1], 0.f);
        xout[(size_t)wid * RU + lane] = packbf(r0, r1);
    } else {
        int half = lane >> 5, i = lane & 31;
        float acc0 = 0.f, acc1 = 0.f;
        if (half == 0) {
            uint32_t v = h[(size_t)wid * RU + i];
            acc0 = wself * bflo(v);
            acc1 = wself * bfhi(v);
        }
        for (int p = beg + half; p < end; p += 2) {
            int s0 = csr_src[p];
            uint32_t v = h[(size_t)s0 * RU + i];
            float w0 = __expf(lrelu(ssrc[s0] + sd) - m) * inv;
            acc0 += w0 * bflo(v);
            acc1 += w0 * bfhi(v);
        }
        acc0 += __shfl_xor(acc0, 32);
        acc1 += __shfl_xor(acc1, 32);
        if (half == 0) {
            float r0 = fmaxf(acc0 + bias[2 * i], 0.f);
            float r1 = fmaxf(acc1 + bias[2 * i + 1], 0.f);
            xout[(size_t)wid * RU + i] = packbf(r0, r1);
        }
    }
}

// ---------------- mean pool (sorted batch), both sides ----------------
__global__ __launch_bounds__(256) void pool2(const uint32_t* __restrict__ xb,
                                             const int* __restrict__ bat0,
                                             const int* __restrict__ bat1,
                                             float* __restrict__ pooled_b, int n) {
    int side = blockIdx.y;
    const uint32_t* x = xb + (size_t)side * HS;
    const int* batch = side ? bat1 : bat0;
    float* pooled = pooled_b + (size_t)side * Gn * 64;
    int g = blockIdx.x;
    int tid = threadIdx.x;
    __shared__ int s_lo, s_hi;
    if (tid == 0) {
        int lo = 0, hi = n;
        while (lo < hi) { int mid = (lo + hi) >> 1; if (batch[mid] < g) lo = mid + 1; else hi = mid; }
        s_lo = lo;
        int lo2 = lo, hi2 = n;
        while (lo2 < hi2) { int mid = (lo2 + hi2) >> 1; if (batch[mid] < g + 1) lo2 = mid + 1; else hi2 = mid; }
        s_hi = lo2;
    }
    __syncthreads();
    int lo = s_lo, hi = s_hi;
    int grp = tid >> 5, col = tid & 31;
    float a0 = 0.f, a1 = 0.f;
    for (int i = lo + grp; i < hi; i += 8) {
        uint32_t v = x[(size_t)i * 32 + col];
        a0 += bflo(v);
        a1 += bfhi(v);
    }
    __shared__ float red0[8][32], red1[8][32];
    red0[grp][col] = a0;
    red1[grp][col] = a1;
    __syncthreads();
    if (tid < 32) {
        float s0 = 0.f, s1 = 0.f;
        #pragma unroll
        for (int r = 0; r < 8; r++) { s0 += red0[r][tid]; s1 += red1[r][tid]; }
        float c = fmaxf((float)(hi - lo), 1.f);
        pooled[g * 64 + 2 * tid]     = s0 / c;
        pooled[g * 64 + 2 * tid + 1] = s1 / c;
    }
}

// ---------------- head ----------------
__global__ __launch_bounds__(256) void head_kernel(const float* __restrict__ xs,
                                                   const float* __restrict__ xt,
                                                   const float* __restrict__ Wlin,
                                                   const float* __restrict__ blin,
                                                   float* __restrict__ out) {
    int g = blockIdx.y;
    int c = blockIdx.x * 256 + threadIdx.x;
    __shared__ float z[64];
    if (threadIdx.x < 64) z[threadIdx.x] = xs[g * 64 + threadIdx.x] + xt[g * 64 + threadIdx.x];
    __syncthreads();
    float a0 = 0.f, a1 = 0.f, a2 = 0.f, a3 = 0.f;
    #pragma unroll
    for (int k = 0; k < 64; k += 4) {
        a0 += z[k]     * Wlin[(size_t)(k)     * Lout + c];
        a1 += z[k + 1] * Wlin[(size_t)(k + 1) * Lout + c];
        a2 += z[k + 2] * Wlin[(size_t)(k + 2) * Lout + c];
        a3 += z[k + 3] * Wlin[(size_t)(k + 3) * Lout + c];
    }
    float acc = (a0 + a1) + (a2 + a3) + blin[c];
    out[(size_t)g * Lout + c] = 1.f / (1.f + expf(-acc));
}

extern "C" void kernel_launch(void* const* d_in, const int* in_sizes, int n_in,
                              void* d_out, int out_size, void* d_ws, size_t ws_size,
                              hipStream_t stream) {
    size_t off = 0;
    auto alloc = [&](size_t bytes) -> void* {
        void* p = (char*)d_ws + off;
        off += (bytes + 255) & ~(size_t)255;
        return p;
    };
    uint32_t* hbuf    = (uint32_t*)alloc(2 * HS * 4);
    uint32_t* xbuf    = (uint32_t*)alloc(2 * HS * 4);
    float* ssrc       = (float*)alloc(2 * (size_t)Nn * 4);
    float* sdst       = (float*)alloc(2 * (size_t)Nn * 4);
    int*   row_ptr    = (int*)alloc(2 * (size_t)(Nn + 1) * 4);
    int*   csr        = (int*)alloc(2 * (size_t)Ecnt * 4);
    uint32_t* bkt_edges = (uint32_t*)alloc(2 * (size_t)Ecnt * 4);
    int*   bkt_cnt    = (int*)alloc(2 * (size_t)(NBKT + 1) * 4);
    int*   bkt_ptr    = (int*)alloc(2 * (size_t)(NBKT + 1) * 4);
    int*   bkt_cur    = (int*)alloc(2 * (size_t)(NBKT + 1) * 4);
    float* pooled     = (float*)alloc(2 * (size_t)Gn * 64 * 4);

    const int NW = (Nn * 64 + 255) / 256;
    const int GB = (Nn + 63) / 64;

    const float* x_s = (const float*)d_in[0];
    const float* x_t = (const float*)d_in[1];
    const int* ei_s  = (const int*)d_in[2];
    const int* ei_t  = (const int*)d_in[3];
    const int* bat_s = (const int*)d_in[4];
    const int* bat_t = (const int*)d_in[5];
    const float *Ws1 = (const float*)d_in[6],  *as1s = (const float*)d_in[7],
                *as1d = (const float*)d_in[8],  *bs1 = (const float*)d_in[9];
    const float *Ws2 = (const float*)d_in[10], *as2s = (const float*)d_in[11],
                *as2d = (const float*)d_in[12], *bs2 = (const float*)d_in[13];
    const float *Wt1 = (const float*)d_in[14], *at1s = (const float*)d_in[15],
                *at1d = (const float*)d_in[16], *bt1 = (const float*)d_in[17];
    const float *Wt2 = (const float*)d_in[18], *at2s = (const float*)d_in[19],
                *at2d = (const float*)d_in[20], *bt2 = (const float*)d_in[21];
    const float *Wlin = (const float*)d_in[22], *blin = (const float*)d_in[23];

    // ---- memset counters, then layer-1 GEMM with FUSED bucket-count ----
    hipMemsetAsync(bkt_cnt, 0, 2 * (size_t)(NBKT + 1) * 4, stream);
    mfma_gemm2<2, 4, 128, false, true><<<dim3(GB + EBC, 2), 256, 0, stream>>>(
        x_s, x_t, Ws1, Wt1, hbuf, HS, as1s, at1s, as1d, at1d, ssrc, sdst, Nn, Din,
        ei_s, ei_t, bkt_cnt);
    // ---- rest of CSR build ----
    bkt_scan2<<<2, 512, 0, stream>>>(bkt_cnt, bkt_ptr, bkt_cur, row_ptr);
    bkt_scatter2<<<dim3(EBC, 2), 256, 0, stream>>>(ei_s, ei_t, bkt_cur, bkt_edges, Ecnt);
    csr_finalize2<<<dim3(NBKT, 2), 256, 0, stream>>>(bkt_edges, bkt_ptr, row_ptr, csr, Nn);
    // ---- attention layer 1 ----
    attn_agg2<128><<<dim3(NW, 2), 256, 0, stream>>>(hbuf, ssrc, sdst, row_ptr, csr, bs1, bt1, xbuf, Nn);
    // ---- layer 2: 128 -> 64 (bf16 A), scores fused ----
    mfma_gemm2<2, 2, 64, true, false><<<dim3(GB, 2), 256, 0, stream>>>(
        xbuf, xbuf + HS, Ws2, Wt2, hbuf, HS, as2s, at2s, as2d, at2d, ssrc, sdst, Nn, 128,
        nullptr, nullptr, nullptr);
    attn_agg2<64><<<dim3(NW, 2), 256, 0, stream>>>(hbuf, ssrc, sdst, row_ptr, csr, bs2, bt2, xbuf, Nn);
    // ---- pool + head ----
    pool2<<<dim3(Gn, 2), 256, 0, stream>>>(xbuf, bat_s, bat_t, pooled, Nn);
    head_kernel<<<dim3(Lout / 256, Gn), 256, 0, stream>>>(pooled, pooled + (size_t)Gn * 64,
                                                          Wlin, blin, (float*)d_out);
}

// Round 12
// 239.341 us; speedup vs baseline: 6.5784x; 1.0456x over previous
//
#include <hip/hip_runtime.h>
#include <hip/hip_bf16.h>
#include <math.h>

constexpr int Nn   = 50000;
constexpr int Ecnt = 800000;
constexpr int Gn   = 128;
constexpr int Din  = 256;
constexpr int Lout = 1024;

constexpr int BKT_SH = 7;
constexpr int NBKT   = (Nn + 127) >> BKT_SH;    // 391
constexpr int CHUNK  = 4096;
constexpr int EBC    = (Ecnt + CHUNK - 1) / CHUNK;  // 196
constexpr size_t HS  = (size_t)Nn * 64;         // xbuf per-side stride (dwords, bf16 rows)

typedef __attribute__((ext_vector_type(8))) short short8;
typedef __attribute__((ext_vector_type(4))) float f32x4;
typedef __attribute__((ext_vector_type(2))) float v2f;

__device__ __forceinline__ float lrelu(float x) { return x >= 0.f ? x : 0.2f * x; }

__device__ __forceinline__ float bflo(uint32_t v) { return __uint_as_float(v << 16); }
__device__ __forceinline__ float bfhi(uint32_t v) { return __uint_as_float(v & 0xffff0000u); }
__device__ __forceinline__ uint32_t f2bf(float f) {
    uint32_t x = __float_as_uint(f);
    return (x + 0x7fffu + ((x >> 16) & 1u)) >> 16;
}
__device__ __forceinline__ uint32_t packbf(float lo, float hi) {
    return f2bf(lo) | (f2bf(hi) << 16);
}
// software fp8 e4m3 decode (cold paths only)
__device__ __forceinline__ float fp8sw(uint32_t b) {
    uint32_t mag = b & 0x7f;
    float fn = __uint_as_float((mag << 20) + 0x3C000000u);
    float fd = (float)(int)mag * 0x1p-9f;
    float af = (mag >= 8u) ? fn : fd;
    return __uint_as_float(__float_as_uint(af) | ((b & 0x80u) << 24));
}

// ================= CSR build (side = blockIdx.y) =================
__global__ __launch_bounds__(512) void bkt_scan2(const int* __restrict__ bkt_cnt_b,
                                                 int* __restrict__ bkt_ptr_b,
                                                 int* __restrict__ bkt_cur_b,
                                                 int* __restrict__ row_ptr_b) {
    int side = blockIdx.x;
    const int* bkt_cnt = bkt_cnt_b + (size_t)side * (NBKT + 1);
    int* bkt_ptr = bkt_ptr_b + (size_t)side * (NBKT + 1);
    int* bkt_cur = bkt_cur_b + (size_t)side * (NBKT + 1);
    int* row_ptr = row_ptr_b + (size_t)side * (Nn + 1);
    __shared__ int buf[512];
    int t = threadIdx.x;
    int v = (t < NBKT) ? bkt_cnt[t] : 0;
    buf[t] = v;
    __syncthreads();
    for (int off = 1; off < 512; off <<= 1) {
        int x = (t >= off) ? buf[t - off] : 0;
        __syncthreads();
        buf[t] += x;
        __syncthreads();
    }
    if (t < NBKT) {
        int excl = buf[t] - v;
        bkt_ptr[t] = excl;
        bkt_cur[t] = excl;
    }
    if (t == 511) {
        bkt_ptr[NBKT] = buf[511];
        row_ptr[Nn]   = buf[511];
    }
}

__global__ __launch_bounds__(256) void bkt_scatter2(const int* __restrict__ e0,
                                                    const int* __restrict__ e1,
                                                    int* __restrict__ bkt_cur_b,
                                                    uint32_t* __restrict__ bkt_edges_b, int E) {
    int side = blockIdx.y;
    const int* src = side ? e1 : e0;
    const int* dst = src + E;
    int* bkt_cur = bkt_cur_b + (size_t)side * (NBKT + 1);
    uint32_t* bkt_edges = bkt_edges_b + (size_t)side * Ecnt;
    __shared__ int h[NBKT];
    __shared__ int cur[NBKT];
    for (int i = threadIdx.x; i < NBKT; i += 256) h[i] = 0;
    __syncthreads();
    int base = blockIdx.x * CHUNK;
    int end = min(base + CHUNK, E);
    for (int i = base + threadIdx.x; i < end; i += 256)
        atomicAdd(&h[dst[i] >> BKT_SH], 1);
    __syncthreads();
    for (int i = threadIdx.x; i < NBKT; i += 256) {
        int c = h[i];
        h[i] = c ? atomicAdd(&bkt_cur[i], c) : 0;
        cur[i] = 0;
    }
    __syncthreads();
    for (int i = base + threadIdx.x; i < end; i += 256) {
        int d = dst[i], b = d >> BKT_SH;
        int pos = h[b] + atomicAdd(&cur[b], 1);
        bkt_edges[pos] = (uint32_t)src[i] | ((uint32_t)(d & 127) << 16);
    }
}

__global__ __launch_bounds__(256) void csr_finalize2(const uint32_t* __restrict__ bkt_edges_b,
                                                     const int* __restrict__ bkt_ptr_b,
                                                     int* __restrict__ row_ptr_b,
                                                     int* __restrict__ csr_b, int n) {
    int side = blockIdx.y;
    const uint32_t* bkt_edges = bkt_edges_b + (size_t)side * Ecnt;
    const int* bkt_ptr = bkt_ptr_b + (size_t)side * (NBKT + 1);
    int* row_ptr = row_ptr_b + (size_t)side * (Nn + 1);
    int* csr = csr_b + (size_t)side * Ecnt;
    int b = blockIdx.x;
    int base = bkt_ptr[b];
    int cnt  = bkt_ptr[b + 1] - base;
    __shared__ int hist[128], curs[128], sc[128];
    int t = threadIdx.x;
    if (t < 128) hist[t] = 0;
    __syncthreads();
    for (int i = t; i < cnt; i += 256)
        atomicAdd(&hist[(bkt_edges[base + i] >> 16) & 127], 1);
    __syncthreads();
    if (t < 128) sc[t] = hist[t];
    __syncthreads();
    for (int off = 1; off < 128; off <<= 1) {
        int x = (t >= off && t < 128) ? sc[t - off] : 0;
        __syncthreads();
        if (t < 128) sc[t] += x;
        __syncthreads();
    }
    if (t < 128) {
        int excl = sc[t] - hist[t];
        int node = (b << BKT_SH) + t;
        if (node < n) row_ptr[node] = base + excl;
        curs[t] = excl;
    }
    __syncthreads();
    for (int i = t; i < cnt; i += 256) {
        uint32_t e = bkt_edges[base + i];
        int pos = atomicAdd(&curs[(e >> 16) & 127], 1);
        csr[base + pos] = (int)(e & 0xFFFFu);
    }
}

// ---------------- MFMA bf16 GEMM -> fp8 C + fused scores (+ optional fused bucket-count) ----------------
template<int MF, int NF, int BN, bool BF16A, bool FUSE_COUNT>
__global__ __launch_bounds__(256) void mfma_gemm2(
        const void* __restrict__ A0, const void* __restrict__ A1,
        const float* __restrict__ B0, const float* __restrict__ B1,
        uint32_t* __restrict__ Cb, size_t cstride,
        const float* __restrict__ as0, const float* __restrict__ as1,
        const float* __restrict__ ad0, const float* __restrict__ ad1,
        float* __restrict__ ssrc_b, float* __restrict__ sdst_b,
        int M, int K,
        const int* __restrict__ e0, const int* __restrict__ e1,
        int* __restrict__ bkt_cnt_b) {
    __shared__ uint32_t Al[64][36];
    __shared__ uint32_t Bl[BN][36];
    __shared__ float sS[64][2], sD[64][2];
    int side = blockIdx.y;

    if constexpr (FUSE_COUNT) {
        int gb = (M + 63) >> 6;
        if ((int)blockIdx.x >= gb) {
            int chunk = blockIdx.x - gb;
            const int* dst = (side ? e1 : e0) + Ecnt;
            int* bkt_cnt = bkt_cnt_b + (size_t)side * (NBKT + 1);
            int* hh = (int*)&Al[0][0];
            for (int i = threadIdx.x; i < NBKT; i += 256) hh[i] = 0;
            __syncthreads();
            int base = chunk * CHUNK;
            int end = min(base + CHUNK, Ecnt);
            for (int i = base + threadIdx.x; i < end; i += 256)
                atomicAdd(&hh[dst[i] >> BKT_SH], 1);
            __syncthreads();
            for (int i = threadIdx.x; i < NBKT; i += 256) {
                int c = hh[i];
                if (c) atomicAdd(&bkt_cnt[i], c);
            }
            return;
        }
    }

    const void* Av = side ? A1 : A0;
    const float* B = side ? B1 : B0;
    const float* Asrc = side ? as1 : as0;
    const float* Adst = side ? ad1 : ad0;
    uint32_t* C = Cb + (size_t)side * cstride;
    float* ssrc = ssrc_b + (size_t)side * Nn;
    float* sdst = sdst_b + (size_t)side * Nn;

    int tid  = threadIdx.x;
    int lane = tid & 63;
    int wid  = tid >> 6;
    int wr = wid >> 1, wc = wid & 1;
    int bm = blockIdx.x * 64;

    int arow = tid >> 2, aq = tid & 3;
    bool avalid = (bm + arow) < M;
    constexpr int NPI = BN * 16 / 256;

    float    fA[16];
    uint32_t uA[8];
    float    fB[NPI][4];

    auto LOADA = [&](int k0) {
        if constexpr (BF16A) {
            const uint32_t* A = (const uint32_t*)Av;
            if (avalid) {
                const uint32_t* p = A + (size_t)(bm + arow) * (K >> 1) + (k0 >> 1) + aq * 8;
                uint4 u0 = *(const uint4*)p;
                uint4 u1 = *(const uint4*)(p + 4);
                uA[0] = u0.x; uA[1] = u0.y; uA[2] = u0.z; uA[3] = u0.w;
                uA[4] = u1.x; uA[5] = u1.y; uA[6] = u1.z; uA[7] = u1.w;
            } else {
                #pragma unroll
                for (int i = 0; i < 8; i++) uA[i] = 0u;
            }
        } else {
            const float* A = (const float*)Av;
            if (avalid) {
                const float* p = A + (size_t)(bm + arow) * K + k0 + aq * 16;
                #pragma unroll
                for (int i = 0; i < 4; i++) {
                    float4 f = *(const float4*)(p + i * 4);
                    fA[4 * i] = f.x; fA[4 * i + 1] = f.y; fA[4 * i + 2] = f.z; fA[4 * i + 3] = f.w;
                }
            } else {
                #pragma unroll
                for (int i = 0; i < 16; i++) fA[i] = 0.f;
            }
        }
    };
    auto LOADB = [&](int k0) {
        #pragma unroll
        for (int it = 0; it < NPI; it++) {
            int pi = tid + it * 256;
            int n = pi & (BN - 1);
            int kp = pi / BN;
            const float* p = B + (size_t)(k0 + 4 * kp) * BN + n;
            fB[it][0] = p[0];
            fB[it][1] = p[BN];
            fB[it][2] = p[2 * BN];
            fB[it][3] = p[3 * BN];
        }
    };
    auto WRITE = [&]() {
        if constexpr (BF16A) {
            uint4* dst = (uint4*)&Al[arow][aq * 8];
            dst[0] = make_uint4(uA[0], uA[1], uA[2], uA[3]);
            dst[1] = make_uint4(uA[4], uA[5], uA[6], uA[7]);
        } else {
            uint32_t d[8];
            #pragma unroll
            for (int i = 0; i < 8; i++) d[i] = packbf(fA[2 * i], fA[2 * i + 1]);
            uint4* dst = (uint4*)&Al[arow][aq * 8];
            dst[0] = make_uint4(d[0], d[1], d[2], d[3]);
            dst[1] = make_uint4(d[4], d[5], d[6], d[7]);
        }
        #pragma unroll
        for (int it = 0; it < NPI; it++) {
            int pi = tid + it * 256;
            int n = pi & (BN - 1);
            int kp = pi / BN;
            *(uint2*)&Bl[n][2 * kp] = make_uint2(packbf(fB[it][0], fB[it][1]),
                                                 packbf(fB[it][2], fB[it][3]));
        }
    };

    f32x4 acc[MF][NF];
    #pragma unroll
    for (int i = 0; i < MF; i++)
        #pragma unroll
        for (int j = 0; j < NF; j++) acc[i][j] = (f32x4){0.f, 0.f, 0.f, 0.f};

    LOADA(0); LOADB(0);
    const int T = K / 64;
    for (int t = 0; t < T; t++) {
        WRITE();
        __syncthreads();
        if (t + 1 < T) { LOADA((t + 1) * 64); LOADB((t + 1) * 64); }
        int lr = lane & 15, lk = lane >> 4;
        #pragma unroll
        for (int ks = 0; ks < 2; ks++) {
            short8 af[MF], bf[NF];
            #pragma unroll
            for (int mf = 0; mf < MF; mf++)
                af[mf] = *(const short8*)&Al[wr * (MF * 16) + mf * 16 + lr][ks * 16 + lk * 4];
            #pragma unroll
            for (int nf = 0; nf < NF; nf++)
                bf[nf] = *(const short8*)&Bl[wc * (NF * 16) + nf * 16 + lr][ks * 16 + lk * 4];
            #pragma unroll
            for (int mf = 0; mf < MF; mf++)
                #pragma unroll
                for (int nf = 0; nf < NF; nf++)
                    acc[mf][nf] = __builtin_amdgcn_mfma_f32_16x16x32_bf16(af[mf], bf[nf], acc[mf][nf], 0, 0, 0);
        }
        __syncthreads();
    }

    int lr = lane & 15, lg = lane >> 4;
    // fused scores (from exact fp32 acc)
    {
        float a_s[NF], a_d[NF];
        #pragma unroll
        for (int nf = 0; nf < NF; nf++) {
            int col = wc * (NF * 16) + nf * 16 + lr;
            a_s[nf] = Asrc[col];
            a_d[nf] = Adst[col];
        }
        #pragma unroll
        for (int mf = 0; mf < MF; mf++) {
            #pragma unroll
            for (int j = 0; j < 4; j++) {
                float ps = 0.f, pd = 0.f;
                #pragma unroll
                for (int nf = 0; nf < NF; nf++) {
                    float v = acc[mf][nf][j];
                    ps += v * a_s[nf];
                    pd += v * a_d[nf];
                }
                #pragma unroll
                for (int o = 1; o < 16; o <<= 1) {
                    ps += __shfl_xor(ps, o);
                    pd += __shfl_xor(pd, o);
                }
                if (lr == 0) {
                    int rl = wr * (MF * 16) + mf * 16 + lg * 4 + j;
                    sS[rl][wc] = ps;
                    sD[rl][wc] = pd;
                }
            }
        }
    }
    // C write as fp8 e4m3 (HW cvt): 4 cols -> 1 dword
    #pragma unroll
    for (int mf = 0; mf < MF; mf++) {
        #pragma unroll
        for (int nf = 0; nf < NF; nf++) {
            int col = wc * (NF * 16) + nf * 16 + lr;
            #pragma unroll
            for (int j = 0; j < 4; j++) {
                int row = bm + wr * (MF * 16) + mf * 16 + lg * 4 + j;
                float v = acc[mf][nf][j];
                float w1 = __shfl_xor(v, 1);
                uint32_t p01 = (uint32_t)__builtin_amdgcn_cvt_pk_fp8_f32(v, w1, 0, false);
                uint32_t p23 = __shfl_xor(p01, 2);
                if (((lane & 3) == 0) && row < M)
                    C[(size_t)row * (BN >> 2) + (col >> 2)] = (p01 & 0xffffu) | (p23 << 16);
            }
        }
    }
    __syncthreads();
    if (tid < 64) {
        int row = bm + tid;
        if (row < M) {
            ssrc[row] = sS[tid][0] + sS[tid][1];
            sdst[row] = sD[tid][0] + sD[tid][1];
        }
    }
}

// ---------------- attention softmax + aggregation: fp8 h gather, bf16 out ----------------
template<int F>
__global__ __launch_bounds__(256) void attn_agg2(const uint32_t* __restrict__ hb,
        const float* __restrict__ ssrc_b, const float* __restrict__ sdst_b,
        const int* __restrict__ row_ptr_b, const int* __restrict__ csr_b,
        const float* __restrict__ bias0, const float* __restrict__ bias1,
        uint32_t* __restrict__ xout_b, int n) {
    constexpr size_t HSTR = (size_t)Nn * (F / 4);   // fp8 row dwords
    constexpr int HD = F / 4;                       // dwords per fp8 row
    constexpr int XD = F / 2;                       // dwords per bf16 out row
    int side = blockIdx.y;
    const uint32_t* h = hb + (size_t)side * HSTR;
    const float* ssrc = ssrc_b + (size_t)side * Nn;
    const float* sdst = sdst_b + (size_t)side * Nn;
    const int* row_ptr = row_ptr_b + (size_t)side * (Nn + 1);
    const int* csr_src = csr_b + (size_t)side * Ecnt;
    const float* bias = side ? bias1 : bias0;
    uint32_t* xout = xout_b + (size_t)side * HS;

    int wid = (blockIdx.x * blockDim.x + threadIdx.x) >> 6;
    int lane = threadIdx.x & 63;
    if (wid >= n) return;
    int beg = row_ptr[wid], end = row_ptr[wid + 1];
    int deg = end - beg;
    float sd = sdst[wid];
    float eself = lrelu(ssrc[wid] + sd);

    if (deg <= 64) {
        int p = beg + lane;
        bool act = p < end;
        int s = act ? csr_src[p] : 0;
        float e = act ? lrelu(ssrc[s] + sd) : -1e30f;
        float m = fmaxf(eself, e);
        #pragma unroll
        for (int o = 32; o; o >>= 1) m = fmaxf(m, __shfl_xor(m, o));
        float ex = act ? __expf(e - m) : 0.f;
        float dsum = ex;
        #pragma unroll
        for (int o = 32; o; o >>= 1) dsum += __shfl_xor(dsum, o);
        float exself = __expf(eself - m);
        dsum += exself;
        float inv = 1.f / dsum;
        float w = ex * inv;
        float wself = exself * inv;

        int q = lane >> 4, i = lane & 15;   // quarter-wave per edge
        if constexpr (F == 128) {
            // lane i owns feats 8i..8i+7 (uint2 of fp8)
            float a0=0,a1=0,a2=0,a3=0,a4=0,a5=0,a6=0,a7=0;
            auto FMA8 = [&](uint2 u, float wj) {
                v2f p0 = __builtin_amdgcn_cvt_pk_f32_fp8(u.x, false);
                v2f p1 = __builtin_amdgcn_cvt_pk_f32_fp8(u.x, true);
                v2f p2 = __builtin_amdgcn_cvt_pk_f32_fp8(u.y, false);
                v2f p3 = __builtin_amdgcn_cvt_pk_f32_fp8(u.y, true);
                a0 += wj * p0[0]; a1 += wj * p0[1];
                a2 += wj * p1[0]; a3 += wj * p1[1];
                a4 += wj * p2[0]; a5 += wj * p2[1];
                a6 += wj * p3[0]; a7 += wj * p3[1];
            };
            if (q == 0) {
                uint2 v = *(const uint2*)(h + (size_t)wid * HD + 2 * i);
                FMA8(v, wself);
            }
            int j = q;
            for (; j + 12 < deg; j += 16) {
                float w0 = __shfl(w, j),     w1 = __shfl(w, j + 4);
                float w2 = __shfl(w, j + 8), w3 = __shfl(w, j + 12);
                int   s0 = __shfl(s, j),     s1 = __shfl(s, j + 4);
                int   s2 = __shfl(s, j + 8), s3 = __shfl(s, j + 12);
                uint2 u0 = *(const uint2*)(h + (size_t)s0 * HD + 2 * i);
                uint2 u1 = *(const uint2*)(h + (size_t)s1 * HD + 2 * i);
                uint2 u2 = *(const uint2*)(h + (size_t)s2 * HD + 2 * i);
                uint2 u3 = *(const uint2*)(h + (size_t)s3 * HD + 2 * i);
                FMA8(u0, w0); FMA8(u1, w1); FMA8(u2, w2); FMA8(u3, w3);
            }
            for (; j < deg; j += 4) {
                float w0 = __shfl(w, j);
                int   s0 = __shfl(s, j);
                uint2 u0 = *(const uint2*)(h + (size_t)s0 * HD + 2 * i);
                FMA8(u0, w0);
            }
            a0 += __shfl_xor(a0, 16); a1 += __shfl_xor(a1, 16);
            a2 += __shfl_xor(a2, 16); a3 += __shfl_xor(a3, 16);
            a4 += __shfl_xor(a4, 16); a5 += __shfl_xor(a5, 16);
            a6 += __shfl_xor(a6, 16); a7 += __shfl_xor(a7, 16);
            a0 += __shfl_xor(a0, 32); a1 += __shfl_xor(a1, 32);
            a2 += __shfl_xor(a2, 32); a3 += __shfl_xor(a3, 32);
            a4 += __shfl_xor(a4, 32); a5 += __shfl_xor(a5, 32);
            a6 += __shfl_xor(a6, 32); a7 += __shfl_xor(a7, 32);
            if (q == 0) {
                float r0 = fmaxf(a0 + bias[8*i],   0.f), r1 = fmaxf(a1 + bias[8*i+1], 0.f);
                float r2 = fmaxf(a2 + bias[8*i+2], 0.f), r3 = fmaxf(a3 + bias[8*i+3], 0.f);
                float r4 = fmaxf(a4 + bias[8*i+4], 0.f), r5 = fmaxf(a5 + bias[8*i+5], 0.f);
                float r6 = fmaxf(a6 + bias[8*i+6], 0.f), r7 = fmaxf(a7 + bias[8*i+7], 0.f);
                *(uint4*)(xout + (size_t)wid * XD + 4 * i) =
                    make_uint4(packbf(r0, r1), packbf(r2, r3), packbf(r4, r5), packbf(r6, r7));
            }
        } else {
            // F==64: lane i owns feats 4i..4i+3 (one dword of fp8)
            float a0=0,a1=0,a2=0,a3=0;
            auto FMA4 = [&](uint32_t u, float wj) {
                v2f p0 = __builtin_amdgcn_cvt_pk_f32_fp8(u, false);
                v2f p1 = __builtin_amdgcn_cvt_pk_f32_fp8(u, true);
                a0 += wj * p0[0]; a1 += wj * p0[1];
                a2 += wj * p1[0]; a3 += wj * p1[1];
            };
            if (q == 0) FMA4(h[(size_t)wid * HD + i], wself);
            int j = q;
            for (; j + 12 < deg; j += 16) {
                float w0 = __shfl(w, j),     w1 = __shfl(w, j + 4);
                float w2 = __shfl(w, j + 8), w3 = __shfl(w, j + 12);
                int   s0 = __shfl(s, j),     s1 = __shfl(s, j + 4);
                int   s2 = __shfl(s, j + 8), s3 = __shfl(s, j + 12);
                uint32_t u0 = h[(size_t)s0 * HD + i];
                uint32_t u1 = h[(size_t)s1 * HD + i];
                uint32_t u2 = h[(size_t)s2 * HD + i];
                uint32_t u3 = h[(size_t)s3 * HD + i];
                FMA4(u0, w0); FMA4(u1, w1); FMA4(u2, w2); FMA4(u3, w3);
            }
            for (; j < deg; j += 4) {
                float w0 = __shfl(w, j);
                int   s0 = __shfl(s, j);
                FMA4(h[(size_t)s0 * HD + i], w0);
            }
            a0 += __shfl_xor(a0, 16); a1 += __shfl_xor(a1, 16);
            a2 += __shfl_xor(a2, 16); a3 += __shfl_xor(a3, 16);
            a0 += __shfl_xor(a0, 32); a1 += __shfl_xor(a1, 32);
            a2 += __shfl_xor(a2, 32); a3 += __shfl_xor(a3, 32);
            if (q == 0) {
                float r0 = fmaxf(a0 + bias[4*i],   0.f), r1 = fmaxf(a1 + bias[4*i+1], 0.f);
                float r2 = fmaxf(a2 + bias[4*i+2], 0.f), r3 = fmaxf(a3 + bias[4*i+3], 0.f);
                *(uint2*)(xout + (size_t)wid * XD + 2 * i) = make_uint2(packbf(r0, r1), packbf(r2, r3));
            }
        }
        return;
    }

    // ---- generic path (deg > 64), software fp8 decode ----
    float m = eself;
    for (int p = beg + lane; p < end; p += 64)
        m = fmaxf(m, lrelu(ssrc[csr_src[p]] + sd));
    #pragma unroll
    for (int o = 32; o; o >>= 1) m = fmaxf(m, __shfl_xor(m, o));
    float dsum = (lane == 0) ? __expf(eself - m) : 0.f;
    for (int p = beg + lane; p < end; p += 64)
        dsum += __expf(lrelu(ssrc[csr_src[p]] + sd) - m);
    #pragma unroll
    for (int o = 32; o; o >>= 1) dsum += __shfl_xor(dsum, o);
    float inv = 1.f / dsum;
    float wself = __expf(eself - m) * inv;

    if constexpr (F == 128) {
        // lane owns feats 2*lane, 2*lane+1
        uint32_t d0 = h[(size_t)wid * HD + (lane >> 1)];
        uint32_t hw = (d0 >> ((lane & 1) * 16)) & 0xffffu;
        float acc0 = wself * fp8sw(hw & 0xff), acc1 = wself * fp8sw(hw >> 8);
        for (int p = beg; p < end; ++p) {
            int s0 = csr_src[p];
            uint32_t dd = h[(size_t)s0 * HD + (lane >> 1)];
            uint32_t hh = (dd >> ((lane & 1) * 16)) & 0xffffu;
            float w0 = __expf(lrelu(ssrc[s0] + sd) - m) * inv;
            acc0 += w0 * fp8sw(hh & 0xff);
            acc1 += w0 * fp8sw(hh >> 8);
        }
        float r0 = fmaxf(acc0 + bias[2 * lane], 0.f);
        float r1 = fmaxf(acc1 + bias[2 * lane + 1], 0.f);
        xout[(size_t)wid * XD + lane] = packbf(r0, r1);
    } else {
        // lane owns feat lane
        auto getf = [&](int row) {
            uint32_t dd = h[(size_t)row * HD + (lane >> 2)];
            return fp8sw((dd >> ((lane & 3) * 8)) & 0xff);
        };
        float acc = wself * getf(wid);
        for (int p = beg; p < end; ++p) {
            int s0 = csr_src[p];
            float w0 = __expf(lrelu(ssrc[s0] + sd) - m) * inv;
            acc += w0 * getf(s0);
        }
        float r = fmaxf(acc + bias[lane], 0.f);
        float rn = __shfl_xor(r, 1);
        if (!(lane & 1))
            xout[(size_t)wid * XD + (lane >> 1)] = packbf(r, rn);
    }
}

// ---------------- mean pool (sorted batch), both sides ----------------
__global__ __launch_bounds__(256) void pool2(const uint32_t* __restrict__ xb,
                                             const int* __restrict__ bat0,
                                             const int* __restrict__ bat1,
                                             float* __restrict__ pooled_b, int n) {
    int side = blockIdx.y;
    const uint32_t* x = xb + (size_t)side * HS;
    const int* batch = side ? bat1 : bat0;
    float* pooled = pooled_b + (size_t)side * Gn * 64;
    int g = blockIdx.x;
    int tid = threadIdx.x;
    __shared__ int s_lo, s_hi;
    if (tid == 0) {
        int lo = 0, hi = n;
        while (lo < hi) { int mid = (lo + hi) >> 1; if (batch[mid] < g) lo = mid + 1; else hi = mid; }
        s_lo = lo;
        int lo2 = lo, hi2 = n;
        while (lo2 < hi2) { int mid = (lo2 + hi2) >> 1; if (batch[mid] < g + 1) lo2 = mid + 1; else hi2 = mid; }
        s_hi = lo2;
    }
    __syncthreads();
    int lo = s_lo, hi = s_hi;
    int grp = tid >> 5, col = tid & 31;
    float a0 = 0.f, a1 = 0.f;
    for (int i = lo + grp; i < hi; i += 8) {
        uint32_t v = x[(size_t)i * 32 + col];
        a0 += bflo(v);
        a1 += bfhi(v);
    }
    __shared__ float red0[8][32], red1[8][32];
    red0[grp][col] = a0;
    red1[grp][col] = a1;
    __syncthreads();
    if (tid < 32) {
        float s0 = 0.f, s1 = 0.f;
        #pragma unroll
        for (int r = 0; r < 8; r++) { s0 += red0[r][tid]; s1 += red1[r][tid]; }
        float c = fmaxf((float)(hi - lo), 1.f);
        pooled[g * 64 + 2 * tid]     = s0 / c;
        pooled[g * 64 + 2 * tid + 1] = s1 / c;
    }
}

// ---------------- head ----------------
__global__ __launch_bounds__(256) void head_kernel(const float* __restrict__ xs,
                                                   const float* __restrict__ xt,
                                                   const float* __restrict__ Wlin,
                                                   const float* __restrict__ blin,
                                                   float* __restrict__ out) {
    int g = blockIdx.y;
    int c = blockIdx.x * 256 + threadIdx.x;
    __shared__ float z[64];
    if (threadIdx.x < 64) z[threadIdx.x] = xs[g * 64 + threadIdx.x] + xt[g * 64 + threadIdx.x];
    __syncthreads();
    float a0 = 0.f, a1 = 0.f, a2 = 0.f, a3 = 0.f;
    #pragma unroll
    for (int k = 0; k < 64; k += 4) {
        a0 += z[k]     * Wlin[(size_t)(k)     * Lout + c];
        a1 += z[k + 1] * Wlin[(size_t)(k + 1) * Lout + c];
        a2 += z[k + 2] * Wlin[(size_t)(k + 2) * Lout + c];
        a3 += z[k + 3] * Wlin[(size_t)(k + 3) * Lout + c];
    }
    float acc = (a0 + a1) + (a2 + a3) + blin[c];
    out[(size_t)g * Lout + c] = 1.f / (1.f + expf(-acc));
}

extern "C" void kernel_launch(void* const* d_in, const int* in_sizes, int n_in,
                              void* d_out, int out_size, void* d_ws, size_t ws_size,
                              hipStream_t stream) {
    size_t off = 0;
    auto alloc = [&](size_t bytes) -> void* {
        void* p = (char*)d_ws + off;
        off += (bytes + 255) & ~(size_t)255;
        return p;
    };
    uint32_t* hbuf    = (uint32_t*)alloc(2 * (size_t)Nn * 32 * 4);   // fp8 rows (max F=128 -> 32 dwords)
    uint32_t* xbuf    = (uint32_t*)alloc(2 * HS * 4);                // bf16 rows
    float* ssrc       = (float*)alloc(2 * (size_t)Nn * 4);
    float* sdst       = (float*)alloc(2 * (size_t)Nn * 4);
    int*   row_ptr    = (int*)alloc(2 * (size_t)(Nn + 1) * 4);
    int*   csr        = (int*)alloc(2 * (size_t)Ecnt * 4);
    uint32_t* bkt_edges = (uint32_t*)alloc(2 * (size_t)Ecnt * 4);
    int*   bkt_cnt    = (int*)alloc(2 * (size_t)(NBKT + 1) * 4);
    int*   bkt_ptr    = (int*)alloc(2 * (size_t)(NBKT + 1) * 4);
    int*   bkt_cur    = (int*)alloc(2 * (size_t)(NBKT + 1) * 4);
    float* pooled     = (float*)alloc(2 * (size_t)Gn * 64 * 4);

    const int NW = (Nn * 64 + 255) / 256;
    const int GB = (Nn + 63) / 64;

    const float* x_s = (const float*)d_in[0];
    const float* x_t = (const float*)d_in[1];
    const int* ei_s  = (const int*)d_in[2];
    const int* ei_t  = (const int*)d_in[3];
    const int* bat_s = (const int*)d_in[4];
    const int* bat_t = (const int*)d_in[5];
    const float *Ws1 = (const float*)d_in[6],  *as1s = (const float*)d_in[7],
                *as1d = (const float*)d_in[8],  *bs1 = (const float*)d_in[9];
    const float *Ws2 = (const float*)d_in[10], *as2s = (const float*)d_in[11],
                *as2d = (const float*)d_in[12], *bs2 = (const float*)d_in[13];
    const float *Wt1 = (const float*)d_in[14], *at1s = (const float*)d_in[15],
                *at1d = (const float*)d_in[16], *bt1 = (const float*)d_in[17];
    const float *Wt2 = (const float*)d_in[18], *at2s = (const float*)d_in[19],
                *at2d = (const float*)d_in[20], *bt2 = (const float*)d_in[21];
    const float *Wlin = (const float*)d_in[22], *blin = (const float*)d_in[23];

    // ---- memset counters, then layer-1 GEMM (fp8 C) with fused bucket-count ----
    hipMemsetAsync(bkt_cnt, 0, 2 * (size_t)(NBKT + 1) * 4, stream);
    mfma_gemm2<2, 4, 128, false, true><<<dim3(GB + EBC, 2), 256, 0, stream>>>(
        x_s, x_t, Ws1, Wt1, hbuf, (size_t)Nn * 32, as1s, at1s, as1d, at1d, ssrc, sdst, Nn, Din,
        ei_s, ei_t, bkt_cnt);
    // ---- rest of CSR build ----
    bkt_scan2<<<2, 512, 0, stream>>>(bkt_cnt, bkt_ptr, bkt_cur, row_ptr);
    bkt_scatter2<<<dim3(EBC, 2), 256, 0, stream>>>(ei_s, ei_t, bkt_cur, bkt_edges, Ecnt);
    csr_finalize2<<<dim3(NBKT, 2), 256, 0, stream>>>(bkt_edges, bkt_ptr, row_ptr, csr, Nn);
    // ---- attention layer 1 (fp8 gather) ----
    attn_agg2<128><<<dim3(NW, 2), 256, 0, stream>>>(hbuf, ssrc, sdst, row_ptr, csr, bs1, bt1, xbuf, Nn);
    // ---- layer 2 GEMM (bf16 A, fp8 C) ----
    mfma_gemm2<2, 2, 64, true, false><<<dim3(GB, 2), 256, 0, stream>>>(
        xbuf, xbuf + HS, Ws2, Wt2, hbuf, (size_t)Nn * 16, as2s, at2s, as2d, at2d, ssrc, sdst, Nn, 128,
        nullptr, nullptr, nullptr);
    attn_agg2<64><<<dim3(NW, 2), 256, 0, stream>>>(hbuf, ssrc, sdst, row_ptr, csr, bs2, bt2, xbuf, Nn);
    // ---- pool + head ----
    pool2<<<dim3(Gn, 2), 256, 0, stream>>>(xbuf, bat_s, bat_t, pooled, Nn);
    head_kernel<<<dim3(Lout / 256, Gn), 256, 0, stream>>>(pooled, pooled + (size_t)Gn * 64,
                                                          Wlin, blin, (float*)d_out);
}

// Round 13
// 207.626 us; speedup vs baseline: 7.5833x; 1.1527x over previous
//
#include <hip/hip_runtime.h>
#include <hip/hip_bf16.h>
#include <math.h>

constexpr int Nn   = 50000;
constexpr int Ecnt = 800000;
constexpr int Gn   = 128;
constexpr int Din  = 256;
constexpr int Lout = 1024;

constexpr int BKT_SH = 7;
constexpr int NBKT   = (Nn + 127) >> BKT_SH;    // 391
constexpr int CHUNK  = 4096;
constexpr int EBC    = (Ecnt + CHUNK - 1) / CHUNK;  // 196
constexpr size_t HS  = (size_t)Nn * 64;         // xbuf per-side stride (dwords, bf16 rows)

typedef __attribute__((ext_vector_type(8))) short short8;
typedef __attribute__((ext_vector_type(4))) float f32x4;
typedef __attribute__((ext_vector_type(2))) float v2f;

__device__ __forceinline__ float lrelu(float x) { return x >= 0.f ? x : 0.2f * x; }

__device__ __forceinline__ float bflo(uint32_t v) { return __uint_as_float(v << 16); }
__device__ __forceinline__ float bfhi(uint32_t v) { return __uint_as_float(v & 0xffff0000u); }
__device__ __forceinline__ uint32_t f2bf(float f) {
    uint32_t x = __float_as_uint(f);
    return (x + 0x7fffu + ((x >> 16) & 1u)) >> 16;
}
__device__ __forceinline__ uint32_t packbf(float lo, float hi) {
    return f2bf(lo) | (f2bf(hi) << 16);
}

// ================= CSR build (side = blockIdx.y) =================
__global__ __launch_bounds__(512) void bkt_scan2(const int* __restrict__ bkt_cnt_b,
                                                 int* __restrict__ bkt_ptr_b,
                                                 int* __restrict__ bkt_cur_b,
                                                 int* __restrict__ row_ptr_b) {
    int side = blockIdx.x;
    const int* bkt_cnt = bkt_cnt_b + (size_t)side * (NBKT + 1);
    int* bkt_ptr = bkt_ptr_b + (size_t)side * (NBKT + 1);
    int* bkt_cur = bkt_cur_b + (size_t)side * (NBKT + 1);
    int* row_ptr = row_ptr_b + (size_t)side * (Nn + 1);
    __shared__ int buf[512];
    int t = threadIdx.x;
    int v = (t < NBKT) ? bkt_cnt[t] : 0;
    buf[t] = v;
    __syncthreads();
    for (int off = 1; off < 512; off <<= 1) {
        int x = (t >= off) ? buf[t - off] : 0;
        __syncthreads();
        buf[t] += x;
        __syncthreads();
    }
    if (t < NBKT) {
        int excl = buf[t] - v;
        bkt_ptr[t] = excl;
        bkt_cur[t] = excl;
    }
    if (t == 511) {
        bkt_ptr[NBKT] = buf[511];
        row_ptr[Nn]   = buf[511];
    }
}

__global__ __launch_bounds__(256) void bkt_scatter2(const int* __restrict__ e0,
                                                    const int* __restrict__ e1,
                                                    int* __restrict__ bkt_cur_b,
                                                    uint32_t* __restrict__ bkt_edges_b, int E) {
    int side = blockIdx.y;
    const int* src = side ? e1 : e0;
    const int* dst = src + E;
    int* bkt_cur = bkt_cur_b + (size_t)side * (NBKT + 1);
    uint32_t* bkt_edges = bkt_edges_b + (size_t)side * Ecnt;
    __shared__ int h[NBKT];
    __shared__ int cur[NBKT];
    for (int i = threadIdx.x; i < NBKT; i += 256) h[i] = 0;
    __syncthreads();
    int base = blockIdx.x * CHUNK;
    int end = min(base + CHUNK, E);
    for (int i = base + threadIdx.x; i < end; i += 256)
        atomicAdd(&h[dst[i] >> BKT_SH], 1);
    __syncthreads();
    for (int i = threadIdx.x; i < NBKT; i += 256) {
        int c = h[i];
        h[i] = c ? atomicAdd(&bkt_cur[i], c) : 0;
        cur[i] = 0;
    }
    __syncthreads();
    for (int i = base + threadIdx.x; i < end; i += 256) {
        int d = dst[i], b = d >> BKT_SH;
        int pos = h[b] + atomicAdd(&cur[b], 1);
        bkt_edges[pos] = (uint32_t)src[i] | ((uint32_t)(d & 127) << 16);
    }
}

__global__ __launch_bounds__(256) void csr_finalize2(const uint32_t* __restrict__ bkt_edges_b,
                                                     const int* __restrict__ bkt_ptr_b,
                                                     int* __restrict__ row_ptr_b,
                                                     int* __restrict__ csr_b, int n) {
    int side = blockIdx.y;
    const uint32_t* bkt_edges = bkt_edges_b + (size_t)side * Ecnt;
    const int* bkt_ptr = bkt_ptr_b + (size_t)side * (NBKT + 1);
    int* row_ptr = row_ptr_b + (size_t)side * (Nn + 1);
    int* csr = csr_b + (size_t)side * Ecnt;
    int b = blockIdx.x;
    int base = bkt_ptr[b];
    int cnt  = bkt_ptr[b + 1] - base;
    __shared__ int hist[128], curs[128], sc[128];
    int t = threadIdx.x;
    if (t < 128) hist[t] = 0;
    __syncthreads();
    for (int i = t; i < cnt; i += 256)
        atomicAdd(&hist[(bkt_edges[base + i] >> 16) & 127], 1);
    __syncthreads();
    if (t < 128) sc[t] = hist[t];
    __syncthreads();
    for (int off = 1; off < 128; off <<= 1) {
        int x = (t >= off && t < 128) ? sc[t - off] : 0;
        __syncthreads();
        if (t < 128) sc[t] += x;
        __syncthreads();
    }
    if (t < 128) {
        int excl = sc[t] - hist[t];
        int node = (b << BKT_SH) + t;
        if (node < n) row_ptr[node] = base + excl;
        curs[t] = excl;
    }
    __syncthreads();
    for (int i = t; i < cnt; i += 256) {
        uint32_t e = bkt_edges[base + i];
        int pos = atomicAdd(&curs[(e >> 16) & 127], 1);
        csr[base + pos] = (int)(e & 0xFFFFu);
    }
}

// ---------------- MFMA bf16 GEMM -> fp8 C + fused scores (+ optional fused bucket-count) ----------------
template<int MF, int NF, int BN, bool BF16A, bool FUSE_COUNT>
__global__ __launch_bounds__(256) void mfma_gemm2(
        const void* __restrict__ A0, const void* __restrict__ A1,
        const float* __restrict__ B0, const float* __restrict__ B1,
        uint32_t* __restrict__ Cb, size_t cstride,
        const float* __restrict__ as0, const float* __restrict__ as1,
        const float* __restrict__ ad0, const float* __restrict__ ad1,
        float* __restrict__ ssrc_b, float* __restrict__ sdst_b,
        int M, int K,
        const int* __restrict__ e0, const int* __restrict__ e1,
        int* __restrict__ bkt_cnt_b) {
    __shared__ uint32_t Al[64][36];
    __shared__ uint32_t Bl[BN][36];
    __shared__ float sS[64][2], sD[64][2];
    int side = blockIdx.y;

    if constexpr (FUSE_COUNT) {
        int gb = (M + 63) >> 6;
        if ((int)blockIdx.x >= gb) {
            int chunk = blockIdx.x - gb;
            const int* dst = (side ? e1 : e0) + Ecnt;
            int* bkt_cnt = bkt_cnt_b + (size_t)side * (NBKT + 1);
            int* hh = (int*)&Al[0][0];
            for (int i = threadIdx.x; i < NBKT; i += 256) hh[i] = 0;
            __syncthreads();
            int base = chunk * CHUNK;
            int end = min(base + CHUNK, Ecnt);
            for (int i = base + threadIdx.x; i < end; i += 256)
                atomicAdd(&hh[dst[i] >> BKT_SH], 1);
            __syncthreads();
            for (int i = threadIdx.x; i < NBKT; i += 256) {
                int c = hh[i];
                if (c) atomicAdd(&bkt_cnt[i], c);
            }
            return;
        }
    }

    const void* Av = side ? A1 : A0;
    const float* B = side ? B1 : B0;
    const float* Asrc = side ? as1 : as0;
    const float* Adst = side ? ad1 : ad0;
    uint32_t* C = Cb + (size_t)side * cstride;
    float* ssrc = ssrc_b + (size_t)side * Nn;
    float* sdst = sdst_b + (size_t)side * Nn;

    int tid  = threadIdx.x;
    int lane = tid & 63;
    int wid  = tid >> 6;
    int wr = wid >> 1, wc = wid & 1;
    int bm = blockIdx.x * 64;

    int arow = tid >> 2, aq = tid & 3;
    bool avalid = (bm + arow) < M;
    constexpr int NPI = BN * 16 / 256;

    float    fA[16];
    uint32_t uA[8];
    float    fB[NPI][4];

    auto LOADA = [&](int k0) {
        if constexpr (BF16A) {
            const uint32_t* A = (const uint32_t*)Av;
            if (avalid) {
                const uint32_t* p = A + (size_t)(bm + arow) * (K >> 1) + (k0 >> 1) + aq * 8;
                uint4 u0 = *(const uint4*)p;
                uint4 u1 = *(const uint4*)(p + 4);
                uA[0] = u0.x; uA[1] = u0.y; uA[2] = u0.z; uA[3] = u0.w;
                uA[4] = u1.x; uA[5] = u1.y; uA[6] = u1.z; uA[7] = u1.w;
            } else {
                #pragma unroll
                for (int i = 0; i < 8; i++) uA[i] = 0u;
            }
        } else {
            const float* A = (const float*)Av;
            if (avalid) {
                const float* p = A + (size_t)(bm + arow) * K + k0 + aq * 16;
                #pragma unroll
                for (int i = 0; i < 4; i++) {
                    float4 f = *(const float4*)(p + i * 4);
                    fA[4 * i] = f.x; fA[4 * i + 1] = f.y; fA[4 * i + 2] = f.z; fA[4 * i + 3] = f.w;
                }
            } else {
                #pragma unroll
                for (int i = 0; i < 16; i++) fA[i] = 0.f;
            }
        }
    };
    auto LOADB = [&](int k0) {
        #pragma unroll
        for (int it = 0; it < NPI; it++) {
            int pi = tid + it * 256;
            int n = pi & (BN - 1);
            int kp = pi / BN;
            const float* p = B + (size_t)(k0 + 4 * kp) * BN + n;
            fB[it][0] = p[0];
            fB[it][1] = p[BN];
            fB[it][2] = p[2 * BN];
            fB[it][3] = p[3 * BN];
        }
    };
    auto WRITE = [&]() {
        if constexpr (BF16A) {
            uint4* dst = (uint4*)&Al[arow][aq * 8];
            dst[0] = make_uint4(uA[0], uA[1], uA[2], uA[3]);
            dst[1] = make_uint4(uA[4], uA[5], uA[6], uA[7]);
        } else {
            uint32_t d[8];
            #pragma unroll
            for (int i = 0; i < 8; i++) d[i] = packbf(fA[2 * i], fA[2 * i + 1]);
            uint4* dst = (uint4*)&Al[arow][aq * 8];
            dst[0] = make_uint4(d[0], d[1], d[2], d[3]);
            dst[1] = make_uint4(d[4], d[5], d[6], d[7]);
        }
        #pragma unroll
        for (int it = 0; it < NPI; it++) {
            int pi = tid + it * 256;
            int n = pi & (BN - 1);
            int kp = pi / BN;
            *(uint2*)&Bl[n][2 * kp] = make_uint2(packbf(fB[it][0], fB[it][1]),
                                                 packbf(fB[it][2], fB[it][3]));
        }
    };

    f32x4 acc[MF][NF];
    #pragma unroll
    for (int i = 0; i < MF; i++)
        #pragma unroll
        for (int j = 0; j < NF; j++) acc[i][j] = (f32x4){0.f, 0.f, 0.f, 0.f};

    LOADA(0); LOADB(0);
    const int T = K / 64;
    for (int t = 0; t < T; t++) {
        WRITE();
        __syncthreads();
        if (t + 1 < T) { LOADA((t + 1) * 64); LOADB((t + 1) * 64); }
        int lr = lane & 15, lk = lane >> 4;
        #pragma unroll
        for (int ks = 0; ks < 2; ks++) {
            short8 af[MF], bf[NF];
            #pragma unroll
            for (int mf = 0; mf < MF; mf++)
                af[mf] = *(const short8*)&Al[wr * (MF * 16) + mf * 16 + lr][ks * 16 + lk * 4];
            #pragma unroll
            for (int nf = 0; nf < NF; nf++)
                bf[nf] = *(const short8*)&Bl[wc * (NF * 16) + nf * 16 + lr][ks * 16 + lk * 4];
            #pragma unroll
            for (int mf = 0; mf < MF; mf++)
                #pragma unroll
                for (int nf = 0; nf < NF; nf++)
                    acc[mf][nf] = __builtin_amdgcn_mfma_f32_16x16x32_bf16(af[mf], bf[nf], acc[mf][nf], 0, 0, 0);
        }
        __syncthreads();
    }

    int lr = lane & 15, lg = lane >> 4;
    // fused scores (from exact fp32 acc)
    {
        float a_s[NF], a_d[NF];
        #pragma unroll
        for (int nf = 0; nf < NF; nf++) {
            int col = wc * (NF * 16) + nf * 16 + lr;
            a_s[nf] = Asrc[col];
            a_d[nf] = Adst[col];
        }
        #pragma unroll
        for (int mf = 0; mf < MF; mf++) {
            #pragma unroll
            for (int j = 0; j < 4; j++) {
                float ps = 0.f, pd = 0.f;
                #pragma unroll
                for (int nf = 0; nf < NF; nf++) {
                    float v = acc[mf][nf][j];
                    ps += v * a_s[nf];
                    pd += v * a_d[nf];
                }
                #pragma unroll
                for (int o = 1; o < 16; o <<= 1) {
                    ps += __shfl_xor(ps, o);
                    pd += __shfl_xor(pd, o);
                }
                if (lr == 0) {
                    int rl = wr * (MF * 16) + mf * 16 + lg * 4 + j;
                    sS[rl][wc] = ps;
                    sD[rl][wc] = pd;
                }
            }
        }
    }
    // C write as fp8 e4m3 (HW cvt): 4 cols -> 1 dword
    #pragma unroll
    for (int mf = 0; mf < MF; mf++) {
        #pragma unroll
        for (int nf = 0; nf < NF; nf++) {
            int col = wc * (NF * 16) + nf * 16 + lr;
            #pragma unroll
            for (int j = 0; j < 4; j++) {
                int row = bm + wr * (MF * 16) + mf * 16 + lg * 4 + j;
                float v = acc[mf][nf][j];
                float w1 = __shfl_xor(v, 1);
                uint32_t p01 = (uint32_t)__builtin_amdgcn_cvt_pk_fp8_f32(v, w1, 0, false);
                uint32_t p23 = __shfl_xor(p01, 2);
                if (((lane & 3) == 0) && row < M)
                    C[(size_t)row * (BN >> 2) + (col >> 2)] = (p01 & 0xffffu) | (p23 << 16);
            }
        }
    }
    __syncthreads();
    if (tid < 64) {
        int row = bm + tid;
        if (row < M) {
            ssrc[row] = sS[tid][0] + sS[tid][1];
            sdst[row] = sD[tid][0] + sD[tid][1];
        }
    }
}

// ---------------- attention: 2 nodes per wave (half-wave each), fp8 gather, pk_fma ----------------
template<int F>
__global__ __launch_bounds__(256) void attn_agg2(const uint32_t* __restrict__ hb,
        const float* __restrict__ ssrc_b, const float* __restrict__ sdst_b,
        const int* __restrict__ row_ptr_b, const int* __restrict__ csr_b,
        const float* __restrict__ bias0, const float* __restrict__ bias1,
        uint32_t* __restrict__ xout_b, int n) {
    constexpr size_t HSTR = (size_t)Nn * (F / 4);
    constexpr int HD = F / 4;                       // fp8 dwords per row
    constexpr int XD = F / 2;                       // bf16 dwords per out row
    int side = blockIdx.y;
    const uint32_t* h = hb + (size_t)side * HSTR;
    const float* ssrc = ssrc_b + (size_t)side * Nn;
    const float* sdst = sdst_b + (size_t)side * Nn;
    const int* row_ptr = row_ptr_b + (size_t)side * (Nn + 1);
    const int* csr_src = csr_b + (size_t)side * Ecnt;
    const float* bias = side ? bias1 : bias0;
    uint32_t* xout = xout_b + (size_t)side * HS;

    int wave = (blockIdx.x * blockDim.x + threadIdx.x) >> 6;
    int lane = threadIdx.x & 63;
    int half = lane >> 5;               // node select within wave
    int lane5 = lane & 31;
    int wid = wave * 2 + half;
    if (wid >= n) return;
    int beg = row_ptr[wid], end = row_ptr[wid + 1];
    int deg = end - beg;
    float sd = sdst[wid];
    float eself = lrelu(ssrc[wid] + sd);
    int base32 = lane & 32;

    // per-lane accumulators: 8 feats as 4 x v2f
    v2f a0 = {0.f, 0.f}, a1 = {0.f, 0.f}, a2 = {0.f, 0.f}, a3 = {0.f, 0.f};
    auto FMA8 = [&](uint2 u, float wj) {
        v2f p0 = __builtin_amdgcn_cvt_pk_f32_fp8(u.x, false);
        v2f p1 = __builtin_amdgcn_cvt_pk_f32_fp8(u.x, true);
        v2f p2 = __builtin_amdgcn_cvt_pk_f32_fp8(u.y, false);
        v2f p3 = __builtin_amdgcn_cvt_pk_f32_fp8(u.y, true);
        v2f wv = {wj, wj};
        a0 += p0 * wv; a1 += p1 * wv; a2 += p2 * wv; a3 += p3 * wv;
    };

    if (deg <= 32) {
        // lane-parallel softmax within half-wave
        int p = beg + lane5;
        bool act = lane5 < deg;
        int s = act ? csr_src[p] : 0;
        float e = act ? lrelu(ssrc[s] + sd) : -1e30f;
        float m = fmaxf(eself, e);
        #pragma unroll
        for (int o = 16; o; o >>= 1) m = fmaxf(m, __shfl_xor(m, o));
        float ex = act ? __expf(e - m) : 0.f;
        float dsum = ex;
        #pragma unroll
        for (int o = 16; o; o >>= 1) dsum += __shfl_xor(dsum, o);
        float exself = __expf(eself - m);
        dsum += exself;
        float inv = 1.f / dsum;
        float w = ex * inv;
        float wself = exself * inv;

        if constexpr (F == 128) {
            // 16 lanes per edge slot, 2 slots per half-wave
            int slot = (lane >> 4) & 1, i = lane & 15;
            size_t foff = 2 * i;
            if (slot == 0) FMA8(*(const uint2*)(h + (size_t)wid * HD + foff), wself);
            int j = slot;
            for (; j + 6 < deg; j += 8) {
                float w0 = __shfl(w, base32 | j),       w1 = __shfl(w, base32 | (j + 2));
                float w2 = __shfl(w, base32 | (j + 4)), w3 = __shfl(w, base32 | (j + 6));
                int   s0 = __shfl(s, base32 | j),       s1 = __shfl(s, base32 | (j + 2));
                int   s2 = __shfl(s, base32 | (j + 4)), s3 = __shfl(s, base32 | (j + 6));
                uint2 u0 = *(const uint2*)(h + (size_t)s0 * HD + foff);
                uint2 u1 = *(const uint2*)(h + (size_t)s1 * HD + foff);
                uint2 u2 = *(const uint2*)(h + (size_t)s2 * HD + foff);
                uint2 u3 = *(const uint2*)(h + (size_t)s3 * HD + foff);
                FMA8(u0, w0); FMA8(u1, w1); FMA8(u2, w2); FMA8(u3, w3);
            }
            for (; j < deg; j += 2) {
                float w0 = __shfl(w, base32 | j);
                int   s0 = __shfl(s, base32 | j);
                FMA8(*(const uint2*)(h + (size_t)s0 * HD + foff), w0);
            }
            a0[0] += __shfl_xor(a0[0], 16); a0[1] += __shfl_xor(a0[1], 16);
            a1[0] += __shfl_xor(a1[0], 16); a1[1] += __shfl_xor(a1[1], 16);
            a2[0] += __shfl_xor(a2[0], 16); a2[1] += __shfl_xor(a2[1], 16);
            a3[0] += __shfl_xor(a3[0], 16); a3[1] += __shfl_xor(a3[1], 16);
            if (!(lane & 16)) {
                float r0 = fmaxf(a0[0] + bias[8*i],   0.f), r1 = fmaxf(a0[1] + bias[8*i+1], 0.f);
                float r2 = fmaxf(a1[0] + bias[8*i+2], 0.f), r3 = fmaxf(a1[1] + bias[8*i+3], 0.f);
                float r4 = fmaxf(a2[0] + bias[8*i+4], 0.f), r5 = fmaxf(a2[1] + bias[8*i+5], 0.f);
                float r6 = fmaxf(a3[0] + bias[8*i+6], 0.f), r7 = fmaxf(a3[1] + bias[8*i+7], 0.f);
                *(uint4*)(xout + (size_t)wid * XD + 4 * i) =
                    make_uint4(packbf(r0, r1), packbf(r2, r3), packbf(r4, r5), packbf(r6, r7));
            }
        } else {
            // F==64: 8 lanes per edge slot, 4 slots per half-wave
            int g = (lane >> 3) & 3, i = lane & 7;
            size_t foff = 2 * i;
            if (g == 0) FMA8(*(const uint2*)(h + (size_t)wid * HD + foff), wself);
            int j = g;
            for (; j + 12 < deg; j += 16) {
                float w0 = __shfl(w, base32 | j),       w1 = __shfl(w, base32 | (j + 4));
                float w2 = __shfl(w, base32 | (j + 8)), w3 = __shfl(w, base32 | (j + 12));
                int   s0 = __shfl(s, base32 | j),       s1 = __shfl(s, base32 | (j + 4));
                int   s2 = __shfl(s, base32 | (j + 8)), s3 = __shfl(s, base32 | (j + 12));
                uint2 u0 = *(const uint2*)(h + (size_t)s0 * HD + foff);
                uint2 u1 = *(const uint2*)(h + (size_t)s1 * HD + foff);
                uint2 u2 = *(const uint2*)(h + (size_t)s2 * HD + foff);
                uint2 u3 = *(const uint2*)(h + (size_t)s3 * HD + foff);
                FMA8(u0, w0); FMA8(u1, w1); FMA8(u2, w2); FMA8(u3, w3);
            }
            for (; j < deg; j += 4) {
                float w0 = __shfl(w, base32 | j);
                int   s0 = __shfl(s, base32 | j);
                FMA8(*(const uint2*)(h + (size_t)s0 * HD + foff), w0);
            }
            #pragma unroll
            for (int o = 8; o <= 16; o <<= 1) {
                a0[0] += __shfl_xor(a0[0], o); a0[1] += __shfl_xor(a0[1], o);
                a1[0] += __shfl_xor(a1[0], o); a1[1] += __shfl_xor(a1[1], o);
                a2[0] += __shfl_xor(a2[0], o); a2[1] += __shfl_xor(a2[1], o);
                a3[0] += __shfl_xor(a3[0], o); a3[1] += __shfl_xor(a3[1], o);
            }
            if (!(lane & 24)) {
                float r0 = fmaxf(a0[0] + bias[8*i],   0.f), r1 = fmaxf(a0[1] + bias[8*i+1], 0.f);
                float r2 = fmaxf(a1[0] + bias[8*i+2], 0.f), r3 = fmaxf(a1[1] + bias[8*i+3], 0.f);
                float r4 = fmaxf(a2[0] + bias[8*i+4], 0.f), r5 = fmaxf(a2[1] + bias[8*i+5], 0.f);
                float r6 = fmaxf(a3[0] + bias[8*i+6], 0.f), r7 = fmaxf(a3[1] + bias[8*i+7], 0.f);
                *(uint4*)(xout + (size_t)wid * XD + 4 * i) =
                    make_uint4(packbf(r0, r1), packbf(r2, r3), packbf(r4, r5), packbf(r6, r7));
            }
        }
        return;
    }

    // ---- generic path (deg > 32): half-wave, per-edge weight recomputed ----
    float m = eself;
    for (int p = beg + lane5; p < end; p += 32)
        m = fmaxf(m, lrelu(ssrc[csr_src[p]] + sd));
    #pragma unroll
    for (int o = 16; o; o >>= 1) m = fmaxf(m, __shfl_xor(m, o));
    float dsum = (lane5 == 0) ? __expf(eself - m) : 0.f;
    for (int p = beg + lane5; p < end; p += 32)
        dsum += __expf(lrelu(ssrc[csr_src[p]] + sd) - m);
    #pragma unroll
    for (int o = 16; o; o >>= 1) dsum += __shfl_xor(dsum, o);
    float inv = 1.f / dsum;
    float wself = __expf(eself - m) * inv;

    if constexpr (F == 128) {
        int slot = (lane >> 4) & 1, i = lane & 15;
        size_t foff = 2 * i;
        if (slot == 0) FMA8(*(const uint2*)(h + (size_t)wid * HD + foff), wself);
        for (int j = slot; j < deg; j += 2) {
            int sj = csr_src[beg + j];
            float wj = __expf(lrelu(ssrc[sj] + sd) - m) * inv;
            FMA8(*(const uint2*)(h + (size_t)sj * HD + foff), wj);
        }
        a0[0] += __shfl_xor(a0[0], 16); a0[1] += __shfl_xor(a0[1], 16);
        a1[0] += __shfl_xor(a1[0], 16); a1[1] += __shfl_xor(a1[1], 16);
        a2[0] += __shfl_xor(a2[0], 16); a2[1] += __shfl_xor(a2[1], 16);
        a3[0] += __shfl_xor(a3[0], 16); a3[1] += __shfl_xor(a3[1], 16);
        if (!(lane & 16)) {
            float r0 = fmaxf(a0[0] + bias[8*i],   0.f), r1 = fmaxf(a0[1] + bias[8*i+1], 0.f);
            float r2 = fmaxf(a1[0] + bias[8*i+2], 0.f), r3 = fmaxf(a1[1] + bias[8*i+3], 0.f);
            float r4 = fmaxf(a2[0] + bias[8*i+4], 0.f), r5 = fmaxf(a2[1] + bias[8*i+5], 0.f);
            float r6 = fmaxf(a3[0] + bias[8*i+6], 0.f), r7 = fmaxf(a3[1] + bias[8*i+7], 0.f);
            *(uint4*)(xout + (size_t)wid * XD + 4 * i) =
                make_uint4(packbf(r0, r1), packbf(r2, r3), packbf(r4, r5), packbf(r6, r7));
        }
    } else {
        int g = (lane >> 3) & 3, i = lane & 7;
        size_t foff = 2 * i;
        if (g == 0) FMA8(*(const uint2*)(h + (size_t)wid * HD + foff), wself);
        for (int j = g; j < deg; j += 4) {
            int sj = csr_src[beg + j];
            float wj = __expf(lrelu(ssrc[sj] + sd) - m) * inv;
            FMA8(*(const uint2*)(h + (size_t)sj * HD + foff), wj);
        }
        #pragma unroll
        for (int o = 8; o <= 16; o <<= 1) {
            a0[0] += __shfl_xor(a0[0], o); a0[1] += __shfl_xor(a0[1], o);
            a1[0] += __shfl_xor(a1[0], o); a1[1] += __shfl_xor(a1[1], o);
            a2[0] += __shfl_xor(a2[0], o); a2[1] += __shfl_xor(a2[1], o);
            a3[0] += __shfl_xor(a3[0], o); a3[1] += __shfl_xor(a3[1], o);
        }
        if (!(lane & 24)) {
            float r0 = fmaxf(a0[0] + bias[8*i],   0.f), r1 = fmaxf(a0[1] + bias[8*i+1], 0.f);
            float r2 = fmaxf(a1[0] + bias[8*i+2], 0.f), r3 = fmaxf(a1[1] + bias[8*i+3], 0.f);
            float r4 = fmaxf(a2[0] + bias[8*i+4], 0.f), r5 = fmaxf(a2[1] + bias[8*i+5], 0.f);
            float r6 = fmaxf(a3[0] + bias[8*i+6], 0.f), r7 = fmaxf(a3[1] + bias[8*i+7], 0.f);
            *(uint4*)(xout + (size_t)wid * XD + 4 * i) =
                make_uint4(packbf(r0, r1), packbf(r2, r3), packbf(r4, r5), packbf(r6, r7));
        }
    }
}

// ---------------- mean pool (sorted batch), both sides ----------------
__global__ __launch_bounds__(256) void pool2(const uint32_t* __restrict__ xb,
                                             const int* __restrict__ bat0,
                                             const int* __restrict__ bat1,
                                             float* __restrict__ pooled_b, int n) {
    int side = blockIdx.y;
    const uint32_t* x = xb + (size_t)side * HS;
    const int* batch = side ? bat1 : bat0;
    float* pooled = pooled_b + (size_t)side * Gn * 64;
    int g = blockIdx.x;
    int tid = threadIdx.x;
    __shared__ int s_lo, s_hi;
    if (tid == 0) {
        int lo = 0, hi = n;
        while (lo < hi) { int mid = (lo + hi) >> 1; if (batch[mid] < g) lo = mid + 1; else hi = mid; }
        s_lo = lo;
        int lo2 = lo, hi2 = n;
        while (lo2 < hi2) { int mid = (lo2 + hi2) >> 1; if (batch[mid] < g + 1) lo2 = mid + 1; else hi2 = mid; }
        s_hi = lo2;
    }
    __syncthreads();
    int lo = s_lo, hi = s_hi;
    int grp = tid >> 5, col = tid & 31;
    float a0 = 0.f, a1 = 0.f;
    for (int i = lo + grp; i < hi; i += 8) {
        uint32_t v = x[(size_t)i * 32 + col];
        a0 += bflo(v);
        a1 += bfhi(v);
    }
    __shared__ float red0[8][32], red1[8][32];
    red0[grp][col] = a0;
    red1[grp][col] = a1;
    __syncthreads();
    if (tid < 32) {
        float s0 = 0.f, s1 = 0.f;
        #pragma unroll
        for (int r = 0; r < 8; r++) { s0 += red0[r][tid]; s1 += red1[r][tid]; }
        float c = fmaxf((float)(hi - lo), 1.f);
        pooled[g * 64 + 2 * tid]     = s0 / c;
        pooled[g * 64 + 2 * tid + 1] = s1 / c;
    }
}

// ---------------- head ----------------
__global__ __launch_bounds__(256) void head_kernel(const float* __restrict__ xs,
                                                   const float* __restrict__ xt,
                                                   const float* __restrict__ Wlin,
                                                   const float* __restrict__ blin,
                                                   float* __restrict__ out) {
    int g = blockIdx.y;
    int c = blockIdx.x * 256 + threadIdx.x;
    __shared__ float z[64];
    if (threadIdx.x < 64) z[threadIdx.x] = xs[g * 64 + threadIdx.x] + xt[g * 64 + threadIdx.x];
    __syncthreads();
    float a0 = 0.f, a1 = 0.f, a2 = 0.f, a3 = 0.f;
    #pragma unroll
    for (int k = 0; k < 64; k += 4) {
        a0 += z[k]     * Wlin[(size_t)(k)     * Lout + c];
        a1 += z[k + 1] * Wlin[(size_t)(k + 1) * Lout + c];
        a2 += z[k + 2] * Wlin[(size_t)(k + 2) * Lout + c];
        a3 += z[k + 3] * Wlin[(size_t)(k + 3) * Lout + c];
    }
    float acc = (a0 + a1) + (a2 + a3) + blin[c];
    out[(size_t)g * Lout + c] = 1.f / (1.f + expf(-acc));
}

extern "C" void kernel_launch(void* const* d_in, const int* in_sizes, int n_in,
                              void* d_out, int out_size, void* d_ws, size_t ws_size,
                              hipStream_t stream) {
    size_t off = 0;
    auto alloc = [&](size_t bytes) -> void* {
        void* p = (char*)d_ws + off;
        off += (bytes + 255) & ~(size_t)255;
        return p;
    };
    uint32_t* hbuf    = (uint32_t*)alloc(2 * (size_t)Nn * 32 * 4);   // fp8 rows
    uint32_t* xbuf    = (uint32_t*)alloc(2 * HS * 4);                // bf16 rows
    float* ssrc       = (float*)alloc(2 * (size_t)Nn * 4);
    float* sdst       = (float*)alloc(2 * (size_t)Nn * 4);
    int*   row_ptr    = (int*)alloc(2 * (size_t)(Nn + 1) * 4);
    int*   csr        = (int*)alloc(2 * (size_t)Ecnt * 4);
    uint32_t* bkt_edges = (uint32_t*)alloc(2 * (size_t)Ecnt * 4);
    int*   bkt_cnt    = (int*)alloc(2 * (size_t)(NBKT + 1) * 4);
    int*   bkt_ptr    = (int*)alloc(2 * (size_t)(NBKT + 1) * 4);
    int*   bkt_cur    = (int*)alloc(2 * (size_t)(NBKT + 1) * 4);
    float* pooled     = (float*)alloc(2 * (size_t)Gn * 64 * 4);

    const int NW2 = (((Nn + 1) / 2) * 64 + 255) / 256;   // 2 nodes per wave
    const int GB  = (Nn + 63) / 64;

    const float* x_s = (const float*)d_in[0];
    const float* x_t = (const float*)d_in[1];
    const int* ei_s  = (const int*)d_in[2];
    const int* ei_t  = (const int*)d_in[3];
    const int* bat_s = (const int*)d_in[4];
    const int* bat_t = (const int*)d_in[5];
    const float *Ws1 = (const float*)d_in[6],  *as1s = (const float*)d_in[7],
                *as1d = (const float*)d_in[8],  *bs1 = (const float*)d_in[9];
    const float *Ws2 = (const float*)d_in[10], *as2s = (const float*)d_in[11],
                *as2d = (const float*)d_in[12], *bs2 = (const float*)d_in[13];
    const float *Wt1 = (const float*)d_in[14], *at1s = (const float*)d_in[15],
                *at1d = (const float*)d_in[16], *bt1 = (const float*)d_in[17];
    const float *Wt2 = (const float*)d_in[18], *at2s = (const float*)d_in[19],
                *at2d = (const float*)d_in[20], *bt2 = (const float*)d_in[21];
    const float *Wlin = (const float*)d_in[22], *blin = (const float*)d_in[23];

    // ---- memset counters, then layer-1 GEMM (fp8 C) with fused bucket-count ----
    hipMemsetAsync(bkt_cnt, 0, 2 * (size_t)(NBKT + 1) * 4, stream);
    mfma_gemm2<2, 4, 128, false, true><<<dim3(GB + EBC, 2), 256, 0, stream>>>(
        x_s, x_t, Ws1, Wt1, hbuf, (size_t)Nn * 32, as1s, at1s, as1d, at1d, ssrc, sdst, Nn, Din,
        ei_s, ei_t, bkt_cnt);
    // ---- rest of CSR build ----
    bkt_scan2<<<2, 512, 0, stream>>>(bkt_cnt, bkt_ptr, bkt_cur, row_ptr);
    bkt_scatter2<<<dim3(EBC, 2), 256, 0, stream>>>(ei_s, ei_t, bkt_cur, bkt_edges, Ecnt);
    csr_finalize2<<<dim3(NBKT, 2), 256, 0, stream>>>(bkt_edges, bkt_ptr, row_ptr, csr, Nn);
    // ---- attention layer 1 (fp8 gather) ----
    attn_agg2<128><<<dim3(NW2, 2), 256, 0, stream>>>(hbuf, ssrc, sdst, row_ptr, csr, bs1, bt1, xbuf, Nn);
    // ---- layer 2 GEMM (bf16 A, fp8 C) ----
    mfma_gemm2<2, 2, 64, true, false><<<dim3(GB, 2), 256, 0, stream>>>(
        xbuf, xbuf + HS, Ws2, Wt2, hbuf, (size_t)Nn * 16, as2s, at2s, as2d, at2d, ssrc, sdst, Nn, 128,
        nullptr, nullptr, nullptr);
    attn_agg2<64><<<dim3(NW2, 2), 256, 0, stream>>>(hbuf, ssrc, sdst, row_ptr, csr, bs2, bt2, xbuf, Nn);
    // ---- pool + head ----
    pool2<<<dim3(Gn, 2), 256, 0, stream>>>(xbuf, bat_s, bat_t, pooled, Nn);
    head_kernel<<<dim3(Lout / 256, Gn), 256, 0, stream>>>(pooled, pooled + (size_t)Gn * 64,
                                                          Wlin, blin, (float*)d_out);
}

// Round 14
// 204.620 us; speedup vs baseline: 7.6947x; 1.0147x over previous
//
#include <hip/hip_runtime.h>
#include <hip/hip_bf16.h>
#include <math.h>

constexpr int Nn   = 50000;
constexpr int Ecnt = 800000;
constexpr int Gn   = 128;
constexpr int Din  = 256;
constexpr int Lout = 1024;

constexpr int BKT_SH = 7;
constexpr int NBKT   = (Nn + 127) >> BKT_SH;    // 391
constexpr int CHUNK  = 4096;
constexpr int EBC    = (Ecnt + CHUNK - 1) / CHUNK;  // 196
constexpr size_t HS  = (size_t)Nn * 64;         // xbuf per-side stride (dwords, bf16 rows)

typedef __attribute__((ext_vector_type(8))) short short8;
typedef __attribute__((ext_vector_type(4))) float f32x4;
typedef __attribute__((ext_vector_type(2))) float v2f;

__device__ __forceinline__ float lrelu(float x) { return x >= 0.f ? x : 0.2f * x; }

__device__ __forceinline__ float bflo(uint32_t v) { return __uint_as_float(v << 16); }
__device__ __forceinline__ float bfhi(uint32_t v) { return __uint_as_float(v & 0xffff0000u); }
__device__ __forceinline__ uint32_t f2bf(float f) {
    uint32_t x = __float_as_uint(f);
    return (x + 0x7fffu + ((x >> 16) & 1u)) >> 16;
}
__device__ __forceinline__ uint32_t packbf(float lo, float hi) {
    return f2bf(lo) | (f2bf(hi) << 16);
}

// ================= CSR build (side = blockIdx.y) =================
__global__ __launch_bounds__(512) void bkt_scan2(const int* __restrict__ bkt_cnt_b,
                                                 int* __restrict__ bkt_ptr_b,
                                                 int* __restrict__ bkt_cur_b,
                                                 int* __restrict__ row_ptr_b) {
    int side = blockIdx.x;
    const int* bkt_cnt = bkt_cnt_b + (size_t)side * (NBKT + 1);
    int* bkt_ptr = bkt_ptr_b + (size_t)side * (NBKT + 1);
    int* bkt_cur = bkt_cur_b + (size_t)side * (NBKT + 1);
    int* row_ptr = row_ptr_b + (size_t)side * (Nn + 1);
    __shared__ int buf[512];
    int t = threadIdx.x;
    int v = (t < NBKT) ? bkt_cnt[t] : 0;
    buf[t] = v;
    __syncthreads();
    for (int off = 1; off < 512; off <<= 1) {
        int x = (t >= off) ? buf[t - off] : 0;
        __syncthreads();
        buf[t] += x;
        __syncthreads();
    }
    if (t < NBKT) {
        int excl = buf[t] - v;
        bkt_ptr[t] = excl;
        bkt_cur[t] = excl;
    }
    if (t == 511) {
        bkt_ptr[NBKT] = buf[511];
        row_ptr[Nn]   = buf[511];
    }
}

__global__ __launch_bounds__(256) void bkt_scatter2(const int* __restrict__ e0,
                                                    const int* __restrict__ e1,
                                                    int* __restrict__ bkt_cur_b,
                                                    uint32_t* __restrict__ bkt_edges_b, int E) {
    int side = blockIdx.y;
    const int* src = side ? e1 : e0;
    const int* dst = src + E;
    int* bkt_cur = bkt_cur_b + (size_t)side * (NBKT + 1);
    uint32_t* bkt_edges = bkt_edges_b + (size_t)side * Ecnt;
    __shared__ int h[NBKT];
    __shared__ int cur[NBKT];
    for (int i = threadIdx.x; i < NBKT; i += 256) h[i] = 0;
    __syncthreads();
    int base = blockIdx.x * CHUNK;
    int end = min(base + CHUNK, E);
    for (int i = base + threadIdx.x; i < end; i += 256)
        atomicAdd(&h[dst[i] >> BKT_SH], 1);
    __syncthreads();
    for (int i = threadIdx.x; i < NBKT; i += 256) {
        int c = h[i];
        h[i] = c ? atomicAdd(&bkt_cur[i], c) : 0;
        cur[i] = 0;
    }
    __syncthreads();
    for (int i = base + threadIdx.x; i < end; i += 256) {
        int d = dst[i], b = d >> BKT_SH;
        int pos = h[b] + atomicAdd(&cur[b], 1);
        bkt_edges[pos] = (uint32_t)src[i] | ((uint32_t)(d & 127) << 16);
    }
}

__global__ __launch_bounds__(256) void csr_finalize2(const uint32_t* __restrict__ bkt_edges_b,
                                                     const int* __restrict__ bkt_ptr_b,
                                                     int* __restrict__ row_ptr_b,
                                                     int* __restrict__ csr_b, int n) {
    int side = blockIdx.y;
    const uint32_t* bkt_edges = bkt_edges_b + (size_t)side * Ecnt;
    const int* bkt_ptr = bkt_ptr_b + (size_t)side * (NBKT + 1);
    int* row_ptr = row_ptr_b + (size_t)side * (Nn + 1);
    int* csr = csr_b + (size_t)side * Ecnt;
    int b = blockIdx.x;
    int base = bkt_ptr[b];
    int cnt  = bkt_ptr[b + 1] - base;
    __shared__ int hist[128], curs[128], sc[128];
    int t = threadIdx.x;
    if (t < 128) hist[t] = 0;
    __syncthreads();
    for (int i = t; i < cnt; i += 256)
        atomicAdd(&hist[(bkt_edges[base + i] >> 16) & 127], 1);
    __syncthreads();
    if (t < 128) sc[t] = hist[t];
    __syncthreads();
    for (int off = 1; off < 128; off <<= 1) {
        int x = (t >= off && t < 128) ? sc[t - off] : 0;
        __syncthreads();
        if (t < 128) sc[t] += x;
        __syncthreads();
    }
    if (t < 128) {
        int excl = sc[t] - hist[t];
        int node = (b << BKT_SH) + t;
        if (node < n) row_ptr[node] = base + excl;
        curs[t] = excl;
    }
    __syncthreads();
    for (int i = t; i < cnt; i += 256) {
        uint32_t e = bkt_edges[base + i];
        int pos = atomicAdd(&curs[(e >> 16) & 127], 1);
        csr[base + pos] = (int)(e & 0xFFFFu);
    }
}

// ---------------- MFMA bf16 GEMM (BM=128, 512 thr, 8 waves) -> fp8 C + fused scores ----------------
template<int MF, int NF, int BN, bool BF16A, bool FUSE_COUNT>
__global__ __launch_bounds__(512) void mfma_gemm2(
        const void* __restrict__ A0, const void* __restrict__ A1,
        const float* __restrict__ B0, const float* __restrict__ B1,
        uint32_t* __restrict__ Cb, size_t cstride,
        const float* __restrict__ as0, const float* __restrict__ as1,
        const float* __restrict__ ad0, const float* __restrict__ ad1,
        float* __restrict__ ssrc_b, float* __restrict__ sdst_b,
        int M, int K,
        const int* __restrict__ e0, const int* __restrict__ e1,
        int* __restrict__ bkt_cnt_b) {
    constexpr int BM = 4 * MF * 16;                 // 128
    __shared__ uint32_t Al[BM][36];
    __shared__ uint32_t Bl[BN][36];
    __shared__ float sS[BM][2], sD[BM][2];
    int side = blockIdx.y;

    if constexpr (FUSE_COUNT) {
        int gb = (M + BM - 1) / BM;
        if ((int)blockIdx.x >= gb) {
            int chunk = blockIdx.x - gb;
            const int* dst = (side ? e1 : e0) + Ecnt;
            int* bkt_cnt = bkt_cnt_b + (size_t)side * (NBKT + 1);
            int* hh = (int*)&Al[0][0];
            for (int i = threadIdx.x; i < NBKT; i += 512) hh[i] = 0;
            __syncthreads();
            int base = chunk * CHUNK;
            int end = min(base + CHUNK, Ecnt);
            for (int i = base + threadIdx.x; i < end; i += 512)
                atomicAdd(&hh[dst[i] >> BKT_SH], 1);
            __syncthreads();
            for (int i = threadIdx.x; i < NBKT; i += 512) {
                int c = hh[i];
                if (c) atomicAdd(&bkt_cnt[i], c);
            }
            return;
        }
    }

    const void* Av = side ? A1 : A0;
    const float* B = side ? B1 : B0;
    const float* Asrc = side ? as1 : as0;
    const float* Adst = side ? ad1 : ad0;
    uint32_t* C = Cb + (size_t)side * cstride;
    float* ssrc = ssrc_b + (size_t)side * Nn;
    float* sdst = sdst_b + (size_t)side * Nn;

    int tid  = threadIdx.x;
    int lane = tid & 63;
    int wid  = tid >> 6;                 // 0..7
    int wr = wid >> 1, wc = wid & 1;     // 4 x 2 wave grid
    int bm = blockIdx.x * BM;

    int arow = tid >> 2, aq = tid & 3;   // 4 threads per A row (128 rows)
    bool avalid = (bm + arow) < M;
    constexpr int NPI = BN * 16 / 512;   // B pair-iters per thread: 4 (BN=128) / 2 (BN=64)

    float    fA[16];
    uint32_t uA[8];
    float    fB[NPI][4];

    auto LOADA = [&](int k0) {
        if constexpr (BF16A) {
            const uint32_t* A = (const uint32_t*)Av;
            if (avalid) {
                const uint32_t* p = A + (size_t)(bm + arow) * (K >> 1) + (k0 >> 1) + aq * 8;
                uint4 u0 = *(const uint4*)p;
                uint4 u1 = *(const uint4*)(p + 4);
                uA[0] = u0.x; uA[1] = u0.y; uA[2] = u0.z; uA[3] = u0.w;
                uA[4] = u1.x; uA[5] = u1.y; uA[6] = u1.z; uA[7] = u1.w;
            } else {
                #pragma unroll
                for (int i = 0; i < 8; i++) uA[i] = 0u;
            }
        } else {
            const float* A = (const float*)Av;
            if (avalid) {
                const float* p = A + (size_t)(bm + arow) * K + k0 + aq * 16;
                #pragma unroll
                for (int i = 0; i < 4; i++) {
                    float4 f = *(const float4*)(p + i * 4);
                    fA[4 * i] = f.x; fA[4 * i + 1] = f.y; fA[4 * i + 2] = f.z; fA[4 * i + 3] = f.w;
                }
            } else {
                #pragma unroll
                for (int i = 0; i < 16; i++) fA[i] = 0.f;
            }
        }
    };
    auto LOADB = [&](int k0) {
        #pragma unroll
        for (int it = 0; it < NPI; it++) {
            int pi = tid + it * 512;
            int n = pi & (BN - 1);
            int kp = pi / BN;                  // 0..15
            const float* p = B + (size_t)(k0 + 4 * kp) * BN + n;
            fB[it][0] = p[0];
            fB[it][1] = p[BN];
            fB[it][2] = p[2 * BN];
            fB[it][3] = p[3 * BN];
        }
    };
    auto WRITE = [&]() {
        if constexpr (BF16A) {
            uint4* dst = (uint4*)&Al[arow][aq * 8];
            dst[0] = make_uint4(uA[0], uA[1], uA[2], uA[3]);
            dst[1] = make_uint4(uA[4], uA[5], uA[6], uA[7]);
        } else {
            uint32_t d[8];
            #pragma unroll
            for (int i = 0; i < 8; i++) d[i] = packbf(fA[2 * i], fA[2 * i + 1]);
            uint4* dst = (uint4*)&Al[arow][aq * 8];
            dst[0] = make_uint4(d[0], d[1], d[2], d[3]);
            dst[1] = make_uint4(d[4], d[5], d[6], d[7]);
        }
        #pragma unroll
        for (int it = 0; it < NPI; it++) {
            int pi = tid + it * 512;
            int n = pi & (BN - 1);
            int kp = pi / BN;
            *(uint2*)&Bl[n][2 * kp] = make_uint2(packbf(fB[it][0], fB[it][1]),
                                                 packbf(fB[it][2], fB[it][3]));
        }
    };

    f32x4 acc[MF][NF];
    #pragma unroll
    for (int i = 0; i < MF; i++)
        #pragma unroll
        for (int j = 0; j < NF; j++) acc[i][j] = (f32x4){0.f, 0.f, 0.f, 0.f};

    LOADA(0); LOADB(0);
    const int T = K / 64;
    for (int t = 0; t < T; t++) {
        WRITE();
        __syncthreads();
        if (t + 1 < T) { LOADA((t + 1) * 64); LOADB((t + 1) * 64); }
        int lr = lane & 15, lk = lane >> 4;
        #pragma unroll
        for (int ks = 0; ks < 2; ks++) {
            short8 af[MF], bf[NF];
            #pragma unroll
            for (int mf = 0; mf < MF; mf++)
                af[mf] = *(const short8*)&Al[wr * (MF * 16) + mf * 16 + lr][ks * 16 + lk * 4];
            #pragma unroll
            for (int nf = 0; nf < NF; nf++)
                bf[nf] = *(const short8*)&Bl[wc * (NF * 16) + nf * 16 + lr][ks * 16 + lk * 4];
            #pragma unroll
            for (int mf = 0; mf < MF; mf++)
                #pragma unroll
                for (int nf = 0; nf < NF; nf++)
                    acc[mf][nf] = __builtin_amdgcn_mfma_f32_16x16x32_bf16(af[mf], bf[nf], acc[mf][nf], 0, 0, 0);
        }
        __syncthreads();
    }

    int lr = lane & 15, lg = lane >> 4;
    // fused scores (from exact fp32 acc)
    {
        float a_s[NF], a_d[NF];
        #pragma unroll
        for (int nf = 0; nf < NF; nf++) {
            int col = wc * (NF * 16) + nf * 16 + lr;
            a_s[nf] = Asrc[col];
            a_d[nf] = Adst[col];
        }
        #pragma unroll
        for (int mf = 0; mf < MF; mf++) {
            #pragma unroll
            for (int j = 0; j < 4; j++) {
                float ps = 0.f, pd = 0.f;
                #pragma unroll
                for (int nf = 0; nf < NF; nf++) {
                    float v = acc[mf][nf][j];
                    ps += v * a_s[nf];
                    pd += v * a_d[nf];
                }
                #pragma unroll
                for (int o = 1; o < 16; o <<= 1) {
                    ps += __shfl_xor(ps, o);
                    pd += __shfl_xor(pd, o);
                }
                if (lr == 0) {
                    int rl = wr * (MF * 16) + mf * 16 + lg * 4 + j;
                    sS[rl][wc] = ps;
                    sD[rl][wc] = pd;
                }
            }
        }
    }
    // C write as fp8 e4m3 (HW cvt): 4 cols -> 1 dword
    #pragma unroll
    for (int mf = 0; mf < MF; mf++) {
        #pragma unroll
        for (int nf = 0; nf < NF; nf++) {
            int col = wc * (NF * 16) + nf * 16 + lr;
            #pragma unroll
            for (int j = 0; j < 4; j++) {
                int row = bm + wr * (MF * 16) + mf * 16 + lg * 4 + j;
                float v = acc[mf][nf][j];
                float w1 = __shfl_xor(v, 1);
                uint32_t p01 = (uint32_t)__builtin_amdgcn_cvt_pk_fp8_f32(v, w1, 0, false);
                uint32_t p23 = __shfl_xor(p01, 2);
                if (((lane & 3) == 0) && row < M)
                    C[(size_t)row * (BN >> 2) + (col >> 2)] = (p01 & 0xffffu) | (p23 << 16);
            }
        }
    }
    __syncthreads();
    if (tid < BM) {
        int row = bm + tid;
        if (row < M) {
            ssrc[row] = sS[tid][0] + sS[tid][1];
            sdst[row] = sD[tid][0] + sD[tid][1];
        }
    }
}

// ---------------- attention: 2 nodes per wave (half-wave each), fp8 gather, pk_fma ----------------
template<int F>
__global__ __launch_bounds__(256) void attn_agg2(const uint32_t* __restrict__ hb,
        const float* __restrict__ ssrc_b, const float* __restrict__ sdst_b,
        const int* __restrict__ row_ptr_b, const int* __restrict__ csr_b,
        const float* __restrict__ bias0, const float* __restrict__ bias1,
        uint32_t* __restrict__ xout_b, int n) {
    constexpr size_t HSTR = (size_t)Nn * (F / 4);
    constexpr int HD = F / 4;                       // fp8 dwords per row
    constexpr int XD = F / 2;                       // bf16 dwords per out row
    int side = blockIdx.y;
    const uint32_t* h = hb + (size_t)side * HSTR;
    const float* ssrc = ssrc_b + (size_t)side * Nn;
    const float* sdst = sdst_b + (size_t)side * Nn;
    const int* row_ptr = row_ptr_b + (size_t)side * (Nn + 1);
    const int* csr_src = csr_b + (size_t)side * Ecnt;
    const float* bias = side ? bias1 : bias0;
    uint32_t* xout = xout_b + (size_t)side * HS;

    int wave = (blockIdx.x * blockDim.x + threadIdx.x) >> 6;
    int lane = threadIdx.x & 63;
    int half = lane >> 5;
    int lane5 = lane & 31;
    int wid = wave * 2 + half;
    if (wid >= n) return;
    int beg = row_ptr[wid], end = row_ptr[wid + 1];
    int deg = end - beg;
    float sd = sdst[wid];
    float eself = lrelu(ssrc[wid] + sd);
    int base32 = lane & 32;

    v2f a0 = {0.f, 0.f}, a1 = {0.f, 0.f}, a2 = {0.f, 0.f}, a3 = {0.f, 0.f};
    auto FMA8 = [&](uint2 u, float wj) {
        v2f p0 = __builtin_amdgcn_cvt_pk_f32_fp8(u.x, false);
        v2f p1 = __builtin_amdgcn_cvt_pk_f32_fp8(u.x, true);
        v2f p2 = __builtin_amdgcn_cvt_pk_f32_fp8(u.y, false);
        v2f p3 = __builtin_amdgcn_cvt_pk_f32_fp8(u.y, true);
        v2f wv = {wj, wj};
        a0 += p0 * wv; a1 += p1 * wv; a2 += p2 * wv; a3 += p3 * wv;
    };

    if (deg <= 32) {
        int p = beg + lane5;
        bool act = lane5 < deg;
        int s = act ? csr_src[p] : 0;
        float e = act ? lrelu(ssrc[s] + sd) : -1e30f;
        float m = fmaxf(eself, e);
        #pragma unroll
        for (int o = 16; o; o >>= 1) m = fmaxf(m, __shfl_xor(m, o));
        float ex = act ? __expf(e - m) : 0.f;
        float dsum = ex;
        #pragma unroll
        for (int o = 16; o; o >>= 1) dsum += __shfl_xor(dsum, o);
        float exself = __expf(eself - m);
        dsum += exself;
        float inv = 1.f / dsum;
        float w = ex * inv;
        float wself = exself * inv;

        if constexpr (F == 128) {
            int slot = (lane >> 4) & 1, i = lane & 15;
            size_t foff = 2 * i;
            if (slot == 0) FMA8(*(const uint2*)(h + (size_t)wid * HD + foff), wself);
            int j = slot;
            for (; j + 6 < deg; j += 8) {
                float w0 = __shfl(w, base32 | j),       w1 = __shfl(w, base32 | (j + 2));
                float w2 = __shfl(w, base32 | (j + 4)), w3 = __shfl(w, base32 | (j + 6));
                int   s0 = __shfl(s, base32 | j),       s1 = __shfl(s, base32 | (j + 2));
                int   s2 = __shfl(s, base32 | (j + 4)), s3 = __shfl(s, base32 | (j + 6));
                uint2 u0 = *(const uint2*)(h + (size_t)s0 * HD + foff);
                uint2 u1 = *(const uint2*)(h + (size_t)s1 * HD + foff);
                uint2 u2 = *(const uint2*)(h + (size_t)s2 * HD + foff);
                uint2 u3 = *(const uint2*)(h + (size_t)s3 * HD + foff);
                FMA8(u0, w0); FMA8(u1, w1); FMA8(u2, w2); FMA8(u3, w3);
            }
            for (; j < deg; j += 2) {
                float w0 = __shfl(w, base32 | j);
                int   s0 = __shfl(s, base32 | j);
                FMA8(*(const uint2*)(h + (size_t)s0 * HD + foff), w0);
            }
            a0[0] += __shfl_xor(a0[0], 16); a0[1] += __shfl_xor(a0[1], 16);
            a1[0] += __shfl_xor(a1[0], 16); a1[1] += __shfl_xor(a1[1], 16);
            a2[0] += __shfl_xor(a2[0], 16); a2[1] += __shfl_xor(a2[1], 16);
            a3[0] += __shfl_xor(a3[0], 16); a3[1] += __shfl_xor(a3[1], 16);
            if (!(lane & 16)) {
                float r0 = fmaxf(a0[0] + bias[8*i],   0.f), r1 = fmaxf(a0[1] + bias[8*i+1], 0.f);
                float r2 = fmaxf(a1[0] + bias[8*i+2], 0.f), r3 = fmaxf(a1[1] + bias[8*i+3], 0.f);
                float r4 = fmaxf(a2[0] + bias[8*i+4], 0.f), r5 = fmaxf(a2[1] + bias[8*i+5], 0.f);
                float r6 = fmaxf(a3[0] + bias[8*i+6], 0.f), r7 = fmaxf(a3[1] + bias[8*i+7], 0.f);
                *(uint4*)(xout + (size_t)wid * XD + 4 * i) =
                    make_uint4(packbf(r0, r1), packbf(r2, r3), packbf(r4, r5), packbf(r6, r7));
            }
        } else {
            int g = (lane >> 3) & 3, i = lane & 7;
            size_t foff = 2 * i;
            if (g == 0) FMA8(*(const uint2*)(h + (size_t)wid * HD + foff), wself);
            int j = g;
            for (; j + 12 < deg; j += 16) {
                float w0 = __shfl(w, base32 | j),       w1 = __shfl(w, base32 | (j + 4));
                float w2 = __shfl(w, base32 | (j + 8)), w3 = __shfl(w, base32 | (j + 12));
                int   s0 = __shfl(s, base32 | j),       s1 = __shfl(s, base32 | (j + 4));
                int   s2 = __shfl(s, base32 | (j + 8)), s3 = __shfl(s, base32 | (j + 12));
                uint2 u0 = *(const uint2*)(h + (size_t)s0 * HD + foff);
                uint2 u1 = *(const uint2*)(h + (size_t)s1 * HD + foff);
                uint2 u2 = *(const uint2*)(h + (size_t)s2 * HD + foff);
                uint2 u3 = *(const uint2*)(h + (size_t)s3 * HD + foff);
                FMA8(u0, w0); FMA8(u1, w1); FMA8(u2, w2); FMA8(u3, w3);
            }
            for (; j < deg; j += 4) {
                float w0 = __shfl(w, base32 | j);
                int   s0 = __shfl(s, base32 | j);
                FMA8(*(const uint2*)(h + (size_t)s0 * HD + foff), w0);
            }
            #pragma unroll
            for (int o = 8; o <= 16; o <<= 1) {
                a0[0] += __shfl_xor(a0[0], o); a0[1] += __shfl_xor(a0[1], o);
                a1[0] += __shfl_xor(a1[0], o); a1[1] += __shfl_xor(a1[1], o);
                a2[0] += __shfl_xor(a2[0], o); a2[1] += __shfl_xor(a2[1], o);
                a3[0] += __shfl_xor(a3[0], o); a3[1] += __shfl_xor(a3[1], o);
            }
            if (!(lane & 24)) {
                float r0 = fmaxf(a0[0] + bias[8*i],   0.f), r1 = fmaxf(a0[1] + bias[8*i+1], 0.f);
                float r2 = fmaxf(a1[0] + bias[8*i+2], 0.f), r3 = fmaxf(a1[1] + bias[8*i+3], 0.f);
                float r4 = fmaxf(a2[0] + bias[8*i+4], 0.f), r5 = fmaxf(a2[1] + bias[8*i+5], 0.f);
                float r6 = fmaxf(a3[0] + bias[8*i+6], 0.f), r7 = fmaxf(a3[1] + bias[8*i+7], 0.f);
                *(uint4*)(xout + (size_t)wid * XD + 4 * i) =
                    make_uint4(packbf(r0, r1), packbf(r2, r3), packbf(r4, r5), packbf(r6, r7));
            }
        }
        return;
    }

    // ---- generic path (deg > 32): half-wave, per-edge weight recomputed ----
    float m = eself;
    for (int p = beg + lane5; p < end; p += 32)
        m = fmaxf(m, lrelu(ssrc[csr_src[p]] + sd));
    #pragma unroll
    for (int o = 16; o; o >>= 1) m = fmaxf(m, __shfl_xor(m, o));
    float dsum = (lane5 == 0) ? __expf(eself - m) : 0.f;
    for (int p = beg + lane5; p < end; p += 32)
        dsum += __expf(lrelu(ssrc[csr_src[p]] + sd) - m);
    #pragma unroll
    for (int o = 16; o; o >>= 1) dsum += __shfl_xor(dsum, o);
    float inv = 1.f / dsum;
    float wself = __expf(eself - m) * inv;

    if constexpr (F == 128) {
        int slot = (lane >> 4) & 1, i = lane & 15;
        size_t foff = 2 * i;
        if (slot == 0) FMA8(*(const uint2*)(h + (size_t)wid * HD + foff), wself);
        for (int j = slot; j < deg; j += 2) {
            int sj = csr_src[beg + j];
            float wj = __expf(lrelu(ssrc[sj] + sd) - m) * inv;
            FMA8(*(const uint2*)(h + (size_t)sj * HD + foff), wj);
        }
        a0[0] += __shfl_xor(a0[0], 16); a0[1] += __shfl_xor(a0[1], 16);
        a1[0] += __shfl_xor(a1[0], 16); a1[1] += __shfl_xor(a1[1], 16);
        a2[0] += __shfl_xor(a2[0], 16); a2[1] += __shfl_xor(a2[1], 16);
        a3[0] += __shfl_xor(a3[0], 16); a3[1] += __shfl_xor(a3[1], 16);
        if (!(lane & 16)) {
            float r0 = fmaxf(a0[0] + bias[8*i],   0.f), r1 = fmaxf(a0[1] + bias[8*i+1], 0.f);
            float r2 = fmaxf(a1[0] + bias[8*i+2], 0.f), r3 = fmaxf(a1[1] + bias[8*i+3], 0.f);
            float r4 = fmaxf(a2[0] + bias[8*i+4], 0.f), r5 = fmaxf(a2[1] + bias[8*i+5], 0.f);
            float r6 = fmaxf(a3[0] + bias[8*i+6], 0.f), r7 = fmaxf(a3[1] + bias[8*i+7], 0.f);
            *(uint4*)(xout + (size_t)wid * XD + 4 * i) =
                make_uint4(packbf(r0, r1), packbf(r2, r3), packbf(r4, r5), packbf(r6, r7));
        }
    } else {
        int g = (lane >> 3) & 3, i = lane & 7;
        size_t foff = 2 * i;
        if (g == 0) FMA8(*(const uint2*)(h + (size_t)wid * HD + foff), wself);
        for (int j = g; j < deg; j += 4) {
            int sj = csr_src[beg + j];
            float wj = __expf(lrelu(ssrc[sj] + sd) - m) * inv;
            FMA8(*(const uint2*)(h + (size_t)sj * HD + foff), wj);
        }
        #pragma unroll
        for (int o = 8; o <= 16; o <<= 1) {
            a0[0] += __shfl_xor(a0[0], o); a0[1] += __shfl_xor(a0[1], o);
            a1[0] += __shfl_xor(a1[0], o); a1[1] += __shfl_xor(a1[1], o);
            a2[0] += __shfl_xor(a2[0], o); a2[1] += __shfl_xor(a2[1], o);
            a3[0] += __shfl_xor(a3[0], o); a3[1] += __shfl_xor(a3[1], o);
        }
        if (!(lane & 24)) {
            float r0 = fmaxf(a0[0] + bias[8*i],   0.f), r1 = fmaxf(a0[1] + bias[8*i+1], 0.f);
            float r2 = fmaxf(a1[0] + bias[8*i+2], 0.f), r3 = fmaxf(a1[1] + bias[8*i+3], 0.f);
            float r4 = fmaxf(a2[0] + bias[8*i+4], 0.f), r5 = fmaxf(a2[1] + bias[8*i+5], 0.f);
            float r6 = fmaxf(a3[0] + bias[8*i+6], 0.f), r7 = fmaxf(a3[1] + bias[8*i+7], 0.f);
            *(uint4*)(xout + (size_t)wid * XD + 4 * i) =
                make_uint4(packbf(r0, r1), packbf(r2, r3), packbf(r4, r5), packbf(r6, r7));
        }
    }
}

// ---------------- mean pool (sorted batch), both sides ----------------
__global__ __launch_bounds__(256) void pool2(const uint32_t* __restrict__ xb,
                                             const int* __restrict__ bat0,
                                             const int* __restrict__ bat1,
                                             float* __restrict__ pooled_b, int n) {
    int side = blockIdx.y;
    const uint32_t* x = xb + (size_t)side * HS;
    const int* batch = side ? bat1 : bat0;
    float* pooled = pooled_b + (size_t)side * Gn * 64;
    int g = blockIdx.x;
    int tid = threadIdx.x;
    __shared__ int s_lo, s_hi;
    if (tid == 0) {
        int lo = 0, hi = n;
        while (lo < hi) { int mid = (lo + hi) >> 1; if (batch[mid] < g) lo = mid + 1; else hi = mid; }
        s_lo = lo;
        int lo2 = lo, hi2 = n;
        while (lo2 < hi2) { int mid = (lo2 + hi2) >> 1; if (batch[mid] < g + 1) lo2 = mid + 1; else hi2 = mid; }
        s_hi = lo2;
    }
    __syncthreads();
    int lo = s_lo, hi = s_hi;
    int grp = tid >> 5, col = tid & 31;
    float a0 = 0.f, a1 = 0.f;
    for (int i = lo + grp; i < hi; i += 8) {
        uint32_t v = x[(size_t)i * 32 + col];
        a0 += bflo(v);
        a1 += bfhi(v);
    }
    __shared__ float red0[8][32], red1[8][32];
    red0[grp][col] = a0;
    red1[grp][col] = a1;
    __syncthreads();
    if (tid < 32) {
        float s0 = 0.f, s1 = 0.f;
        #pragma unroll
        for (int r = 0; r < 8; r++) { s0 += red0[r][tid]; s1 += red1[r][tid]; }
        float c = fmaxf((float)(hi - lo), 1.f);
        pooled[g * 64 + 2 * tid]     = s0 / c;
        pooled[g * 64 + 2 * tid + 1] = s1 / c;
    }
}

// ---------------- head ----------------
__global__ __launch_bounds__(256) void head_kernel(const float* __restrict__ xs,
                                                   const float* __restrict__ xt,
                                                   const float* __restrict__ Wlin,
                                                   const float* __restrict__ blin,
                                                   float* __restrict__ out) {
    int g = blockIdx.y;
    int c = blockIdx.x * 256 + threadIdx.x;
    __shared__ float z[64];
    if (threadIdx.x < 64) z[threadIdx.x] = xs[g * 64 + threadIdx.x] + xt[g * 64 + threadIdx.x];
    __syncthreads();
    float a0 = 0.f, a1 = 0.f, a2 = 0.f, a3 = 0.f;
    #pragma unroll
    for (int k = 0; k < 64; k += 4) {
        a0 += z[k]     * Wlin[(size_t)(k)     * Lout + c];
        a1 += z[k + 1] * Wlin[(size_t)(k + 1) * Lout + c];
        a2 += z[k + 2] * Wlin[(size_t)(k + 2) * Lout + c];
        a3 += z[k + 3] * Wlin[(size_t)(k + 3) * Lout + c];
    }
    float acc = (a0 + a1) + (a2 + a3) + blin[c];
    out[(size_t)g * Lout + c] = 1.f / (1.f + expf(-acc));
}

extern "C" void kernel_launch(void* const* d_in, const int* in_sizes, int n_in,
                              void* d_out, int out_size, void* d_ws, size_t ws_size,
                              hipStream_t stream) {
    size_t off = 0;
    auto alloc = [&](size_t bytes) -> void* {
        void* p = (char*)d_ws + off;
        off += (bytes + 255) & ~(size_t)255;
        return p;
    };
    uint32_t* hbuf    = (uint32_t*)alloc(2 * (size_t)Nn * 32 * 4);   // fp8 rows
    uint32_t* xbuf    = (uint32_t*)alloc(2 * HS * 4);                // bf16 rows
    float* ssrc       = (float*)alloc(2 * (size_t)Nn * 4);
    float* sdst       = (float*)alloc(2 * (size_t)Nn * 4);
    int*   row_ptr    = (int*)alloc(2 * (size_t)(Nn + 1) * 4);
    int*   csr        = (int*)alloc(2 * (size_t)Ecnt * 4);
    uint32_t* bkt_edges = (uint32_t*)alloc(2 * (size_t)Ecnt * 4);
    int*   bkt_cnt    = (int*)alloc(2 * (size_t)(NBKT + 1) * 4);
    int*   bkt_ptr    = (int*)alloc(2 * (size_t)(NBKT + 1) * 4);
    int*   bkt_cur    = (int*)alloc(2 * (size_t)(NBKT + 1) * 4);
    float* pooled     = (float*)alloc(2 * (size_t)Gn * 64 * 4);

    const int NW2 = (((Nn + 1) / 2) * 64 + 255) / 256;   // 2 nodes per wave
    const int GB  = (Nn + 127) / 128;                    // BM=128 -> 391

    const float* x_s = (const float*)d_in[0];
    const float* x_t = (const float*)d_in[1];
    const int* ei_s  = (const int*)d_in[2];
    const int* ei_t  = (const int*)d_in[3];
    const int* bat_s = (const int*)d_in[4];
    const int* bat_t = (const int*)d_in[5];
    const float *Ws1 = (const float*)d_in[6],  *as1s = (const float*)d_in[7],
                *as1d = (const float*)d_in[8],  *bs1 = (const float*)d_in[9];
    const float *Ws2 = (const float*)d_in[10], *as2s = (const float*)d_in[11],
                *as2d = (const float*)d_in[12], *bs2 = (const float*)d_in[13];
    const float *Wt1 = (const float*)d_in[14], *at1s = (const float*)d_in[15],
                *at1d = (const float*)d_in[16], *bt1 = (const float*)d_in[17];
    const float *Wt2 = (const float*)d_in[18], *at2s = (const float*)d_in[19],
                *at2d = (const float*)d_in[20], *bt2 = (const float*)d_in[21];
    const float *Wlin = (const float*)d_in[22], *blin = (const float*)d_in[23];

    // ---- memset counters, then layer-1 GEMM (fp8 C) with fused bucket-count ----
    hipMemsetAsync(bkt_cnt, 0, 2 * (size_t)(NBKT + 1) * 4, stream);
    mfma_gemm2<2, 4, 128, false, true><<<dim3(GB + EBC, 2), 512, 0, stream>>>(
        x_s, x_t, Ws1, Wt1, hbuf, (size_t)Nn * 32, as1s, at1s, as1d, at1d, ssrc, sdst, Nn, Din,
        ei_s, ei_t, bkt_cnt);
    // ---- rest of CSR build ----
    bkt_scan2<<<2, 512, 0, stream>>>(bkt_cnt, bkt_ptr, bkt_cur, row_ptr);
    bkt_scatter2<<<dim3(EBC, 2), 256, 0, stream>>>(ei_s, ei_t, bkt_cur, bkt_edges, Ecnt);
    csr_finalize2<<<dim3(NBKT, 2), 256, 0, stream>>>(bkt_edges, bkt_ptr, row_ptr, csr, Nn);
    // ---- attention layer 1 (fp8 gather) ----
    attn_agg2<128><<<dim3(NW2, 2), 256, 0, stream>>>(hbuf, ssrc, sdst, row_ptr, csr, bs1, bt1, xbuf, Nn);
    // ---- layer 2 GEMM (bf16 A, fp8 C) ----
    mfma_gemm2<2, 2, 64, true, false><<<dim3(GB, 2), 512, 0, stream>>>(
        xbuf, xbuf + HS, Ws2, Wt2, hbuf, (size_t)Nn * 16, as2s, at2s, as2d, at2d, ssrc, sdst, Nn, 128,
        nullptr, nullptr, nullptr);
    attn_agg2<64><<<dim3(NW2, 2), 256, 0, stream>>>(hbuf, ssrc, sdst, row_ptr, csr, bs2, bt2, xbuf, Nn);
    // ---- pool + head ----
    pool2<<<dim3(Gn, 2), 256, 0, stream>>>(xbuf, bat_s, bat_t, pooled, Nn);
    head_kernel<<<dim3(Lout / 256, Gn), 256, 0, stream>>>(pooled, pooled + (size_t)Gn * 64,
                                                          Wlin, blin, (float*)d_out);
}